// Round 9
// baseline (2265.932 us; speedup 1.0000x reference)
//
#include <hip/hip_runtime.h>
#include <cstddef>
#include <cmath>

namespace {

constexpr int H = 4, D = 32, HID = 128;
constexpr int NA = 100000, NW = 20000, NO = 50000;
constexpr int NTOT = NA + NW + NO;
constexpr int E = 150000;
constexpr float SCALE = 0.17677669529663687f;  // 1/sqrt(32)

typedef __attribute__((ext_vector_type(8))) short short8v;
typedef __attribute__((ext_vector_type(4))) float f32x4;

__device__ __forceinline__ float gelu_exact(float x) {
  return 0.5f * x * (1.f + erff(x * 0.7071067811865475f));
}

__device__ __forceinline__ unsigned short f2bf(float f) {  // RNE
  unsigned u = __float_as_uint(f);
  return (unsigned short)((u + 0x7FFF + ((u >> 16) & 1)) >> 16);
}
__device__ __forceinline__ float bf2f(unsigned short s) {
  return __uint_as_float(((unsigned)s) << 16);
}

// ---------------- MFMA GEMM: C_bf16 = act(A @ W_f32slice + bias) ----------
// tile 64x64, 4 waves; wave w owns rows [16w,16w+16). K = KSTEPS*32.
template <int KSTEPS, bool A_FP32, bool RELU_OUT>
__global__ __launch_bounds__(256) void gemm_mfma(
    const void* __restrict__ Av, const float* __restrict__ W,
    const float* __restrict__ bias, unsigned short* __restrict__ C,
    int M, int lda, int ldw, int ldc) {
  __shared__ unsigned short As[64][40];
  __shared__ unsigned short Bs[64][40];
  const int tid = threadIdx.x;
  const int wv = tid >> 6;
  const int l = tid & 63;
  const int bm = blockIdx.x * 64, bn = blockIdx.y * 64;
  f32x4 acc[4] = {};
  const int srow = tid >> 2, sc8 = (tid & 3) * 8;
  for (int ks = 0; ks < KSTEPS; ks++) {
    const int kk = ks * 32;
    {
      int gr = bm + srow;
      if (A_FP32) {
        unsigned short tmp[8] = {};
        if (gr < M) {
          const float* src = (const float*)Av + (size_t)gr * lda + kk + sc8;
          float4 f0 = *(const float4*)src;
          float4 f1 = *(const float4*)(src + 4);
          tmp[0] = f2bf(f0.x); tmp[1] = f2bf(f0.y);
          tmp[2] = f2bf(f0.z); tmp[3] = f2bf(f0.w);
          tmp[4] = f2bf(f1.x); tmp[5] = f2bf(f1.y);
          tmp[6] = f2bf(f1.z); tmp[7] = f2bf(f1.w);
        }
        *(uint4*)&As[srow][sc8] = *(const uint4*)tmp;
      } else {
        uint4 v = {0, 0, 0, 0};
        if (gr < M)
          v = *(const uint4*)((const unsigned short*)Av + (size_t)gr * lda +
                              kk + sc8);
        *(uint4*)&As[srow][sc8] = v;
      }
    }
    #pragma unroll
    for (int i = 0; i < 8; i++) {
      int idx = tid + i * 256;
      int r = idx >> 6, c = idx & 63;
      Bs[c][r] = f2bf(W[(size_t)(kk + r) * ldw + bn + c]);
    }
    __syncthreads();
    const int arow = wv * 16 + (l & 15);
    const int k8 = (l >> 4) * 8;
    short8v af = *(const short8v*)&As[arow][k8];
    #pragma unroll
    for (int n = 0; n < 4; n++) {
      short8v bf = *(const short8v*)&Bs[n * 16 + (l & 15)][k8];
      acc[n] = __builtin_amdgcn_mfma_f32_16x16x32_bf16(af, bf, acc[n], 0, 0, 0);
    }
    __syncthreads();
  }
  #pragma unroll
  for (int n = 0; n < 4; n++) {
    int col = bn + n * 16 + (l & 15);
    float bb = bias[col];
    #pragma unroll
    for (int j = 0; j < 4; j++) {
      int row = bm + wv * 16 + (l >> 4) * 4 + j;
      if (row < M) {
        float o = acc[n][j] + bb;
        if (RELU_OUT) o = fmaxf(o, 0.f);
        C[(size_t)row * ldc + col] = f2bf(o);
      }
    }
  }
}

// fused: xs = relu(LN( g*(gelu(A_bf16) @ W_o + b_o) + (1-g)*xs ))  [MFMA]
__global__ __launch_bounds__(256) void wo_ln_mfma(
    const unsigned short* __restrict__ A, int lda, const float* __restrict__ W,
    const float* __restrict__ bias, unsigned short* __restrict__ xs,
    const float* __restrict__ skip_p, const float* __restrict__ g_ln,
    const float* __restrict__ b_ln, int M) {
  __shared__ unsigned short As[64][40];
  __shared__ unsigned short Bs[128][40];
  const int tid = threadIdx.x;
  const int wv = tid >> 6;
  const int l = tid & 63;
  const int bm = blockIdx.x * 64;
  f32x4 acc[8] = {};
  const int srow = tid >> 2, sc8 = (tid & 3) * 8;
  for (int ks = 0; ks < 4; ks++) {
    const int kk = ks * 32;
    {
      int gr = bm + srow;
      uint4 v = {0, 0, 0, 0};
      if (gr < M)
        v = *(const uint4*)(A + (size_t)gr * lda + kk + sc8);
      unsigned w4[4] = {v.x, v.y, v.z, v.w};
      unsigned short tmp[8];
      #pragma unroll
      for (int j = 0; j < 4; j++) {
        tmp[j * 2 + 0] = f2bf(gelu_exact(bf2f((unsigned short)(w4[j] & 0xFFFF))));
        tmp[j * 2 + 1] = f2bf(gelu_exact(bf2f((unsigned short)(w4[j] >> 16))));
      }
      *(uint4*)&As[srow][sc8] = *(const uint4*)tmp;
    }
    #pragma unroll
    for (int i = 0; i < 16; i++) {
      int idx = tid + i * 256;
      int r = idx >> 7, c = idx & 127;
      Bs[c][r] = f2bf(W[(size_t)(kk + r) * HID + c]);
    }
    __syncthreads();
    const int arow = wv * 16 + (l & 15);
    const int k8 = (l >> 4) * 8;
    short8v af = *(const short8v*)&As[arow][k8];
    #pragma unroll
    for (int n = 0; n < 8; n++) {
      short8v bf = *(const short8v*)&Bs[n * 16 + (l & 15)][k8];
      acc[n] = __builtin_amdgcn_mfma_f32_16x16x32_bf16(af, bf, acc[n], 0, 0, 0);
    }
    __syncthreads();
  }
  const float g = 1.f / (1.f + expf(-skip_p[0]));
  float bb[8], gl[8], bl[8];
  #pragma unroll
  for (int n = 0; n < 8; n++) {
    int col = n * 16 + (l & 15);
    bb[n] = bias[col];
    gl[n] = g_ln[col];
    bl[n] = b_ln[col];
  }
  #pragma unroll
  for (int j = 0; j < 4; j++) {
    int row = bm + wv * 16 + (l >> 4) * 4 + j;
    bool ok = row < M;
    float vv[8], sum = 0.f, sq = 0.f;
    #pragma unroll
    for (int n = 0; n < 8; n++) {
      int col = n * 16 + (l & 15);
      float xo = ok ? bf2f(xs[(size_t)row * HID + col]) : 0.f;
      float val = g * (acc[n][j] + bb[n]) + (1.f - g) * xo;
      vv[n] = val;
      sum += val;
      sq += val * val;
    }
    #pragma unroll
    for (int m = 1; m < 16; m <<= 1) {
      sum += __shfl_xor(sum, m, 64);
      sq += __shfl_xor(sq, m, 64);
    }
    float mu = sum * (1.f / 128.f);
    float var = sq * (1.f / 128.f) - mu * mu;
    float r = rsqrtf(var + 1e-5f);
    if (ok) {
      #pragma unroll
      for (int n = 0; n < 8; n++) {
        float y = fmaxf((vv[n] - mu) * r * gl[n] + bl[n], 0.f);
        xs[(size_t)row * HID + n * 16 + (l & 15)] = f2bf(y);
      }
    }
  }
}

// ---------------- CSR build (deterministic) ----------------
__global__ __launch_bounds__(256) void csr_hist(const int* __restrict__ dst,
                                                int* __restrict__ cnt, int n) {
  int e = blockIdx.x * 256 + threadIdx.x;
  if (e < n) atomicAdd(&cnt[dst[e]], 1);
}

__global__ __launch_bounds__(256) void scan_block(const int* __restrict__ cnt,
                                                  int* __restrict__ excl,
                                                  int* __restrict__ bsum,
                                                  int n) {
  __shared__ int tmp[256];
  int i = blockIdx.x * 256 + threadIdx.x;
  int v = (i < n) ? cnt[i] : 0;
  tmp[threadIdx.x] = v;
  __syncthreads();
  int acc = v;
  for (int off = 1; off < 256; off <<= 1) {
    int other = (threadIdx.x >= off) ? tmp[threadIdx.x - off] : 0;
    __syncthreads();
    acc += other;
    tmp[threadIdx.x] = acc;
    __syncthreads();
  }
  if (i < n) excl[i] = acc - v;
  if (threadIdx.x == 255) bsum[blockIdx.x] = acc;
}

__global__ __launch_bounds__(256) void scan_bsums(int* __restrict__ bsum,
                                                  int nb) {
  __shared__ int tmp[256];
  __shared__ int carry;
  if (threadIdx.x == 0) carry = 0;
  __syncthreads();
  for (int start = 0; start < nb; start += 256) {
    int i = start + threadIdx.x;
    int v = (i < nb) ? bsum[i] : 0;
    tmp[threadIdx.x] = v;
    __syncthreads();
    int acc = v;
    for (int off = 1; off < 256; off <<= 1) {
      int other = (threadIdx.x >= off) ? tmp[threadIdx.x - off] : 0;
      __syncthreads();
      acc += other;
      tmp[threadIdx.x] = acc;
      __syncthreads();
    }
    int c = carry;
    if (i < nb) bsum[i] = c + acc - v;
    __syncthreads();
    if (threadIdx.x == 255) carry = c + acc;
    __syncthreads();
  }
}

__global__ __launch_bounds__(256) void csr_finalize(int* __restrict__ rp,
                                                    const int* __restrict__ bsum,
                                                    int* __restrict__ cursor,
                                                    int n, int ne) {
  int i = blockIdx.x * 256 + threadIdx.x;
  if (i < n) {
    int v = rp[i] + bsum[i >> 8];
    rp[i] = v;
    cursor[i] = v;
  } else if (i == n) {
    rp[n] = ne;
  }
}

__global__ __launch_bounds__(256) void csr_scatter(const int* __restrict__ dst,
                                                   int* __restrict__ cursor,
                                                   int* __restrict__ ce, int n) {
  int e = blockIdx.x * 256 + threadIdx.x;
  if (e < n) {
    int slot = atomicAdd(&cursor[dst[e]], 1);
    ce[slot] = e;
  }
}

__global__ __launch_bounds__(256) void csr_sort(const int* __restrict__ rp,
                                                int* __restrict__ ce, int n) {
  int d = blockIdx.x * 256 + threadIdx.x;
  if (d >= n) return;
  int b = rp[d], e = rp[d + 1];
  for (int i = b + 1; i < e; i++) {
    int key = ce[i];
    int j = i - 1;
    while (j >= b && ce[j] > key) { ce[j + 1] = ce[j]; j--; }
    ce[j + 1] = key;
  }
}

__global__ __launch_bounds__(256) void build_sd(
    const int* __restrict__ ce, const int* __restrict__ s0,
    const int* __restrict__ s1, const int* __restrict__ s2,
    const int* __restrict__ s3, const int* __restrict__ d0,
    const int* __restrict__ d1, const int* __restrict__ d2,
    const int* __restrict__ d3, int* __restrict__ srcOf,
    int* __restrict__ dstOf) {
  int t = blockIdx.x * 256 + threadIdx.x;
  if (t >= 4 * E) return;
  int et = t / E;
  int e = ce[t];
  const int* sp = et == 0 ? s0 : et == 1 ? s1 : et == 2 ? s2 : s3;
  const int* dp = et == 0 ? d0 : et == 1 ? d1 : et == 2 ? d2 : d3;
  srcOf[t] = sp[e];
  dstOf[t] = dp[e];
}

// ---------------- attention ----------------
// rel32: 32-lane group per (src-node, h); lane = output dim e.
// out[n,h,e] = sum_d in[n,h,d] * T[h,d,e]   (used for both k@A and v@M)
__global__ __launch_bounds__(256) void rel32(
    const unsigned short* __restrict__ in, int ldin,
    const float* __restrict__ T, unsigned short* __restrict__ out, int srcOff,
    int Nsrc) {
  int g = (blockIdx.x * 256 + threadIdx.x) >> 5;
  int lane = threadIdx.x & 31;
  if (g >= Nsrc * H) return;
  int n = g >> 2, h = g & 3;
  float kd = bf2f(in[(size_t)(srcOff + n) * ldin + h * 32 + lane]);
  const float* Tr = T + h * D * D;
  float o = 0.f;
  #pragma unroll 8
  for (int d2 = 0; d2 < 32; d2++)
    o += __shfl(kd, d2, 32) * Tr[d2 * 32 + lane];
  out[(size_t)n * HID + h * 32 + lane] = f2bf(o);
}

// alpha32: 32-lane group per (slot, h); lane = dim.
__global__ __launch_bounds__(256) void alpha32(
    const unsigned short* __restrict__ ke,
    const unsigned short* __restrict__ qbase, int ldq,
    const int* __restrict__ srcOf, const int* __restrict__ dstOf,
    const float* __restrict__ prel, float* __restrict__ alphaOut, int dstOff) {
  int g = (blockIdx.x * 256 + threadIdx.x) >> 5;
  int lane = threadIdx.x & 31;
  if (g >= E * H) return;
  int i = g >> 2, h = g & 3;
  int s_ = srcOf[i], d_ = dstOf[i];
  float pv = bf2f(qbase[(size_t)(dstOff + d_) * ldq + h * 32 + lane]) *
             bf2f(ke[(size_t)s_ * HID + h * 32 + lane]);
  #pragma unroll
  for (int m = 1; m < 32; m <<= 1) pv += __shfl_xor(pv, m, 32);
  if (lane == 0) alphaOut[(size_t)i * H + h] = pv * prel[h] * SCALE;
}

// softmax32: per (dst,h): mx, den over contiguous slots; normalize in place
__global__ __launch_bounds__(256) void softmax32(
    const int* __restrict__ rp0, float* __restrict__ al0,
    const int* __restrict__ rp1, float* __restrict__ al1, int net, int Ndst) {
  int g = (blockIdx.x * 256 + threadIdx.x) >> 5;
  int lane = threadIdx.x & 31;
  if (g >= Ndst * H) return;
  int dl = g >> 2, h = g & 3;
  int b0 = rp0[dl], e0 = rp0[dl + 1];
  int b1 = 0, e1 = 0;
  if (net == 2) { b1 = rp1[dl]; e1 = rp1[dl + 1]; }
  float mx = -INFINITY;
  for (int i = b0 + lane; i < e0; i += 32) mx = fmaxf(mx, al0[(size_t)i * H + h]);
  for (int i = b1 + lane; i < e1; i += 32) mx = fmaxf(mx, al1[(size_t)i * H + h]);
  #pragma unroll
  for (int m = 1; m < 32; m <<= 1) mx = fmaxf(mx, __shfl_xor(mx, m, 32));
  float den = 0.f;
  for (int i = b0 + lane; i < e0; i += 32) den += expf(al0[(size_t)i * H + h] - mx);
  for (int i = b1 + lane; i < e1; i += 32) den += expf(al1[(size_t)i * H + h] - mx);
  #pragma unroll
  for (int m = 1; m < 32; m <<= 1) den += __shfl_xor(den, m, 32);
  float inv = 1.f / (den + 1e-16f);
  for (int i = b0 + lane; i < e0; i += 32)
    al0[(size_t)i * H + h] = expf(al0[(size_t)i * H + h] - mx) * inv;
  for (int i = b1 + lane; i < e1; i += 32)
    al1[(size_t)i * H + h] = expf(al1[(size_t)i * H + h] - mx) * inv;
}

// agg32: pure gather-accumulate. acc = sum_i w[i] * v'[src[i]]; lane = dim.
__global__ __launch_bounds__(256) void agg32(
    const unsigned short* __restrict__ vp0, const int* __restrict__ rp0,
    const int* __restrict__ srcOf0, const float* __restrict__ w0,
    const unsigned short* __restrict__ vp1, const int* __restrict__ rp1,
    const int* __restrict__ srcOf1, const float* __restrict__ w1, int net,
    int dstOff, int Ndst, unsigned short* __restrict__ aggBase, int ldagg) {
  int g = (blockIdx.x * 256 + threadIdx.x) >> 5;
  int lane = threadIdx.x & 31;
  if (g >= Ndst * H) return;
  int dl = g >> 2, h = g & 3;
  float acc = 0.f;
  {
    int b = rp0[dl], e = rp0[dl + 1];
    for (int i = b; i < e; i++)
      acc += w0[(size_t)i * H + h] *
             bf2f(vp0[(size_t)srcOf0[i] * HID + h * 32 + lane]);
  }
  if (net == 2) {
    int b = rp1[dl], e = rp1[dl + 1];
    for (int i = b; i < e; i++)
      acc += w1[(size_t)i * H + h] *
             bf2f(vp1[(size_t)srcOf1[i] * HID + h * 32 + lane]);
  }
  aggBase[(size_t)(dstOff + dl) * ldagg + h * 32 + lane] = f2bf(acc);
}

__global__ __launch_bounds__(256) void head_kernel(
    const unsigned short* __restrict__ xs0, const float* __restrict__ w_head,
    const float* __restrict__ b_head, const float* __restrict__ basep,
    float* __restrict__ out, int Nrows) {
  int wid = (blockIdx.x * 256 + threadIdx.x) >> 6;
  int lane = threadIdx.x & 63;
  if (wid >= Nrows) return;
  size_t base = (size_t)wid * HID;
  float d = bf2f(xs0[base + lane]) * w_head[lane] +
            bf2f(xs0[base + 64 + lane]) * w_head[64 + lane];
  #pragma unroll
  for (int m = 1; m < 64; m <<= 1) d += __shfl_xor(d, m, 64);
  if (lane == 0) out[wid] = basep[0] + b_head[0] + d;
}

}  // namespace

extern "C" void kernel_launch(void* const* d_in, const int* in_sizes, int n_in,
                              void* d_out, int out_size, void* d_ws,
                              size_t ws_size, hipStream_t stream) {
  const float* x_a = (const float*)d_in[0];
  const float* x_w = (const float*)d_in[1];
  const float* x_o = (const float*)d_in[2];
  const float* W_in = (const float*)d_in[3];
  const float* b_in = (const float*)d_in[4];
  const float* W_kqv = (const float*)d_in[5];
  const float* b_kqv = (const float*)d_in[6];
  const float* a_rel = (const float*)d_in[7];
  const float* m_rel = (const float*)d_in[8];
  const float* p_rel = (const float*)d_in[9];
  const float* skip_p = (const float*)d_in[10];
  const float* W_o = (const float*)d_in[11];
  const float* b_o = (const float*)d_in[12];
  const float* ln_g = (const float*)d_in[13];
  const float* ln_b = (const float*)d_in[14];
  const float* w_head = (const float*)d_in[15];
  const float* b_head = (const float*)d_in[16];
  const float* basep = (const float*)d_in[17];
  const int* srcs[4] = {(const int*)d_in[18], (const int*)d_in[20],
                        (const int*)d_in[22], (const int*)d_in[24]};
  const int* dsts[4] = {(const int*)d_in[19], (const int*)d_in[21],
                        (const int*)d_in[23], (const int*)d_in[25]};
  const int OFF[4] = {0, NA, NA + NW, NTOT};
  const int NT[3] = {NA, NW, NO};
  const float* xin[3] = {x_a, x_w, x_o};

  // ---- workspace layout (~218 MB) ----
  const size_t SZ_XS = (size_t)NTOT * HID * 2;        // bf16 xs        43.5 MB
  const size_t SZ_KQV = (size_t)NTOT * 3 * HID * 2;   // bf16 k|q|v    130.6 MB
  const size_t SZ_AL = (size_t)4 * E * H * 4;         // fp32 alpha->w   9.6 MB
  const size_t SZ_KE = (size_t)NA * HID * 2;          // bf16 k'/v'     25.6 MB
  const size_t SZ_SD = (size_t)4 * E * 4;
  const int RP_TOT = 2 * (NA + 1) + (NW + 1) + (NO + 1);
  const size_t SZ_RP = ((size_t)RP_TOT * 4 + 63) & ~63ull;
  const size_t SZ_CE = (size_t)4 * E * 4;
  const size_t SZ_CU = ((size_t)(NA + 1) * 4 + 63) & ~63ull;
  const size_t SZ_BS = 512 * 4;
  const size_t need = SZ_XS + SZ_KQV + SZ_AL + SZ_KE + 2 * SZ_SD + SZ_RP +
                      SZ_CE + 2 * SZ_CU + SZ_BS;
  if (ws_size < need) return;

  char* p = (char*)d_ws;
  unsigned short* xs = (unsigned short*)p;   p += SZ_XS;
  unsigned short* kqvB = (unsigned short*)p; p += SZ_KQV;
  float* alphaB = (float*)p;                 p += SZ_AL;
  unsigned short* keB = (unsigned short*)p;  p += SZ_KE;
  int* srcOf = (int*)p;                      p += SZ_SD;
  int* dstOf = (int*)p;                      p += SZ_SD;
  int* rpAll = (int*)p;                      p += SZ_RP;
  int* ceAll = (int*)p;                      p += SZ_CE;
  int* cursor = (int*)p;                     p += SZ_CU;
  int* cnt = (int*)p;                        p += SZ_CU;
  int* bsum = (int*)p;

  const int rpOff[4] = {0, NA + 1, 2 * (NA + 1), 2 * (NA + 1) + NW + 1};
  const int NdstE[4] = {NA, NA, NW, NO};
  const int NsrcE[4] = {NW, NO, NA, NA};
  const int srcOffE[4] = {OFF[1], OFF[2], 0, 0};
  const int dstOffE[4] = {0, 0, OFF[1], OFF[2]};
  const int eb = (E + 255) / 256;
  const int LDKQV = 3 * HID;

  // ---- CSR build (once; edges shared by both layers) ----
  for (int et = 0; et < 4; et++) {
    int nd = NdstE[et];
    int* rp = rpAll + rpOff[et];
    int* ce = ceAll + (size_t)et * E;
    hipMemsetAsync(cnt, 0, (size_t)nd * 4, stream);
    csr_hist<<<eb, 256, 0, stream>>>(dsts[et], cnt, E);
    int nb = (nd + 255) / 256;
    scan_block<<<nb, 256, 0, stream>>>(cnt, rp, bsum, nd);
    scan_bsums<<<1, 256, 0, stream>>>(bsum, nb);
    csr_finalize<<<(nd + 256) / 256 + 1, 256, 0, stream>>>(rp, bsum, cursor,
                                                           nd, E);
    csr_scatter<<<eb, 256, 0, stream>>>(dsts[et], cursor, ce, E);
    csr_sort<<<(nd + 255) / 256, 256, 0, stream>>>(rp, ce, nd);
  }
  build_sd<<<(4 * E + 255) / 256, 256, 0, stream>>>(
      ceAll, srcs[0], srcs[1], srcs[2], srcs[3], dsts[0], dsts[1], dsts[2],
      dsts[3], srcOf, dstOf);

  // ---- input projection: xs[t] = relu(x @ W_in[t] + b_in[t]) [MFMA] ----
  for (int t = 0; t < 3; t++) {
    dim3 g((NT[t] + 63) / 64, 2);
    gemm_mfma<2, true, true><<<g, 256, 0, stream>>>(
        xin[t], W_in + (size_t)t * 64 * HID, b_in + t * HID,
        xs + (size_t)OFF[t] * HID, NT[t], 64, HID, HID);
  }

  for (int l = 0; l < 2; l++) {
    const size_t DD = (size_t)H * D * D;
    // fused kqv projection: one 384-col GEMM per node type
    for (int t = 0; t < 3; t++) {
      const float* Wk = W_kqv + (size_t)(l * 3 + t) * HID * 3 * HID;
      const float* bk = b_kqv + (size_t)(l * 3 + t) * 3 * HID;
      dim3 g((NT[t] + 63) / 64, 6);
      gemm_mfma<4, false, false><<<g, 256, 0, stream>>>(
          xs + (size_t)OFF[t] * HID, Wk, bk, kqvB + (size_t)OFF[t] * LDKQV,
          NT[t], HID, LDKQV, LDKQV);
    }
    const float* Al = a_rel + (size_t)l * 4 * DD;
    const float* Ml = m_rel + (size_t)l * 4 * DD;
    const float* Pl = p_rel + (size_t)l * 4 * H;
    // k' = k @ A_rel per et, then slot-parallel alpha
    for (int et = 0; et < 4; et++) {
      rel32<<<((size_t)NsrcE[et] * H * 32 + 255) / 256, 256, 0, stream>>>(
          kqvB, LDKQV, Al + et * DD, keB, srcOffE[et], NsrcE[et]);
      alpha32<<<((size_t)E * H * 32 + 255) / 256, 256, 0, stream>>>(
          keB, kqvB + HID, LDKQV, srcOf + (size_t)et * E,
          dstOf + (size_t)et * E, Pl + et * H, alphaB + (size_t)et * E * H,
          dstOffE[et]);
    }
    // softmax normalize alpha -> w (in place)
    softmax32<<<((size_t)NA * H * 32 + 255) / 256, 256, 0, stream>>>(
        rpAll + rpOff[0], alphaB, rpAll + rpOff[1], alphaB + (size_t)E * H, 2,
        NA);
    softmax32<<<((size_t)NW * H * 32 + 255) / 256, 256, 0, stream>>>(
        rpAll + rpOff[2], alphaB + 2 * (size_t)E * H, nullptr, nullptr, 1, NW);
    softmax32<<<((size_t)NO * H * 32 + 255) / 256, 256, 0, stream>>>(
        rpAll + rpOff[3], alphaB + 3 * (size_t)E * H, nullptr, nullptr, 1, NO);
    // v' = v @ M_rel, then pure-gather agg into the dead q slice
    unsigned short* vP0 = keB;                          // et0: w-src (20k rows)
    unsigned short* vP1 = keB + (size_t)NW * HID;       // et1: o-src (50k rows)
    rel32<<<((size_t)NW * H * 32 + 255) / 256, 256, 0, stream>>>(
        kqvB + 2 * HID, LDKQV, Ml, vP0, OFF[1], NW);
    rel32<<<((size_t)NO * H * 32 + 255) / 256, 256, 0, stream>>>(
        kqvB + 2 * HID, LDKQV, Ml + DD, vP1, OFF[2], NO);
    agg32<<<((size_t)NA * H * 32 + 255) / 256, 256, 0, stream>>>(
        vP0, rpAll + rpOff[0], srcOf, alphaB, vP1, rpAll + rpOff[1], srcOf + E,
        alphaB + (size_t)E * H, 2, 0, NA, kqvB + HID, LDKQV);
    rel32<<<((size_t)NA * H * 32 + 255) / 256, 256, 0, stream>>>(
        kqvB + 2 * HID, LDKQV, Ml + 2 * DD, keB, 0, NA);
    agg32<<<((size_t)NW * H * 32 + 255) / 256, 256, 0, stream>>>(
        keB, rpAll + rpOff[2], srcOf + 2 * (size_t)E,
        alphaB + 2 * (size_t)E * H, nullptr, nullptr, nullptr, nullptr, 1,
        OFF[1], NW, kqvB + HID, LDKQV);
    rel32<<<((size_t)NA * H * 32 + 255) / 256, 256, 0, stream>>>(
        kqvB + 2 * HID, LDKQV, Ml + 3 * DD, keB, 0, NA);
    agg32<<<((size_t)NO * H * 32 + 255) / 256, 256, 0, stream>>>(
        keB, rpAll + rpOff[3], srcOf + 3 * (size_t)E,
        alphaB + 3 * (size_t)E * H, nullptr, nullptr, nullptr, nullptr, 1,
        OFF[2], NO, kqvB + HID, LDKQV);
    // fused: xs = relu(LN(g*(gelu(agg) @ W_o + b_o) + (1-g)*xs)) [MFMA]
    for (int t = 0; t < 3; t++) {
      int blocks = (NT[t] + 63) / 64;
      wo_ln_mfma<<<blocks, 256, 0, stream>>>(
          kqvB + (size_t)OFF[t] * LDKQV + HID, LDKQV,
          W_o + (size_t)(l * 3 + t) * HID * HID,
          b_o + (size_t)(l * 3 + t) * HID, xs + (size_t)OFF[t] * HID,
          skip_p + l * 3 + t, ln_g + (size_t)(l * 3 + t) * HID,
          ln_b + (size_t)(l * 3 + t) * HID, NT[t]);
    }
  }
  head_kernel<<<(NA + 3) / 4, 256, 0, stream>>>(xs, w_head, b_head, basep,
                                                (float*)d_out, NA);
}

// Round 10
// 1941.346 us; speedup vs baseline: 1.1672x; 1.1672x over previous
//
#include <hip/hip_runtime.h>
#include <cstddef>
#include <cmath>

namespace {

constexpr int H = 4, D = 32, HID = 128;
constexpr int NA = 100000, NW = 20000, NO = 50000;
constexpr int NTOT = NA + NW + NO;
constexpr int E = 150000;
constexpr float SCALE = 0.17677669529663687f;  // 1/sqrt(32)
constexpr int LDK = 3 * HID;  // kqv row stride (384)
// keB row layout (k' phase): [k'W 20k][k'O 50k][qA'W 20k][qA'O 50k]
constexpr int KE_ROWS = 140000;

typedef __attribute__((ext_vector_type(8))) short short8v;
typedef __attribute__((ext_vector_type(4))) float f32x4;

__device__ __forceinline__ float gelu_exact(float x) {
  return 0.5f * x * (1.f + erff(x * 0.7071067811865475f));
}
__device__ __forceinline__ unsigned short f2bf(float f) {  // RNE
  unsigned u = __float_as_uint(f);
  return (unsigned short)((u + 0x7FFF + ((u >> 16) & 1)) >> 16);
}
__device__ __forceinline__ float bf2f(unsigned short s) {
  return __uint_as_float(((unsigned)s) << 16);
}

// ---------------- shared 64x64 MFMA tile body ----------------
template <int KSTEPS, bool A_FP32, bool RELU_OUT>
__device__ __forceinline__ void mfma64(
    const void* __restrict__ Av, int lda, const float* __restrict__ W, int ldw,
    const float* __restrict__ bias, unsigned short* __restrict__ C, int ldc,
    int M, int bm, int bn) {
  __shared__ unsigned short As[64][40];
  __shared__ unsigned short Bs[64][40];
  const int tid = threadIdx.x;
  const int wv = tid >> 6;
  const int l = tid & 63;
  f32x4 acc[4] = {};
  const int srow = tid >> 2, sc8 = (tid & 3) * 8;
  for (int ks = 0; ks < KSTEPS; ks++) {
    const int kk = ks * 32;
    {
      int gr = bm + srow;
      if (A_FP32) {
        unsigned short tmp[8] = {};
        if (gr < M) {
          const float* src = (const float*)Av + (size_t)gr * lda + kk + sc8;
          float4 f0 = *(const float4*)src;
          float4 f1 = *(const float4*)(src + 4);
          tmp[0] = f2bf(f0.x); tmp[1] = f2bf(f0.y);
          tmp[2] = f2bf(f0.z); tmp[3] = f2bf(f0.w);
          tmp[4] = f2bf(f1.x); tmp[5] = f2bf(f1.y);
          tmp[6] = f2bf(f1.z); tmp[7] = f2bf(f1.w);
        }
        *(uint4*)&As[srow][sc8] = *(const uint4*)tmp;
      } else {
        uint4 v = {0, 0, 0, 0};
        if (gr < M)
          v = *(const uint4*)((const unsigned short*)Av + (size_t)gr * lda +
                              kk + sc8);
        *(uint4*)&As[srow][sc8] = v;
      }
    }
    #pragma unroll
    for (int i = 0; i < 8; i++) {
      int idx = tid + i * 256;
      int r = idx >> 6, c = idx & 63;
      Bs[c][r] = f2bf(W[(size_t)(kk + r) * ldw + bn + c]);
    }
    __syncthreads();
    const int arow = wv * 16 + (l & 15);
    const int k8 = (l >> 4) * 8;
    short8v af = *(const short8v*)&As[arow][k8];
    #pragma unroll
    for (int n = 0; n < 4; n++) {
      short8v bf = *(const short8v*)&Bs[n * 16 + (l & 15)][k8];
      acc[n] = __builtin_amdgcn_mfma_f32_16x16x32_bf16(af, bf, acc[n], 0, 0, 0);
    }
    __syncthreads();
  }
  #pragma unroll
  for (int n = 0; n < 4; n++) {
    int col = bn + n * 16 + (l & 15);
    float bb = bias[col];
    #pragma unroll
    for (int j = 0; j < 4; j++) {
      int row = bm + wv * 16 + (l >> 4) * 4 + j;
      if (row < M) {
        float o = acc[n][j] + bb;
        if (RELU_OUT) o = fmaxf(o, 0.f);
        C[(size_t)row * ldc + col] = f2bf(o);
      }
    }
  }
}

__device__ __forceinline__ int btype(int bx, int nb0, int nb01) {
  return bx < nb0 ? 0 : (bx < nb01 ? 1 : 2);
}

// input proj (fused over 3 node types): xs = relu(x @ W_in[t] + b_in[t])
__global__ __launch_bounds__(256) void in_fused(
    const float* __restrict__ xa, const float* __restrict__ xw,
    const float* __restrict__ xo, const float* __restrict__ W_in,
    const float* __restrict__ b_in, unsigned short* __restrict__ xs, int nb0,
    int nb01) {
  int t = btype(blockIdx.x, nb0, nb01);
  int base = t == 0 ? 0 : (t == 1 ? nb0 : nb01);
  int M = t == 0 ? NA : (t == 1 ? NW : NO);
  int off = t == 0 ? 0 : (t == 1 ? NA : NA + NW);
  const float* A = t == 0 ? xa : (t == 1 ? xw : xo);
  mfma64<2, true, true>(A, 64, W_in + (size_t)t * 64 * HID, HID,
                        b_in + t * HID, xs + (size_t)off * HID, HID, M,
                        (blockIdx.x - base) * 64, blockIdx.y * 64);
}

// kqv proj (fused): kqv = xs @ W_kqv[l,t] + b
__global__ __launch_bounds__(256) void kqv_fused(
    const unsigned short* __restrict__ xs, const float* __restrict__ Wl,
    const float* __restrict__ bl, unsigned short* __restrict__ kqvB, int nb0,
    int nb01) {
  int t = btype(blockIdx.x, nb0, nb01);
  int base = t == 0 ? 0 : (t == 1 ? nb0 : nb01);
  int M = t == 0 ? NA : (t == 1 ? NW : NO);
  int off = t == 0 ? 0 : (t == 1 ? NA : NA + NW);
  mfma64<4, false, false>(xs + (size_t)off * HID, HID,
                          Wl + (size_t)t * HID * LDK, LDK, bl + t * LDK,
                          kqvB + (size_t)off * LDK, LDK, M,
                          (blockIdx.x - base) * 64, blockIdx.y * 64);
}

// fused: xs = relu(LN( g*(gelu(agg) @ W_o + b_o) + (1-g)*xs ))  [64x128 tile]
__global__ __launch_bounds__(256) void wo_ln_fused(
    const unsigned short* __restrict__ kqvB, const float* __restrict__ Wl,
    const float* __restrict__ bl, unsigned short* __restrict__ xs,
    const float* __restrict__ skipl, const float* __restrict__ gll,
    const float* __restrict__ bll, int nb0, int nb01) {
  __shared__ unsigned short As[64][40];
  __shared__ unsigned short Bs[128][40];
  int t = btype(blockIdx.x, nb0, nb01);
  int base = t == 0 ? 0 : (t == 1 ? nb0 : nb01);
  int M = t == 0 ? NA : (t == 1 ? NW : NO);
  int off = t == 0 ? 0 : (t == 1 ? NA : NA + NW);
  const unsigned short* A = kqvB + (size_t)off * LDK + HID;  // agg in q slice
  const float* W = Wl + (size_t)t * HID * HID;
  const float* bias = bl + t * HID;
  const float* gln = gll + t * HID;
  const float* bln = bll + t * HID;
  unsigned short* xsT = xs + (size_t)off * HID;
  const int bm = (blockIdx.x - base) * 64;
  const int tid = threadIdx.x;
  const int wv = tid >> 6;
  const int l = tid & 63;
  f32x4 acc[8] = {};
  const int srow = tid >> 2, sc8 = (tid & 3) * 8;
  for (int ks = 0; ks < 4; ks++) {
    const int kk = ks * 32;
    {
      int gr = bm + srow;
      uint4 v = {0, 0, 0, 0};
      if (gr < M) v = *(const uint4*)(A + (size_t)gr * LDK + kk + sc8);
      unsigned w4[4] = {v.x, v.y, v.z, v.w};
      unsigned short tmp[8];
      #pragma unroll
      for (int j = 0; j < 4; j++) {
        tmp[j * 2 + 0] = f2bf(gelu_exact(bf2f((unsigned short)(w4[j] & 0xFFFF))));
        tmp[j * 2 + 1] = f2bf(gelu_exact(bf2f((unsigned short)(w4[j] >> 16))));
      }
      *(uint4*)&As[srow][sc8] = *(const uint4*)tmp;
    }
    #pragma unroll
    for (int i = 0; i < 16; i++) {
      int idx = tid + i * 256;
      int r = idx >> 7, c = idx & 127;
      Bs[c][r] = f2bf(W[(size_t)(kk + r) * HID + c]);
    }
    __syncthreads();
    const int arow = wv * 16 + (l & 15);
    const int k8 = (l >> 4) * 8;
    short8v af = *(const short8v*)&As[arow][k8];
    #pragma unroll
    for (int n = 0; n < 8; n++) {
      short8v bf = *(const short8v*)&Bs[n * 16 + (l & 15)][k8];
      acc[n] = __builtin_amdgcn_mfma_f32_16x16x32_bf16(af, bf, acc[n], 0, 0, 0);
    }
    __syncthreads();
  }
  const float g = 1.f / (1.f + expf(-skipl[t]));
  float bb[8], gl8[8], bl8[8];
  #pragma unroll
  for (int n = 0; n < 8; n++) {
    int col = n * 16 + (l & 15);
    bb[n] = bias[col];
    gl8[n] = gln[col];
    bl8[n] = bln[col];
  }
  #pragma unroll
  for (int j = 0; j < 4; j++) {
    int row = bm + wv * 16 + (l >> 4) * 4 + j;
    bool ok = row < M;
    float vv[8], sum = 0.f, sq = 0.f;
    #pragma unroll
    for (int n = 0; n < 8; n++) {
      int col = n * 16 + (l & 15);
      float xo = ok ? bf2f(xsT[(size_t)row * HID + col]) : 0.f;
      float val = g * (acc[n][j] + bb[n]) + (1.f - g) * xo;
      vv[n] = val;
      sum += val;
      sq += val * val;
    }
    #pragma unroll
    for (int m = 1; m < 16; m <<= 1) {
      sum += __shfl_xor(sum, m, 64);
      sq += __shfl_xor(sq, m, 64);
    }
    float mu = sum * (1.f / 128.f);
    float var = sq * (1.f / 128.f) - mu * mu;
    float r = rsqrtf(var + 1e-5f);
    if (ok) {
      #pragma unroll
      for (int n = 0; n < 8; n++) {
        float y = fmaxf((vv[n] - mu) * r * gl8[n] + bl8[n], 0.f);
        xsT[(size_t)row * HID + n * 16 + (l & 15)] = f2bf(y);
      }
    }
  }
}

// ---------------- CSR build (deterministic, 4 ets fused) ----------------
// cnt/cursor layout: [et0:NA][et1:NA][et2:NW][et3:NO]; rpOff per et.
__global__ __launch_bounds__(256) void csr_hist4(
    const int* __restrict__ d0, const int* __restrict__ d1,
    const int* __restrict__ d2, const int* __restrict__ d3,
    int* __restrict__ cnt) {
  int t = blockIdx.x * 256 + threadIdx.x;
  if (t >= 4 * E) return;
  int et = t / E, e = t - et * E;
  const int* dp = et == 0 ? d0 : et == 1 ? d1 : et == 2 ? d2 : d3;
  int base = et == 0 ? 0 : et == 1 ? NA : et == 2 ? 2 * NA : 2 * NA + NW;
  atomicAdd(&cnt[base + dp[e]], 1);
}

__global__ __launch_bounds__(256) void scan_block(const int* __restrict__ cnt,
                                                  int* __restrict__ excl,
                                                  int* __restrict__ bsum,
                                                  int n) {
  __shared__ int tmp[256];
  int i = blockIdx.x * 256 + threadIdx.x;
  int v = (i < n) ? cnt[i] : 0;
  tmp[threadIdx.x] = v;
  __syncthreads();
  int acc = v;
  for (int off = 1; off < 256; off <<= 1) {
    int other = (threadIdx.x >= off) ? tmp[threadIdx.x - off] : 0;
    __syncthreads();
    acc += other;
    tmp[threadIdx.x] = acc;
    __syncthreads();
  }
  if (i < n) excl[i] = acc - v;
  if (threadIdx.x == 255) bsum[blockIdx.x] = acc;
}

__global__ __launch_bounds__(256) void scan_bsums(int* __restrict__ bsum,
                                                  int nb) {
  __shared__ int tmp[256];
  __shared__ int carry;
  if (threadIdx.x == 0) carry = 0;
  __syncthreads();
  for (int start = 0; start < nb; start += 256) {
    int i = start + threadIdx.x;
    int v = (i < nb) ? bsum[i] : 0;
    tmp[threadIdx.x] = v;
    __syncthreads();
    int acc = v;
    for (int off = 1; off < 256; off <<= 1) {
      int other = (threadIdx.x >= off) ? tmp[threadIdx.x - off] : 0;
      __syncthreads();
      acc += other;
      tmp[threadIdx.x] = acc;
      __syncthreads();
    }
    int c = carry;
    if (i < nb) bsum[i] = c + acc - v;
    __syncthreads();
    if (threadIdx.x == 255) carry = c + acc;
    __syncthreads();
  }
}

__device__ __forceinline__ void et_of_node(int i, int& et, int& base, int& nd,
                                           int& rpo) {
  if (i < NA) { et = 0; base = 0; nd = NA; rpo = 0; }
  else if (i < 2 * NA) { et = 1; base = NA; nd = NA; rpo = NA + 1; }
  else if (i < 2 * NA + NW) { et = 2; base = 2 * NA; nd = NW; rpo = 2 * (NA + 1); }
  else { et = 3; base = 2 * NA + NW; nd = NO; rpo = 2 * (NA + 1) + NW + 1; }
}

__global__ __launch_bounds__(256) void csr_finalize4(
    int* __restrict__ rpAll, const int* __restrict__ bsum,
    int* __restrict__ cursor) {
  int i = blockIdx.x * 256 + threadIdx.x;
  if (i >= 2 * NA + NW + NO) return;
  int et, base, nd, rpo;
  et_of_node(i, et, base, nd, rpo);
  int local = i - base;
  int v = rpAll[rpo + local] + bsum[et * 512 + (local >> 8)];
  rpAll[rpo + local] = v;
  cursor[base + local] = v;
  if (local == 0) rpAll[rpo + nd] = E;
}

__global__ __launch_bounds__(256) void csr_scatter4(
    const int* __restrict__ d0, const int* __restrict__ d1,
    const int* __restrict__ d2, const int* __restrict__ d3,
    int* __restrict__ cursor, int* __restrict__ ceAll) {
  int t = blockIdx.x * 256 + threadIdx.x;
  if (t >= 4 * E) return;
  int et = t / E, e = t - et * E;
  const int* dp = et == 0 ? d0 : et == 1 ? d1 : et == 2 ? d2 : d3;
  int base = et == 0 ? 0 : et == 1 ? NA : et == 2 ? 2 * NA : 2 * NA + NW;
  int slot = atomicAdd(&cursor[base + dp[e]], 1);
  ceAll[(size_t)et * E + slot] = e;
}

__global__ __launch_bounds__(256) void csr_sort4(const int* __restrict__ rpAll,
                                                 int* __restrict__ ceAll) {
  int i = blockIdx.x * 256 + threadIdx.x;
  if (i >= 2 * NA + NW + NO) return;
  int et, base, nd, rpo;
  et_of_node(i, et, base, nd, rpo);
  int local = i - base;
  int b = rpAll[rpo + local], e = rpAll[rpo + local + 1];
  int* ce = ceAll + (size_t)et * E;
  for (int k = b + 1; k < e; k++) {
    int key = ce[k];
    int j = k - 1;
    while (j >= b && ce[j] > key) { ce[j + 1] = ce[j]; j--; }
    ce[j + 1] = key;
  }
}

__global__ __launch_bounds__(256) void build_sd(
    const int* __restrict__ ce, const int* __restrict__ s0,
    const int* __restrict__ s1, const int* __restrict__ s2,
    const int* __restrict__ s3, const int* __restrict__ d0,
    const int* __restrict__ d1, const int* __restrict__ d2,
    const int* __restrict__ d3, int* __restrict__ srcOf,
    int* __restrict__ dstOf) {
  int t = blockIdx.x * 256 + threadIdx.x;
  if (t >= 4 * E) return;
  int et = t / E;
  int e = ce[t];
  const int* sp = et == 0 ? s0 : et == 1 ? s1 : et == 2 ? s2 : s3;
  const int* dp = et == 0 ? d0 : et == 1 ? d1 : et == 2 ? d2 : d3;
  srcOf[t] = sp[e];
  dstOf[t] = dp[e];
}

// ---------------- attention ----------------
// k-phase transforms (one dispatch): rows 0-70k = k' (et0 W-src, et1 O-src);
// rows 70k-140k = qA' (et2 W-dst, et3 O-dst; transposed apply).
__global__ __launch_bounds__(256) void rel_k_fused(
    const unsigned short* __restrict__ kqv, const float* __restrict__ Al,
    unsigned short* __restrict__ ke) {
  int g = (blockIdx.x * 256 + threadIdx.x) >> 5;
  int lane = threadIdx.x & 31;
  if (g >= KE_ROWS * H) return;
  int r = g >> 2, h = g & 3;
  int srcRow, slice, et;
  bool tr;
  if (r < 20000) { et = 0; srcRow = NA + r; slice = 0; tr = false; }
  else if (r < 70000) { et = 1; srcRow = NA + NW + (r - 20000); slice = 0; tr = false; }
  else if (r < 90000) { et = 2; srcRow = NA + (r - 70000); slice = HID; tr = true; }
  else { et = 3; srcRow = NA + NW + (r - 90000); slice = HID; tr = true; }
  float x = bf2f(kqv[(size_t)srcRow * LDK + slice + h * 32 + lane]);
  const float* T = Al + ((size_t)et * H + h) * D * D;
  float o = 0.f;
  if (!tr) {
    #pragma unroll 8
    for (int d = 0; d < 32; d++) o += __shfl(x, d, 32) * T[d * 32 + lane];
  } else {
    #pragma unroll 8
    for (int d = 0; d < 32; d++) o += __shfl(x, d, 32) * T[lane * 32 + d];
  }
  ke[(size_t)r * HID + h * 32 + lane] = f2bf(o);
}

// v-phase transforms: rows 0-20k = v'W (M0), 20k-70k = v'O (M1).
__global__ __launch_bounds__(256) void rel_v_fused(
    const unsigned short* __restrict__ kqv, const float* __restrict__ Ml,
    unsigned short* __restrict__ vp) {
  int g = (blockIdx.x * 256 + threadIdx.x) >> 5;
  int lane = threadIdx.x & 31;
  if (g >= 70000 * H) return;
  int r = g >> 2, h = g & 3;
  int srcRow, et;
  if (r < 20000) { et = 0; srcRow = NA + r; }
  else { et = 1; srcRow = NA + NW + (r - 20000); }
  float x = bf2f(kqv[(size_t)srcRow * LDK + 2 * HID + h * 32 + lane]);
  const float* T = Ml + ((size_t)et * H + h) * D * D;
  float o = 0.f;
  #pragma unroll 8
  for (int d = 0; d < 32; d++) o += __shfl(x, d, 32) * T[d * 32 + lane];
  vp[(size_t)r * HID + h * 32 + lane] = f2bf(o);
}

// all-edge alpha (one dispatch over 4E slots)
__global__ __launch_bounds__(256) void alpha_fused(
    const unsigned short* __restrict__ kqv, const unsigned short* __restrict__ ke,
    const int* __restrict__ srcOf, const int* __restrict__ dstOf,
    const float* __restrict__ Pl, float* __restrict__ alphaB) {
  int g = (blockIdx.x * 256 + threadIdx.x) >> 5;
  int lane = threadIdx.x & 31;
  if (g >= 4 * E * H) return;
  int i = g >> 2, h = g & 3;
  int et = i / E;
  int s_ = srcOf[i], d_ = dstOf[i];
  float a, b;
  if (et == 0) {
    a = bf2f(kqv[(size_t)d_ * LDK + HID + h * 32 + lane]);
    b = bf2f(ke[(size_t)s_ * HID + h * 32 + lane]);
  } else if (et == 1) {
    a = bf2f(kqv[(size_t)d_ * LDK + HID + h * 32 + lane]);
    b = bf2f(ke[(size_t)(20000 + s_) * HID + h * 32 + lane]);
  } else if (et == 2) {
    a = bf2f(ke[(size_t)(70000 + d_) * HID + h * 32 + lane]);
    b = bf2f(kqv[(size_t)s_ * LDK + h * 32 + lane]);
  } else {
    a = bf2f(ke[(size_t)(90000 + d_) * HID + h * 32 + lane]);
    b = bf2f(kqv[(size_t)s_ * LDK + h * 32 + lane]);
  }
  float pv = a * b;
  #pragma unroll
  for (int m = 1; m < 32; m <<= 1) pv += __shfl_xor(pv, m, 32);
  if (lane == 0) alphaB[(size_t)i * H + h] = pv * Pl[et * H + h] * SCALE;
}

// all-dst softmax normalize (in place alpha -> w)
__global__ __launch_bounds__(256) void softmax_fused(
    const int* __restrict__ rpAll, float* __restrict__ alphaB) {
  int g = (blockIdx.x * 256 + threadIdx.x) >> 5;
  int lane = threadIdx.x & 31;
  if (g >= NTOT * H) return;
  int dl = g >> 2, h = g & 3;
  int b0, e0, b1 = 0, e1 = 0;
  size_t o0;
  const size_t EH = (size_t)E * H;
  if (dl < NA) {
    b0 = rpAll[dl]; e0 = rpAll[dl + 1];
    b1 = rpAll[(NA + 1) + dl]; e1 = rpAll[(NA + 1) + dl + 1];
    o0 = 0;
  } else if (dl < NA + NW) {
    int x = dl - NA;
    b0 = rpAll[2 * (NA + 1) + x]; e0 = rpAll[2 * (NA + 1) + x + 1];
    o0 = 2 * EH;
  } else {
    int x = dl - NA - NW;
    b0 = rpAll[2 * (NA + 1) + (NW + 1) + x];
    e0 = rpAll[2 * (NA + 1) + (NW + 1) + x + 1];
    o0 = 3 * EH;
  }
  float mx = -INFINITY;
  for (int i = b0 + lane; i < e0; i += 32)
    mx = fmaxf(mx, alphaB[o0 + (size_t)i * H + h]);
  for (int i = b1 + lane; i < e1; i += 32)
    mx = fmaxf(mx, alphaB[EH + (size_t)i * H + h]);
  #pragma unroll
  for (int m = 1; m < 32; m <<= 1) mx = fmaxf(mx, __shfl_xor(mx, m, 32));
  float den = 0.f;
  for (int i = b0 + lane; i < e0; i += 32)
    den += expf(alphaB[o0 + (size_t)i * H + h] - mx);
  for (int i = b1 + lane; i < e1; i += 32)
    den += expf(alphaB[EH + (size_t)i * H + h] - mx);
  #pragma unroll
  for (int m = 1; m < 32; m <<= 1) den += __shfl_xor(den, m, 32);
  float inv = 1.f / (den + 1e-16f);
  for (int i = b0 + lane; i < e0; i += 32)
    alphaB[o0 + (size_t)i * H + h] = expf(alphaB[o0 + (size_t)i * H + h] - mx) * inv;
  for (int i = b1 + lane; i < e1; i += 32)
    alphaB[EH + (size_t)i * H + h] = expf(alphaB[EH + (size_t)i * H + h] - mx) * inv;
}

// all-dst aggregation: A-dst pure v' gather; W/O-dst raw-v gather + M shfl.
__global__ __launch_bounds__(256) void agg_fused(
    const unsigned short* __restrict__ kqv, const unsigned short* __restrict__ vp,
    const int* __restrict__ rpAll, const int* __restrict__ srcOf,
    const float* __restrict__ alphaB, const float* __restrict__ Ml,
    unsigned short* __restrict__ out) {
  int g = (blockIdx.x * 256 + threadIdx.x) >> 5;
  int lane = threadIdx.x & 31;
  if (g >= NTOT * H) return;
  int dl = g >> 2, h = g & 3;
  const size_t EH = (size_t)E * H;
  float acc;
  if (dl < NA) {
    acc = 0.f;
    int b = rpAll[dl], e = rpAll[dl + 1];
    for (int i = b; i < e; i++)
      acc += alphaB[(size_t)i * H + h] *
             bf2f(vp[(size_t)srcOf[i] * HID + h * 32 + lane]);
    b = rpAll[(NA + 1) + dl]; e = rpAll[(NA + 1) + dl + 1];
    for (int i = b; i < e; i++)
      acc += alphaB[EH + (size_t)i * H + h] *
             bf2f(vp[(size_t)(20000 + srcOf[(size_t)E + i]) * HID + h * 32 + lane]);
  } else {
    int et, x, rpo;
    if (dl < NA + NW) { et = 2; x = dl - NA; rpo = 2 * (NA + 1); }
    else { et = 3; x = dl - NA - NW; rpo = 2 * (NA + 1) + (NW + 1); }
    int b = rpAll[rpo + x], e = rpAll[rpo + x + 1];
    const float* al = alphaB + (size_t)et * EH;
    const int* so = srcOf + (size_t)et * E;
    float sv = 0.f;
    for (int i = b; i < e; i++)
      sv += al[(size_t)i * H + h] *
            bf2f(kqv[(size_t)so[i] * LDK + 2 * HID + h * 32 + lane]);
    const float* Mm = Ml + ((size_t)et * H + h) * D * D;
    acc = 0.f;
    #pragma unroll 8
    for (int d = 0; d < 32; d++) acc += __shfl(sv, d, 32) * Mm[d * 32 + lane];
  }
  out[(size_t)dl * LDK + HID + h * 32 + lane] = f2bf(acc);
}

__global__ __launch_bounds__(256) void head_kernel(
    const unsigned short* __restrict__ xs0, const float* __restrict__ w_head,
    const float* __restrict__ b_head, const float* __restrict__ basep,
    float* __restrict__ out, int Nrows) {
  int wid = (blockIdx.x * 256 + threadIdx.x) >> 6;
  int lane = threadIdx.x & 63;
  if (wid >= Nrows) return;
  size_t base = (size_t)wid * HID;
  float d = bf2f(xs0[base + lane]) * w_head[lane] +
            bf2f(xs0[base + 64 + lane]) * w_head[64 + lane];
  #pragma unroll
  for (int m = 1; m < 64; m <<= 1) d += __shfl_xor(d, m, 64);
  if (lane == 0) out[wid] = basep[0] + b_head[0] + d;
}

}  // namespace

extern "C" void kernel_launch(void* const* d_in, const int* in_sizes, int n_in,
                              void* d_out, int out_size, void* d_ws,
                              size_t ws_size, hipStream_t stream) {
  const float* x_a = (const float*)d_in[0];
  const float* x_w = (const float*)d_in[1];
  const float* x_o = (const float*)d_in[2];
  const float* W_in = (const float*)d_in[3];
  const float* b_in = (const float*)d_in[4];
  const float* W_kqv = (const float*)d_in[5];
  const float* b_kqv = (const float*)d_in[6];
  const float* a_rel = (const float*)d_in[7];
  const float* m_rel = (const float*)d_in[8];
  const float* p_rel = (const float*)d_in[9];
  const float* skip_p = (const float*)d_in[10];
  const float* W_o = (const float*)d_in[11];
  const float* b_o = (const float*)d_in[12];
  const float* ln_g = (const float*)d_in[13];
  const float* ln_b = (const float*)d_in[14];
  const float* w_head = (const float*)d_in[15];
  const float* b_head = (const float*)d_in[16];
  const float* basep = (const float*)d_in[17];
  const int* srcs[4] = {(const int*)d_in[18], (const int*)d_in[20],
                        (const int*)d_in[22], (const int*)d_in[24]};
  const int* dsts[4] = {(const int*)d_in[19], (const int*)d_in[21],
                        (const int*)d_in[23], (const int*)d_in[25]};

  // ---- workspace layout (~230 MB) ----
  const size_t SZ_XS = (size_t)NTOT * HID * 2;        // bf16 xs        43.5 MB
  const size_t SZ_KQV = (size_t)NTOT * LDK * 2;       // bf16 k|q|v    130.6 MB
  const size_t SZ_AL = (size_t)4 * E * H * 4;         // fp32 w          9.6 MB
  const size_t SZ_KE = (size_t)KE_ROWS * HID * 2;     // k'/qA' -> v'   35.8 MB
  const size_t SZ_SD = (size_t)4 * E * 4;
  const int CNT_TOT = 2 * NA + NW + NO;               // 270000
  const int RP_TOT = 2 * (NA + 1) + (NW + 1) + (NO + 1);
  const size_t SZ_RP = ((size_t)RP_TOT * 4 + 63) & ~63ull;
  const size_t SZ_CE = (size_t)4 * E * 4;
  const size_t SZ_CU = ((size_t)CNT_TOT * 4 + 63) & ~63ull;
  const size_t SZ_BS = 4 * 512 * 4;
  const size_t need = SZ_XS + SZ_KQV + SZ_AL + SZ_KE + 2 * SZ_SD + SZ_RP +
                      SZ_CE + 2 * SZ_CU + SZ_BS;
  if (ws_size < need) return;

  char* p = (char*)d_ws;
  unsigned short* xs = (unsigned short*)p;   p += SZ_XS;
  unsigned short* kqvB = (unsigned short*)p; p += SZ_KQV;
  float* alphaB = (float*)p;                 p += SZ_AL;
  unsigned short* keB = (unsigned short*)p;  p += SZ_KE;
  int* srcOf = (int*)p;                      p += SZ_SD;
  int* dstOf = (int*)p;                      p += SZ_SD;
  int* rpAll = (int*)p;                      p += SZ_RP;
  int* ceAll = (int*)p;                      p += SZ_CE;
  int* cursor = (int*)p;                     p += SZ_CU;
  int* cnt = (int*)p;                        p += SZ_CU;
  int* bsum = (int*)p;

  const int rpOff[4] = {0, NA + 1, 2 * (NA + 1), 2 * (NA + 1) + NW + 1};
  const int cntBase[4] = {0, NA, 2 * NA, 2 * NA + NW};
  const int ndE[4] = {NA, NA, NW, NO};
  const int e4b = (4 * E + 255) / 256;
  const int nb0 = (NA + 63) / 64, nb01 = nb0 + (NW + 63) / 64;
  const int nbTot = nb01 + (NO + 63) / 64;

  // ---- CSR build (once) ----
  hipMemsetAsync(cnt, 0, (size_t)CNT_TOT * 4, stream);
  csr_hist4<<<e4b, 256, 0, stream>>>(dsts[0], dsts[1], dsts[2], dsts[3], cnt);
  for (int et = 0; et < 4; et++) {
    int nb = (ndE[et] + 255) / 256;
    scan_block<<<nb, 256, 0, stream>>>(cnt + cntBase[et], rpAll + rpOff[et],
                                       bsum + et * 512, ndE[et]);
    scan_bsums<<<1, 256, 0, stream>>>(bsum + et * 512, nb);
  }
  csr_finalize4<<<(CNT_TOT + 255) / 256, 256, 0, stream>>>(rpAll, bsum, cursor);
  csr_scatter4<<<e4b, 256, 0, stream>>>(dsts[0], dsts[1], dsts[2], dsts[3],
                                        cursor, ceAll);
  csr_sort4<<<(CNT_TOT + 255) / 256, 256, 0, stream>>>(rpAll, ceAll);
  build_sd<<<e4b, 256, 0, stream>>>(ceAll, srcs[0], srcs[1], srcs[2], srcs[3],
                                    dsts[0], dsts[1], dsts[2], dsts[3], srcOf,
                                    dstOf);

  // ---- input projection ----
  in_fused<<<dim3(nbTot, 2), 256, 0, stream>>>(x_a, x_w, x_o, W_in, b_in, xs,
                                               nb0, nb01);

  const size_t DD = (size_t)H * D * D;
  for (int l = 0; l < 2; l++) {
    kqv_fused<<<dim3(nbTot, 6), 256, 0, stream>>>(
        xs, W_kqv + (size_t)l * 3 * HID * LDK, b_kqv + (size_t)l * 3 * LDK,
        kqvB, nb0, nb01);
    const float* Al = a_rel + (size_t)l * 4 * DD;
    const float* Ml = m_rel + (size_t)l * 4 * DD;
    const float* Pl = p_rel + (size_t)l * 4 * H;
    rel_k_fused<<<((size_t)KE_ROWS * H * 32 + 255) / 256, 256, 0, stream>>>(
        kqvB, Al, keB);
    alpha_fused<<<((size_t)4 * E * H * 32 + 255) / 256, 256, 0, stream>>>(
        kqvB, keB, srcOf, dstOf, Pl, alphaB);
    softmax_fused<<<((size_t)NTOT * H * 32 + 255) / 256, 256, 0, stream>>>(
        rpAll, alphaB);
    rel_v_fused<<<((size_t)70000 * H * 32 + 255) / 256, 256, 0, stream>>>(
        kqvB, Ml, keB);
    agg_fused<<<((size_t)NTOT * H * 32 + 255) / 256, 256, 0, stream>>>(
        kqvB, keB, rpAll, srcOf, alphaB, Ml, kqvB);
    wo_ln_fused<<<nbTot, 256, 0, stream>>>(
        kqvB, W_o + (size_t)l * 3 * HID * HID, b_o + (size_t)l * 3 * HID, xs,
        skip_p + l * 3, ln_g + (size_t)l * 3 * HID, ln_b + (size_t)l * 3 * HID,
        nb0, nb01);
  }
  head_kernel<<<(NA + 3) / 4, 256, 0, stream>>>(xs, w_head, b_head, basep,
                                                (float*)d_out, NA);
}

// Round 11
// 1277.038 us; speedup vs baseline: 1.7744x; 1.5202x over previous
//
#include <hip/hip_runtime.h>
#include <cstddef>
#include <cmath>

namespace {

constexpr int H = 4, D = 32, HID = 128;
constexpr int NA = 100000, NW = 20000, NO = 50000;
constexpr int NTOT = NA + NW + NO;
constexpr int E = 150000;
constexpr float SCALE = 0.17677669529663687f;  // 1/sqrt(32)
constexpr int LDK = 3 * HID;  // kqv row stride (384)

typedef __attribute__((ext_vector_type(8))) short short8v;
typedef __attribute__((ext_vector_type(4))) float f32x4;

__device__ __forceinline__ float gelu_exact(float x) {
  return 0.5f * x * (1.f + erff(x * 0.7071067811865475f));
}
__device__ __forceinline__ unsigned short f2bf(float f) {  // RNE
  unsigned u = __float_as_uint(f);
  return (unsigned short)((u + 0x7FFF + ((u >> 16) & 1)) >> 16);
}
__device__ __forceinline__ float bf2f(unsigned short s) {
  return __uint_as_float(((unsigned)s) << 16);
}

__device__ __forceinline__ int btype(int bx, int nb0, int nb01) {
  return bx < nb0 ? 0 : (bx < nb01 ? 1 : 2);
}

// ---------------- 64x64 MFMA tile (input projection) ----------------
template <int KSTEPS, bool A_FP32, bool RELU_OUT>
__device__ __forceinline__ void mfma64(
    const void* __restrict__ Av, int lda, const float* __restrict__ W, int ldw,
    const float* __restrict__ bias, unsigned short* __restrict__ C, int ldc,
    int M, int bm, int bn) {
  __shared__ unsigned short As[64][40];
  __shared__ unsigned short Bs[64][40];
  const int tid = threadIdx.x;
  const int wv = tid >> 6;
  const int l = tid & 63;
  f32x4 acc[4] = {};
  const int srow = tid >> 2, sc8 = (tid & 3) * 8;
  for (int ks = 0; ks < KSTEPS; ks++) {
    const int kk = ks * 32;
    {
      int gr = bm + srow;
      if (A_FP32) {
        unsigned short tmp[8] = {};
        if (gr < M) {
          const float* src = (const float*)Av + (size_t)gr * lda + kk + sc8;
          float4 f0 = *(const float4*)src;
          float4 f1 = *(const float4*)(src + 4);
          tmp[0] = f2bf(f0.x); tmp[1] = f2bf(f0.y);
          tmp[2] = f2bf(f0.z); tmp[3] = f2bf(f0.w);
          tmp[4] = f2bf(f1.x); tmp[5] = f2bf(f1.y);
          tmp[6] = f2bf(f1.z); tmp[7] = f2bf(f1.w);
        }
        *(uint4*)&As[srow][sc8] = *(const uint4*)tmp;
      } else {
        uint4 v = {0, 0, 0, 0};
        if (gr < M)
          v = *(const uint4*)((const unsigned short*)Av + (size_t)gr * lda +
                              kk + sc8);
        *(uint4*)&As[srow][sc8] = v;
      }
    }
    #pragma unroll
    for (int i = 0; i < 8; i++) {
      int idx = tid + i * 256;
      int r = idx >> 6, c = idx & 63;
      Bs[c][r] = f2bf(W[(size_t)(kk + r) * ldw + bn + c]);
    }
    __syncthreads();
    const int arow = wv * 16 + (l & 15);
    const int k8 = (l >> 4) * 8;
    short8v af = *(const short8v*)&As[arow][k8];
    #pragma unroll
    for (int n = 0; n < 4; n++) {
      short8v bf = *(const short8v*)&Bs[n * 16 + (l & 15)][k8];
      acc[n] = __builtin_amdgcn_mfma_f32_16x16x32_bf16(af, bf, acc[n], 0, 0, 0);
    }
    __syncthreads();
  }
  #pragma unroll
  for (int n = 0; n < 4; n++) {
    int col = bn + n * 16 + (l & 15);
    float bb = bias[col];
    #pragma unroll
    for (int j = 0; j < 4; j++) {
      int row = bm + wv * 16 + (l >> 4) * 4 + j;
      if (row < M) {
        float o = acc[n][j] + bb;
        if (RELU_OUT) o = fmaxf(o, 0.f);
        C[(size_t)row * ldc + col] = f2bf(o);
      }
    }
  }
}

// input proj (fused over 3 node types): xs = relu(x @ W_in[t] + b_in[t])
__global__ __launch_bounds__(256) void in_fused(
    const float* __restrict__ xa, const float* __restrict__ xw,
    const float* __restrict__ xo, const float* __restrict__ W_in,
    const float* __restrict__ b_in, unsigned short* __restrict__ xs, int nb0,
    int nb01) {
  int t = btype(blockIdx.x, nb0, nb01);
  int base = t == 0 ? 0 : (t == 1 ? nb0 : nb01);
  int M = t == 0 ? NA : (t == 1 ? NW : NO);
  int off = t == 0 ? 0 : (t == 1 ? NA : NA + NW);
  const float* A = t == 0 ? xa : (t == 1 ? xw : xo);
  mfma64<2, true, true>(A, 64, W_in + (size_t)t * 64 * HID, HID,
                        b_in + t * HID, xs + (size_t)off * HID, HID, M,
                        (blockIdx.x - base) * 64, blockIdx.y * 64);
}

// ---------------- weight folding (per layer) ----------------
// We[tt] (tt: 0=W-type,1=O-type) 128x384 fp32:
//  cols [0,128):  ke  = W_k @ A_rel[et=tt]
//  cols [128,256):qA' = W_q @ A_rel[et=2+tt]^T
//  cols [256,384):v'  = W_v @ M_rel[et=tt]
// be: same transforms on biases.
__global__ __launch_bounds__(256) void fold_weights(
    const float* __restrict__ Wl, const float* __restrict__ bl,
    const float* __restrict__ Al, const float* __restrict__ Ml,
    float* __restrict__ We, float* __restrict__ be) {
  int idx = blockIdx.x * 256 + threadIdx.x;
  const int NW_ = 2 * 128 * 384;
  if (idx < NW_) {
    int tt = idx / (128 * 384);
    int rem = idx - tt * (128 * 384);
    int r = rem / 384, c = rem - r * 384;
    int slice = c >> 7, h = (c >> 5) & 3, j = c & 31;
    const float* Wsrc = Wl + (size_t)(tt + 1) * 128 * 384 + (size_t)r * 384;
    float acc = 0.f;
    if (slice == 0) {
      const float* A = Al + ((size_t)tt * H + h) * D * D;
      for (int d = 0; d < 32; d++) acc += Wsrc[h * 32 + d] * A[d * 32 + j];
    } else if (slice == 1) {
      const float* A = Al + ((size_t)(2 + tt) * H + h) * D * D;
      for (int e = 0; e < 32; e++)
        acc += Wsrc[128 + h * 32 + e] * A[j * 32 + e];
    } else {
      const float* Mm = Ml + ((size_t)tt * H + h) * D * D;
      for (int d = 0; d < 32; d++)
        acc += Wsrc[256 + h * 32 + d] * Mm[d * 32 + j];
    }
    We[idx] = acc;
  } else if (idx < NW_ + 2 * 384) {
    int rem = idx - NW_;
    int tt = rem / 384, c = rem - tt * 384;
    int slice = c >> 7, h = (c >> 5) & 3, j = c & 31;
    const float* bsrc = bl + (size_t)(tt + 1) * 384;
    float acc = 0.f;
    if (slice == 0) {
      const float* A = Al + ((size_t)tt * H + h) * D * D;
      for (int d = 0; d < 32; d++) acc += bsrc[h * 32 + d] * A[d * 32 + j];
    } else if (slice == 1) {
      const float* A = Al + ((size_t)(2 + tt) * H + h) * D * D;
      for (int e = 0; e < 32; e++)
        acc += bsrc[128 + h * 32 + e] * A[j * 32 + e];
    } else {
      const float* Mm = Ml + ((size_t)tt * H + h) * D * D;
      for (int d = 0; d < 32; d++)
        acc += bsrc[256 + h * 32 + d] * Mm[d * 32 + j];
    }
    be[rem] = acc;
  }
}

// kqv proj: 64x128 tile; t=0 -> raw W_kqv; t=1,2 -> folded We/be
__global__ __launch_bounds__(256) void kqv_fused(
    const unsigned short* __restrict__ xs, const float* __restrict__ W0,
    const float* __restrict__ b0, const float* __restrict__ We,
    const float* __restrict__ be, unsigned short* __restrict__ kqvB, int nb0,
    int nb01) {
  __shared__ unsigned short As[64][40];
  __shared__ unsigned short Bs[128][40];
  int t = btype(blockIdx.x, nb0, nb01);
  int base = t == 0 ? 0 : (t == 1 ? nb0 : nb01);
  int M = t == 0 ? NA : (t == 1 ? NW : NO);
  int off = t == 0 ? 0 : (t == 1 ? NA : NA + NW);
  const float* W = t == 0 ? W0 : We + (size_t)(t - 1) * 128 * 384;
  const float* bias = t == 0 ? b0 : be + (size_t)(t - 1) * 384;
  const unsigned short* A = xs + (size_t)off * HID;
  unsigned short* C = kqvB + (size_t)off * LDK;
  const int bm = (blockIdx.x - base) * 64;
  const int bn = blockIdx.y * 128;
  const int tid = threadIdx.x;
  const int wv = tid >> 6;
  const int l = tid & 63;
  f32x4 acc[8] = {};
  const int srow = tid >> 2, sc8 = (tid & 3) * 8;
  for (int ks = 0; ks < 4; ks++) {
    const int kk = ks * 32;
    {
      int gr = bm + srow;
      uint4 v = {0, 0, 0, 0};
      if (gr < M) v = *(const uint4*)(A + (size_t)gr * HID + kk + sc8);
      *(uint4*)&As[srow][sc8] = v;
    }
    #pragma unroll
    for (int i = 0; i < 16; i++) {
      int idx = tid + i * 256;
      int r = idx >> 7, c = idx & 127;
      Bs[c][r] = f2bf(W[(size_t)(kk + r) * LDK + bn + c]);
    }
    __syncthreads();
    const int arow = wv * 16 + (l & 15);
    const int k8 = (l >> 4) * 8;
    short8v af = *(const short8v*)&As[arow][k8];
    #pragma unroll
    for (int n = 0; n < 8; n++) {
      short8v bf = *(const short8v*)&Bs[n * 16 + (l & 15)][k8];
      acc[n] = __builtin_amdgcn_mfma_f32_16x16x32_bf16(af, bf, acc[n], 0, 0, 0);
    }
    __syncthreads();
  }
  #pragma unroll
  for (int n = 0; n < 8; n++) {
    int col = bn + n * 16 + (l & 15);
    float bb = bias[col];
    #pragma unroll
    for (int j = 0; j < 4; j++) {
      int row = bm + wv * 16 + (l >> 4) * 4 + j;
      if (row < M) C[(size_t)row * LDK + col] = f2bf(acc[n][j] + bb);
    }
  }
}

// fused: xs = relu(LN( g*(gelu(agg) @ W_o + b_o) + (1-g)*xs ))  [64x128 tile]
__global__ __launch_bounds__(256) void wo_ln_fused(
    const unsigned short* __restrict__ kqvB, const float* __restrict__ Wl,
    const float* __restrict__ bl, unsigned short* __restrict__ xs,
    const float* __restrict__ skipl, const float* __restrict__ gll,
    const float* __restrict__ bll, int nb0, int nb01) {
  __shared__ unsigned short As[64][40];
  __shared__ unsigned short Bs[128][40];
  int t = btype(blockIdx.x, nb0, nb01);
  int base = t == 0 ? 0 : (t == 1 ? nb0 : nb01);
  int M = t == 0 ? NA : (t == 1 ? NW : NO);
  int off = t == 0 ? 0 : (t == 1 ? NA : NA + NW);
  const unsigned short* A = kqvB + (size_t)off * LDK + HID;  // agg in q slice
  const float* W = Wl + (size_t)t * HID * HID;
  const float* bias = bl + t * HID;
  const float* gln = gll + t * HID;
  const float* bln = bll + t * HID;
  unsigned short* xsT = xs + (size_t)off * HID;
  const int bm = (blockIdx.x - base) * 64;
  const int tid = threadIdx.x;
  const int wv = tid >> 6;
  const int l = tid & 63;
  f32x4 acc[8] = {};
  const int srow = tid >> 2, sc8 = (tid & 3) * 8;
  for (int ks = 0; ks < 4; ks++) {
    const int kk = ks * 32;
    {
      int gr = bm + srow;
      uint4 v = {0, 0, 0, 0};
      if (gr < M) v = *(const uint4*)(A + (size_t)gr * LDK + kk + sc8);
      unsigned w4[4] = {v.x, v.y, v.z, v.w};
      unsigned short tmp[8];
      #pragma unroll
      for (int j = 0; j < 4; j++) {
        tmp[j * 2 + 0] = f2bf(gelu_exact(bf2f((unsigned short)(w4[j] & 0xFFFF))));
        tmp[j * 2 + 1] = f2bf(gelu_exact(bf2f((unsigned short)(w4[j] >> 16))));
      }
      *(uint4*)&As[srow][sc8] = *(const uint4*)tmp;
    }
    #pragma unroll
    for (int i = 0; i < 16; i++) {
      int idx = tid + i * 256;
      int r = idx >> 7, c = idx & 127;
      Bs[c][r] = f2bf(W[(size_t)(kk + r) * HID + c]);
    }
    __syncthreads();
    const int arow = wv * 16 + (l & 15);
    const int k8 = (l >> 4) * 8;
    short8v af = *(const short8v*)&As[arow][k8];
    #pragma unroll
    for (int n = 0; n < 8; n++) {
      short8v bf = *(const short8v*)&Bs[n * 16 + (l & 15)][k8];
      acc[n] = __builtin_amdgcn_mfma_f32_16x16x32_bf16(af, bf, acc[n], 0, 0, 0);
    }
    __syncthreads();
  }
  const float g = 1.f / (1.f + expf(-skipl[t]));
  float bb[8], gl8[8], bl8[8];
  #pragma unroll
  for (int n = 0; n < 8; n++) {
    int col = n * 16 + (l & 15);
    bb[n] = bias[col];
    gl8[n] = gln[col];
    bl8[n] = bln[col];
  }
  #pragma unroll
  for (int j = 0; j < 4; j++) {
    int row = bm + wv * 16 + (l >> 4) * 4 + j;
    bool ok = row < M;
    float vv[8], sum = 0.f, sq = 0.f;
    #pragma unroll
    for (int n = 0; n < 8; n++) {
      int col = n * 16 + (l & 15);
      float xo = ok ? bf2f(xsT[(size_t)row * HID + col]) : 0.f;
      float val = g * (acc[n][j] + bb[n]) + (1.f - g) * xo;
      vv[n] = val;
      sum += val;
      sq += val * val;
    }
    #pragma unroll
    for (int m = 1; m < 16; m <<= 1) {
      sum += __shfl_xor(sum, m, 64);
      sq += __shfl_xor(sq, m, 64);
    }
    float mu = sum * (1.f / 128.f);
    float var = sq * (1.f / 128.f) - mu * mu;
    float r = rsqrtf(var + 1e-5f);
    if (ok) {
      #pragma unroll
      for (int n = 0; n < 8; n++) {
        float y = fmaxf((vv[n] - mu) * r * gl8[n] + bl8[n], 0.f);
        xsT[(size_t)row * HID + n * 16 + (l & 15)] = f2bf(y);
      }
    }
  }
}

// ---------------- CSR build (deterministic, 4 ets fused) ----------------
__global__ __launch_bounds__(256) void csr_hist4(
    const int* __restrict__ d0, const int* __restrict__ d1,
    const int* __restrict__ d2, const int* __restrict__ d3,
    int* __restrict__ cnt) {
  int t = blockIdx.x * 256 + threadIdx.x;
  if (t >= 4 * E) return;
  int et = t / E, e = t - et * E;
  const int* dp = et == 0 ? d0 : et == 1 ? d1 : et == 2 ? d2 : d3;
  int base = et == 0 ? 0 : et == 1 ? NA : et == 2 ? 2 * NA : 2 * NA + NW;
  atomicAdd(&cnt[base + dp[e]], 1);
}

__global__ __launch_bounds__(256) void scan_block(const int* __restrict__ cnt,
                                                  int* __restrict__ excl,
                                                  int* __restrict__ bsum,
                                                  int n) {
  __shared__ int tmp[256];
  int i = blockIdx.x * 256 + threadIdx.x;
  int v = (i < n) ? cnt[i] : 0;
  tmp[threadIdx.x] = v;
  __syncthreads();
  int acc = v;
  for (int off = 1; off < 256; off <<= 1) {
    int other = (threadIdx.x >= off) ? tmp[threadIdx.x - off] : 0;
    __syncthreads();
    acc += other;
    tmp[threadIdx.x] = acc;
    __syncthreads();
  }
  if (i < n) excl[i] = acc - v;
  if (threadIdx.x == 255) bsum[blockIdx.x] = acc;
}

__global__ __launch_bounds__(256) void scan_bsums(int* __restrict__ bsum,
                                                  int nb) {
  __shared__ int tmp[256];
  __shared__ int carry;
  if (threadIdx.x == 0) carry = 0;
  __syncthreads();
  for (int start = 0; start < nb; start += 256) {
    int i = start + threadIdx.x;
    int v = (i < nb) ? bsum[i] : 0;
    tmp[threadIdx.x] = v;
    __syncthreads();
    int acc = v;
    for (int off = 1; off < 256; off <<= 1) {
      int other = (threadIdx.x >= off) ? tmp[threadIdx.x - off] : 0;
      __syncthreads();
      acc += other;
      tmp[threadIdx.x] = acc;
      __syncthreads();
    }
    int c = carry;
    if (i < nb) bsum[i] = c + acc - v;
    __syncthreads();
    if (threadIdx.x == 255) carry = c + acc;
    __syncthreads();
  }
}

__device__ __forceinline__ void et_of_node(int i, int& et, int& base, int& nd,
                                           int& rpo) {
  if (i < NA) { et = 0; base = 0; nd = NA; rpo = 0; }
  else if (i < 2 * NA) { et = 1; base = NA; nd = NA; rpo = NA + 1; }
  else if (i < 2 * NA + NW) { et = 2; base = 2 * NA; nd = NW; rpo = 2 * (NA + 1); }
  else { et = 3; base = 2 * NA + NW; nd = NO; rpo = 2 * (NA + 1) + NW + 1; }
}

__global__ __launch_bounds__(256) void csr_finalize4(
    int* __restrict__ rpAll, const int* __restrict__ bsum,
    int* __restrict__ cursor) {
  int i = blockIdx.x * 256 + threadIdx.x;
  if (i >= 2 * NA + NW + NO) return;
  int et, base, nd, rpo;
  et_of_node(i, et, base, nd, rpo);
  int local = i - base;
  int v = rpAll[rpo + local] + bsum[et * 512 + (local >> 8)];
  rpAll[rpo + local] = v;
  cursor[base + local] = v;
  if (local == 0) rpAll[rpo + nd] = E;
}

__global__ __launch_bounds__(256) void csr_scatter4(
    const int* __restrict__ d0, const int* __restrict__ d1,
    const int* __restrict__ d2, const int* __restrict__ d3,
    int* __restrict__ cursor, int* __restrict__ ceAll) {
  int t = blockIdx.x * 256 + threadIdx.x;
  if (t >= 4 * E) return;
  int et = t / E, e = t - et * E;
  const int* dp = et == 0 ? d0 : et == 1 ? d1 : et == 2 ? d2 : d3;
  int base = et == 0 ? 0 : et == 1 ? NA : et == 2 ? 2 * NA : 2 * NA + NW;
  int slot = atomicAdd(&cursor[base + dp[e]], 1);
  ceAll[(size_t)et * E + slot] = e;
}

__global__ __launch_bounds__(256) void csr_sort4(const int* __restrict__ rpAll,
                                                 int* __restrict__ ceAll) {
  int i = blockIdx.x * 256 + threadIdx.x;
  if (i >= 2 * NA + NW + NO) return;
  int et, base, nd, rpo;
  et_of_node(i, et, base, nd, rpo);
  int local = i - base;
  int b = rpAll[rpo + local], e = rpAll[rpo + local + 1];
  int* ce = ceAll + (size_t)et * E;
  for (int k = b + 1; k < e; k++) {
    int key = ce[k];
    int j = k - 1;
    while (j >= b && ce[j] > key) { ce[j + 1] = ce[j]; j--; }
    ce[j + 1] = key;
  }
}

// slot-ordered GLOBAL src/dst node ids
__global__ __launch_bounds__(256) void build_sd(
    const int* __restrict__ ce, const int* __restrict__ s0,
    const int* __restrict__ s1, const int* __restrict__ s2,
    const int* __restrict__ s3, const int* __restrict__ d0,
    const int* __restrict__ d1, const int* __restrict__ d2,
    const int* __restrict__ d3, int* __restrict__ srcOf,
    int* __restrict__ dstOf) {
  int t = blockIdx.x * 256 + threadIdx.x;
  if (t >= 4 * E) return;
  int et = t / E;
  int e = ce[t];
  const int* sp = et == 0 ? s0 : et == 1 ? s1 : et == 2 ? s2 : s3;
  const int* dp = et == 0 ? d0 : et == 1 ? d1 : et == 2 ? d2 : d3;
  int sOff = et == 0 ? NA : et == 1 ? NA + NW : 0;
  int dOff = et == 0 ? 0 : et == 1 ? 0 : et == 2 ? NA : NA + NW;
  srcOf[t] = sOff + sp[e];
  dstOf[t] = dOff + dp[e];
}

// ---------------- attention ----------------
// alpha: 32 lanes = one slot (4 h x 8 lanes x 4 dims). Branch-free:
// alpha = kqv[dst].q_slice . kqv[src].k_slice  (folded semantics per et)
__global__ __launch_bounds__(256) void alpha_fused(
    const unsigned short* __restrict__ kqv, const int* __restrict__ srcOf,
    const int* __restrict__ dstOf, const float* __restrict__ Pl,
    float* __restrict__ alphaB) {
  int g = (blockIdx.x * 256 + threadIdx.x) >> 5;
  int lane = threadIdx.x & 31;
  if (g >= 4 * E) return;
  int h = lane >> 3;
  int d4 = (lane & 7) * 4;
  int s_ = srcOf[g], d_ = dstOf[g];
  uint2 av = *(const uint2*)(kqv + (size_t)d_ * LDK + HID + h * 32 + d4);
  uint2 bv = *(const uint2*)(kqv + (size_t)s_ * LDK + h * 32 + d4);
  float pv = bf2f((unsigned short)(av.x & 0xFFFF)) *
                 bf2f((unsigned short)(bv.x & 0xFFFF)) +
             bf2f((unsigned short)(av.x >> 16)) *
                 bf2f((unsigned short)(bv.x >> 16)) +
             bf2f((unsigned short)(av.y & 0xFFFF)) *
                 bf2f((unsigned short)(bv.y & 0xFFFF)) +
             bf2f((unsigned short)(av.y >> 16)) *
                 bf2f((unsigned short)(bv.y >> 16));
  pv += __shfl_xor(pv, 1, 32);
  pv += __shfl_xor(pv, 2, 32);
  pv += __shfl_xor(pv, 4, 32);
  if ((lane & 7) == 0) {
    int et = g / E;
    alphaB[(size_t)g * H + h] = pv * Pl[et * H + h] * SCALE;
  }
}

// all-dst softmax normalize (in place alpha -> w)
__global__ __launch_bounds__(256) void softmax_fused(
    const int* __restrict__ rpAll, float* __restrict__ alphaB) {
  int g = (blockIdx.x * 256 + threadIdx.x) >> 5;
  int lane = threadIdx.x & 31;
  if (g >= NTOT * H) return;
  int dl = g >> 2, h = g & 3;
  int b0, e0, b1 = 0, e1 = 0;
  size_t o0;
  const size_t EH = (size_t)E * H;
  if (dl < NA) {
    b0 = rpAll[dl]; e0 = rpAll[dl + 1];
    b1 = rpAll[(NA + 1) + dl]; e1 = rpAll[(NA + 1) + dl + 1];
    o0 = 0;
  } else if (dl < NA + NW) {
    int x = dl - NA;
    b0 = rpAll[2 * (NA + 1) + x]; e0 = rpAll[2 * (NA + 1) + x + 1];
    o0 = 2 * EH;
  } else {
    int x = dl - NA - NW;
    b0 = rpAll[2 * (NA + 1) + (NW + 1) + x];
    e0 = rpAll[2 * (NA + 1) + (NW + 1) + x + 1];
    o0 = 3 * EH;
  }
  float mx = -INFINITY;
  for (int i = b0 + lane; i < e0; i += 32)
    mx = fmaxf(mx, alphaB[o0 + (size_t)i * H + h]);
  for (int i = b1 + lane; i < e1; i += 32)
    mx = fmaxf(mx, alphaB[EH + (size_t)i * H + h]);
  #pragma unroll
  for (int m = 1; m < 32; m <<= 1) mx = fmaxf(mx, __shfl_xor(mx, m, 32));
  float den = 0.f;
  for (int i = b0 + lane; i < e0; i += 32)
    den += expf(alphaB[o0 + (size_t)i * H + h] - mx);
  for (int i = b1 + lane; i < e1; i += 32)
    den += expf(alphaB[EH + (size_t)i * H + h] - mx);
  #pragma unroll
  for (int m = 1; m < 32; m <<= 1) den += __shfl_xor(den, m, 32);
  float inv = 1.f / (den + 1e-16f);
  for (int i = b0 + lane; i < e0; i += 32)
    alphaB[o0 + (size_t)i * H + h] = expf(alphaB[o0 + (size_t)i * H + h] - mx) * inv;
  for (int i = b1 + lane; i < e1; i += 32)
    alphaB[EH + (size_t)i * H + h] = expf(alphaB[EH + (size_t)i * H + h] - mx) * inv;
}

// all-dst aggregation: A-dst pure v'(folded) gather; W/O-dst raw-v + M shfl.
__global__ __launch_bounds__(256) void agg_fused(
    const unsigned short* __restrict__ kqv, const int* __restrict__ rpAll,
    const int* __restrict__ srcOf, const float* __restrict__ alphaB,
    const float* __restrict__ Ml, unsigned short* __restrict__ out) {
  int g = (blockIdx.x * 256 + threadIdx.x) >> 5;
  int lane = threadIdx.x & 31;
  if (g >= NTOT * H) return;
  int dl = g >> 2, h = g & 3;
  const size_t EH = (size_t)E * H;
  float acc;
  if (dl < NA) {
    acc = 0.f;
    int b = rpAll[dl], e = rpAll[dl + 1];
    for (int i = b; i < e; i++)
      acc += alphaB[(size_t)i * H + h] *
             bf2f(kqv[(size_t)srcOf[i] * LDK + 2 * HID + h * 32 + lane]);
    b = rpAll[(NA + 1) + dl]; e = rpAll[(NA + 1) + dl + 1];
    for (int i = b; i < e; i++)
      acc += alphaB[EH + (size_t)i * H + h] *
             bf2f(kqv[(size_t)srcOf[(size_t)E + i] * LDK + 2 * HID + h * 32 +
                      lane]);
  } else {
    int et, x, rpo;
    if (dl < NA + NW) { et = 2; x = dl - NA; rpo = 2 * (NA + 1); }
    else { et = 3; x = dl - NA - NW; rpo = 2 * (NA + 1) + (NW + 1); }
    int b = rpAll[rpo + x], e = rpAll[rpo + x + 1];
    const float* al = alphaB + (size_t)et * EH;
    const int* so = srcOf + (size_t)et * E;
    float sv = 0.f;
    for (int i = b; i < e; i++)
      sv += al[(size_t)i * H + h] *
            bf2f(kqv[(size_t)so[i] * LDK + 2 * HID + h * 32 + lane]);
    const float* Mm = Ml + ((size_t)et * H + h) * D * D;
    acc = 0.f;
    #pragma unroll 8
    for (int d = 0; d < 32; d++) acc += __shfl(sv, d, 32) * Mm[d * 32 + lane];
  }
  out[(size_t)dl * LDK + HID + h * 32 + lane] = f2bf(acc);
}

__global__ __launch_bounds__(256) void head_kernel(
    const unsigned short* __restrict__ xs0, const float* __restrict__ w_head,
    const float* __restrict__ b_head, const float* __restrict__ basep,
    float* __restrict__ out, int Nrows) {
  int wid = (blockIdx.x * 256 + threadIdx.x) >> 6;
  int lane = threadIdx.x & 63;
  if (wid >= Nrows) return;
  size_t base = (size_t)wid * HID;
  float d = bf2f(xs0[base + lane]) * w_head[lane] +
            bf2f(xs0[base + 64 + lane]) * w_head[64 + lane];
  #pragma unroll
  for (int m = 1; m < 64; m <<= 1) d += __shfl_xor(d, m, 64);
  if (lane == 0) out[wid] = basep[0] + b_head[0] + d;
}

}  // namespace

extern "C" void kernel_launch(void* const* d_in, const int* in_sizes, int n_in,
                              void* d_out, int out_size, void* d_ws,
                              size_t ws_size, hipStream_t stream) {
  const float* x_a = (const float*)d_in[0];
  const float* x_w = (const float*)d_in[1];
  const float* x_o = (const float*)d_in[2];
  const float* W_in = (const float*)d_in[3];
  const float* b_in = (const float*)d_in[4];
  const float* W_kqv = (const float*)d_in[5];
  const float* b_kqv = (const float*)d_in[6];
  const float* a_rel = (const float*)d_in[7];
  const float* m_rel = (const float*)d_in[8];
  const float* p_rel = (const float*)d_in[9];
  const float* skip_p = (const float*)d_in[10];
  const float* W_o = (const float*)d_in[11];
  const float* b_o = (const float*)d_in[12];
  const float* ln_g = (const float*)d_in[13];
  const float* ln_b = (const float*)d_in[14];
  const float* w_head = (const float*)d_in[15];
  const float* b_head = (const float*)d_in[16];
  const float* basep = (const float*)d_in[17];
  const int* srcs[4] = {(const int*)d_in[18], (const int*)d_in[20],
                        (const int*)d_in[22], (const int*)d_in[24]};
  const int* dsts[4] = {(const int*)d_in[19], (const int*)d_in[21],
                        (const int*)d_in[23], (const int*)d_in[25]};

  // ---- workspace layout (~194 MB) ----
  const size_t SZ_XS = (size_t)NTOT * HID * 2;        // bf16 xs        43.5 MB
  const size_t SZ_KQV = (size_t)NTOT * LDK * 2;       // bf16 kqv      130.6 MB
  const size_t SZ_AL = (size_t)4 * E * H * 4;         // fp32 w          9.6 MB
  const size_t SZ_WE = (size_t)2 * 128 * 384 * 4;     // folded W        0.4 MB
  const size_t SZ_BE = ((size_t)2 * 384 * 4 + 63) & ~63ull;
  const size_t SZ_SD = (size_t)4 * E * 4;
  const int CNT_TOT = 2 * NA + NW + NO;               // 270000
  const int RP_TOT = 2 * (NA + 1) + (NW + 1) + (NO + 1);
  const size_t SZ_RP = ((size_t)RP_TOT * 4 + 63) & ~63ull;
  const size_t SZ_CE = (size_t)4 * E * 4;
  const size_t SZ_CU = ((size_t)CNT_TOT * 4 + 63) & ~63ull;
  const size_t SZ_BS = 4 * 512 * 4;
  const size_t need = SZ_XS + SZ_KQV + SZ_AL + SZ_WE + SZ_BE + 2 * SZ_SD +
                      SZ_RP + SZ_CE + 2 * SZ_CU + SZ_BS;
  if (ws_size < need) return;

  char* p = (char*)d_ws;
  unsigned short* xs = (unsigned short*)p;   p += SZ_XS;
  unsigned short* kqvB = (unsigned short*)p; p += SZ_KQV;
  float* alphaB = (float*)p;                 p += SZ_AL;
  float* weB = (float*)p;                    p += SZ_WE;
  float* beB = (float*)p;                    p += SZ_BE;
  int* srcOf = (int*)p;                      p += SZ_SD;
  int* dstOf = (int*)p;                      p += SZ_SD;
  int* rpAll = (int*)p;                      p += SZ_RP;
  int* ceAll = (int*)p;                      p += SZ_CE;
  int* cursor = (int*)p;                     p += SZ_CU;
  int* cnt = (int*)p;                        p += SZ_CU;
  int* bsum = (int*)p;

  const int rpOff[4] = {0, NA + 1, 2 * (NA + 1), 2 * (NA + 1) + NW + 1};
  const int cntBase[4] = {0, NA, 2 * NA, 2 * NA + NW};
  const int ndE[4] = {NA, NA, NW, NO};
  const int e4b = (4 * E + 255) / 256;
  const int nb0 = (NA + 63) / 64, nb01 = nb0 + (NW + 63) / 64;
  const int nbTot = nb01 + (NO + 63) / 64;

  // ---- CSR build (once) ----
  hipMemsetAsync(cnt, 0, (size_t)CNT_TOT * 4, stream);
  csr_hist4<<<e4b, 256, 0, stream>>>(dsts[0], dsts[1], dsts[2], dsts[3], cnt);
  for (int et = 0; et < 4; et++) {
    int nb = (ndE[et] + 255) / 256;
    scan_block<<<nb, 256, 0, stream>>>(cnt + cntBase[et], rpAll + rpOff[et],
                                       bsum + et * 512, ndE[et]);
    scan_bsums<<<1, 256, 0, stream>>>(bsum + et * 512, nb);
  }
  csr_finalize4<<<(CNT_TOT + 255) / 256, 256, 0, stream>>>(rpAll, bsum, cursor);
  csr_scatter4<<<e4b, 256, 0, stream>>>(dsts[0], dsts[1], dsts[2], dsts[3],
                                        cursor, ceAll);
  csr_sort4<<<(CNT_TOT + 255) / 256, 256, 0, stream>>>(rpAll, ceAll);
  build_sd<<<e4b, 256, 0, stream>>>(ceAll, srcs[0], srcs[1], srcs[2], srcs[3],
                                    dsts[0], dsts[1], dsts[2], dsts[3], srcOf,
                                    dstOf);

  // ---- input projection ----
  in_fused<<<dim3(nbTot, 2), 256, 0, stream>>>(x_a, x_w, x_o, W_in, b_in, xs,
                                               nb0, nb01);

  const size_t DD = (size_t)H * D * D;
  for (int l = 0; l < 2; l++) {
    const float* Al = a_rel + (size_t)l * 4 * DD;
    const float* Ml = m_rel + (size_t)l * 4 * DD;
    const float* Pl = p_rel + (size_t)l * 4 * H;
    const float* Wl = W_kqv + (size_t)l * 3 * HID * LDK;
    const float* bl = b_kqv + (size_t)l * 3 * LDK;
    fold_weights<<<(2 * 128 * 384 + 2 * 384 + 255) / 256, 256, 0, stream>>>(
        Wl, bl, Al, Ml, weB, beB);
    kqv_fused<<<dim3(nbTot, 3), 256, 0, stream>>>(xs, Wl, bl, weB, beB, kqvB,
                                                  nb0, nb01);
    alpha_fused<<<((size_t)4 * E * 32 + 255) / 256, 256, 0, stream>>>(
        kqvB, srcOf, dstOf, Pl, alphaB);
    softmax_fused<<<((size_t)NTOT * H * 32 + 255) / 256, 256, 0, stream>>>(
        rpAll, alphaB);
    agg_fused<<<((size_t)NTOT * H * 32 + 255) / 256, 256, 0, stream>>>(
        kqvB, rpAll, srcOf, alphaB, Ml, kqvB);
    wo_ln_fused<<<nbTot, 256, 0, stream>>>(
        kqvB, W_o + (size_t)l * 3 * HID * HID, b_o + (size_t)l * 3 * HID, xs,
        skip_p + l * 3, ln_g + (size_t)l * 3 * HID, ln_b + (size_t)l * 3 * HID,
        nb0, nb01);
  }
  head_kernel<<<(NA + 3) / 4, 256, 0, stream>>>(xs, w_head, b_head, basep,
                                                (float*)d_out, NA);
}

// Round 12
// 1134.983 us; speedup vs baseline: 1.9964x; 1.1252x over previous
//
#include <hip/hip_runtime.h>
#include <cstddef>
#include <cmath>

namespace {

constexpr int H = 4, D = 32, HID = 128;
constexpr int NA = 100000, NW = 20000, NO = 50000;
constexpr int NTOT = NA + NW + NO;
constexpr int E = 150000;
constexpr float SCALE = 0.17677669529663687f;  // 1/sqrt(32)
constexpr int LDK = 3 * HID;  // kqv row stride (384)

typedef __attribute__((ext_vector_type(8))) short short8v;
typedef __attribute__((ext_vector_type(4))) float f32x4;

__device__ __forceinline__ float gelu_exact(float x) {
  return 0.5f * x * (1.f + erff(x * 0.7071067811865475f));
}
__device__ __forceinline__ unsigned short f2bf(float f) {  // RNE
  unsigned u = __float_as_uint(f);
  return (unsigned short)((u + 0x7FFF + ((u >> 16) & 1)) >> 16);
}
__device__ __forceinline__ float bf2f(unsigned short s) {
  return __uint_as_float(((unsigned)s) << 16);
}

__device__ __forceinline__ int btype(int bx, int nb0, int nb01) {
  return bx < nb0 ? 0 : (bx < nb01 ? 1 : 2);
}

// ---------------- swizzled BK=64 MFMA GEMM body ----------------
// tile 64 rows x 128 cols, 4 waves. LDS rows = 128B (32 banks); 16B chunk c
// of row r stored at (c ^ (r&7)) -> conflict-free writes, 2-way reads.
// BT: bf16 pre-transposed weights [n][k], pre-offset to col-tile; ldb = K.
template <int KSTEPS, bool A_FP32>
__device__ __forceinline__ void gemm_body(
    const void* __restrict__ Av, int lda, const unsigned short* __restrict__ BT,
    int ldb, f32x4* acc, int M, int bm) {
  __shared__ unsigned short As[64 * 64];
  __shared__ unsigned short Bs[128 * 64];
  const int tid = threadIdx.x;
  const int wv = tid >> 6, l = tid & 63;
  for (int ks = 0; ks < KSTEPS; ks++) {
    const int kk = ks * 64;
    // stage A: 64 rows x 8 chunks, 2 per thread
    #pragma unroll
    for (int p = 0; p < 2; p++) {
      int idx = tid + p * 256;
      int r = idx >> 3, c = idx & 7;
      int gr = bm + r;
      unsigned short tmp[8] = {0, 0, 0, 0, 0, 0, 0, 0};
      if (gr < M) {
        if (A_FP32) {
          const float* src = (const float*)Av + (size_t)gr * lda + kk + c * 8;
          float4 f0 = *(const float4*)src;
          float4 f1 = *(const float4*)(src + 4);
          tmp[0] = f2bf(f0.x); tmp[1] = f2bf(f0.y);
          tmp[2] = f2bf(f0.z); tmp[3] = f2bf(f0.w);
          tmp[4] = f2bf(f1.x); tmp[5] = f2bf(f1.y);
          tmp[6] = f2bf(f1.z); tmp[7] = f2bf(f1.w);
        } else {
          *(uint4*)tmp = *(const uint4*)((const unsigned short*)Av +
                                         (size_t)gr * lda + kk + c * 8);
        }
      }
      *(uint4*)&As[r * 64 + ((c ^ (r & 7)) * 8)] = *(const uint4*)tmp;
    }
    // stage B: 128 rows x 8 chunks, 4 per thread (pure bf16 copy)
    #pragma unroll
    for (int p = 0; p < 4; p++) {
      int idx = tid + p * 256;
      int r = idx >> 3, c = idx & 7;
      uint4 v = *(const uint4*)(BT + (size_t)r * ldb + kk + c * 8);
      *(uint4*)&Bs[r * 64 + ((c ^ (r & 7)) * 8)] = v;
    }
    __syncthreads();
    const int arow = wv * 16 + (l & 15);
    #pragma unroll
    for (int ksub = 0; ksub < 2; ksub++) {
      int ch = ksub * 4 + (l >> 4);
      short8v af = *(const short8v*)&As[arow * 64 + ((ch ^ (arow & 7)) * 8)];
      #pragma unroll
      for (int n = 0; n < 8; n++) {
        int brow = n * 16 + (l & 15);
        short8v bf =
            *(const short8v*)&Bs[brow * 64 + ((ch ^ (brow & 7)) * 8)];
        acc[n] =
            __builtin_amdgcn_mfma_f32_16x16x32_bf16(af, bf, acc[n], 0, 0, 0);
      }
    }
    __syncthreads();
  }
}

// ---------------- weight prep: bf16 transposed copies ----------------
// WinT[3][128n][64k]; Wk0T[2][384n][128k]; WoT[2][3][128n][128k]
__global__ __launch_bounds__(256) void prep_weights(
    const float* __restrict__ W_in, const float* __restrict__ W_kqv,
    const float* __restrict__ W_o, unsigned short* __restrict__ WinT,
    unsigned short* __restrict__ Wk0T, unsigned short* __restrict__ WoT) {
  int idx = blockIdx.x * 256 + threadIdx.x;
  const int N1 = 3 * 128 * 64, N2 = 2 * 384 * 128, N3 = 6 * 128 * 128;
  if (idx < N1) {
    int t = idx / 8192, rem = idx - t * 8192;
    int n = rem >> 6, k = rem & 63;
    WinT[idx] = f2bf(W_in[(size_t)t * 64 * 128 + (size_t)k * 128 + n]);
  } else if (idx < N1 + N2) {
    int r = idx - N1;
    int lyr = r / (384 * 128), rem = r - lyr * (384 * 128);
    int n = rem >> 7, k = rem & 127;
    Wk0T[r] = f2bf(W_kqv[(size_t)lyr * 3 * 128 * 384 + (size_t)k * 384 + n]);
  } else if (idx < N1 + N2 + N3) {
    int r = idx - N1 - N2;
    int lt = r / (128 * 128), rem = r - lt * (128 * 128);
    int n = rem >> 7, k = rem & 127;
    WoT[r] = f2bf(W_o[(size_t)lt * 128 * 128 + (size_t)k * 128 + n]);
  }
}

// ---------------- weight folding (per layer) -> bf16 transposed ----------
// WeT[tt][c(384)][r(128)]:
//  c in [0,128):   ke  = W_k @ A_rel[et=tt]
//  c in [128,256): qA' = W_q @ A_rel[et=2+tt]^T
//  c in [256,384): v'  = W_v @ M_rel[et=tt]
__global__ __launch_bounds__(256) void fold_weights(
    const float* __restrict__ Wl, const float* __restrict__ bl,
    const float* __restrict__ Al, const float* __restrict__ Ml,
    unsigned short* __restrict__ WeT, float* __restrict__ be) {
  int idx = blockIdx.x * 256 + threadIdx.x;
  const int NW_ = 2 * 128 * 384;
  if (idx < NW_) {
    int tt = idx / (128 * 384);
    int rem = idx - tt * (128 * 384);
    int r = rem / 384, c = rem - r * 384;
    int slice = c >> 7, h = (c >> 5) & 3, j = c & 31;
    const float* Wsrc = Wl + (size_t)(tt + 1) * 128 * 384 + (size_t)r * 384;
    float acc = 0.f;
    if (slice == 0) {
      const float* A = Al + ((size_t)tt * H + h) * D * D;
      for (int d = 0; d < 32; d++) acc += Wsrc[h * 32 + d] * A[d * 32 + j];
    } else if (slice == 1) {
      const float* A = Al + ((size_t)(2 + tt) * H + h) * D * D;
      for (int e = 0; e < 32; e++)
        acc += Wsrc[128 + h * 32 + e] * A[j * 32 + e];
    } else {
      const float* Mm = Ml + ((size_t)tt * H + h) * D * D;
      for (int d = 0; d < 32; d++)
        acc += Wsrc[256 + h * 32 + d] * Mm[d * 32 + j];
    }
    WeT[(size_t)tt * 384 * 128 + (size_t)c * 128 + r] = f2bf(acc);
  } else if (idx < NW_ + 2 * 384) {
    int rem = idx - NW_;
    int tt = rem / 384, c = rem - tt * 384;
    int slice = c >> 7, h = (c >> 5) & 3, j = c & 31;
    const float* bsrc = bl + (size_t)(tt + 1) * 384;
    float acc = 0.f;
    if (slice == 0) {
      const float* A = Al + ((size_t)tt * H + h) * D * D;
      for (int d = 0; d < 32; d++) acc += bsrc[h * 32 + d] * A[d * 32 + j];
    } else if (slice == 1) {
      const float* A = Al + ((size_t)(2 + tt) * H + h) * D * D;
      for (int e = 0; e < 32; e++)
        acc += bsrc[128 + h * 32 + e] * A[j * 32 + e];
    } else {
      const float* Mm = Ml + ((size_t)tt * H + h) * D * D;
      for (int d = 0; d < 32; d++)
        acc += bsrc[256 + h * 32 + d] * Mm[d * 32 + j];
    }
    be[rem] = acc;
  }
}

// input proj: xs = relu(x @ W_in[t] + b_in[t])  [K=64, 128-col tile]
__global__ __launch_bounds__(256) void in_fused(
    const float* __restrict__ xa, const float* __restrict__ xw,
    const float* __restrict__ xo, const unsigned short* __restrict__ WinT,
    const float* __restrict__ b_in, unsigned short* __restrict__ xs, int nb0,
    int nb01) {
  int t = btype(blockIdx.x, nb0, nb01);
  int base = t == 0 ? 0 : (t == 1 ? nb0 : nb01);
  int M = t == 0 ? NA : (t == 1 ? NW : NO);
  int off = t == 0 ? 0 : (t == 1 ? NA : NA + NW);
  const float* A = t == 0 ? xa : (t == 1 ? xw : xo);
  const int bm = (blockIdx.x - base) * 64;
  f32x4 acc[8] = {};
  gemm_body<1, true>(A, 64, WinT + (size_t)t * 128 * 64, 64, acc, M, bm);
  const int l = threadIdx.x & 63, wv = threadIdx.x >> 6;
  const float* bias = b_in + t * HID;
  unsigned short* C = xs + (size_t)off * HID;
  #pragma unroll
  for (int n = 0; n < 8; n++) {
    int col = n * 16 + (l & 15);
    float bb = bias[col];
    #pragma unroll
    for (int j = 0; j < 4; j++) {
      int row = bm + wv * 16 + (l >> 4) * 4 + j;
      if (row < M) C[(size_t)row * HID + col] = f2bf(fmaxf(acc[n][j] + bb, 0.f));
    }
  }
}

// kqv proj: t=0 raw Wk0T; t=1,2 folded WeT. 64x128 tile, y = col-tile (3).
__global__ __launch_bounds__(256) void kqv_fused(
    const unsigned short* __restrict__ xs, const unsigned short* __restrict__ Wk0Tl,
    const float* __restrict__ b0, const unsigned short* __restrict__ WeT,
    const float* __restrict__ be, unsigned short* __restrict__ kqvB, int nb0,
    int nb01) {
  int t = btype(blockIdx.x, nb0, nb01);
  int base = t == 0 ? 0 : (t == 1 ? nb0 : nb01);
  int M = t == 0 ? NA : (t == 1 ? NW : NO);
  int off = t == 0 ? 0 : (t == 1 ? NA : NA + NW);
  const unsigned short* BT =
      (t == 0 ? Wk0Tl : WeT + (size_t)(t - 1) * 384 * 128);
  const float* bias = t == 0 ? b0 : be + (size_t)(t - 1) * 384;
  const int bm = (blockIdx.x - base) * 64;
  const int bn = blockIdx.y * 128;
  f32x4 acc[8] = {};
  gemm_body<2, false>(xs + (size_t)off * HID, HID, BT + (size_t)bn * 128, 128,
                      acc, M, bm);
  const int l = threadIdx.x & 63, wv = threadIdx.x >> 6;
  unsigned short* C = kqvB + (size_t)off * LDK;
  #pragma unroll
  for (int n = 0; n < 8; n++) {
    int col = bn + n * 16 + (l & 15);
    float bb = bias[col];
    #pragma unroll
    for (int j = 0; j < 4; j++) {
      int row = bm + wv * 16 + (l >> 4) * 4 + j;
      if (row < M) C[(size_t)row * LDK + col] = f2bf(acc[n][j] + bb);
    }
  }
}

// fused: xs = relu(LN( g*(agg_gelu @ W_o + b_o) + (1-g)*xs ))
// (gelu already applied to agg by agg_fused)
__global__ __launch_bounds__(256) void wo_ln_fused(
    const unsigned short* __restrict__ kqvB, const unsigned short* __restrict__ WoTl,
    const float* __restrict__ bl, unsigned short* __restrict__ xs,
    const float* __restrict__ skipl, const float* __restrict__ gll,
    const float* __restrict__ bll, int nb0, int nb01) {
  int t = btype(blockIdx.x, nb0, nb01);
  int base = t == 0 ? 0 : (t == 1 ? nb0 : nb01);
  int M = t == 0 ? NA : (t == 1 ? NW : NO);
  int off = t == 0 ? 0 : (t == 1 ? NA : NA + NW);
  const int bm = (blockIdx.x - base) * 64;
  f32x4 acc[8] = {};
  gemm_body<2, false>(kqvB + (size_t)off * LDK + HID, LDK,
                      WoTl + (size_t)t * 128 * 128, 128, acc, M, bm);
  const int l = threadIdx.x & 63, wv = threadIdx.x >> 6;
  const float* bias = bl + t * HID;
  const float* gln = gll + t * HID;
  const float* bln = bll + t * HID;
  unsigned short* xsT = xs + (size_t)off * HID;
  const float g = 1.f / (1.f + expf(-skipl[t]));
  float bb[8], gl8[8], bl8[8];
  #pragma unroll
  for (int n = 0; n < 8; n++) {
    int col = n * 16 + (l & 15);
    bb[n] = bias[col];
    gl8[n] = gln[col];
    bl8[n] = bln[col];
  }
  #pragma unroll
  for (int j = 0; j < 4; j++) {
    int row = bm + wv * 16 + (l >> 4) * 4 + j;
    bool ok = row < M;
    float vv[8], sum = 0.f, sq = 0.f;
    #pragma unroll
    for (int n = 0; n < 8; n++) {
      int col = n * 16 + (l & 15);
      float xo = ok ? bf2f(xsT[(size_t)row * HID + col]) : 0.f;
      float val = g * (acc[n][j] + bb[n]) + (1.f - g) * xo;
      vv[n] = val;
      sum += val;
      sq += val * val;
    }
    #pragma unroll
    for (int m = 1; m < 16; m <<= 1) {
      sum += __shfl_xor(sum, m, 64);
      sq += __shfl_xor(sq, m, 64);
    }
    float mu = sum * (1.f / 128.f);
    float var = sq * (1.f / 128.f) - mu * mu;
    float r = rsqrtf(var + 1e-5f);
    if (ok) {
      #pragma unroll
      for (int n = 0; n < 8; n++) {
        float y = fmaxf((vv[n] - mu) * r * gl8[n] + bl8[n], 0.f);
        xsT[(size_t)row * HID + n * 16 + (l & 15)] = f2bf(y);
      }
    }
  }
}

// ---------------- CSR build (deterministic, 4 ets fused) ----------------
__global__ __launch_bounds__(256) void csr_hist4(
    const int* __restrict__ d0, const int* __restrict__ d1,
    const int* __restrict__ d2, const int* __restrict__ d3,
    int* __restrict__ cnt) {
  int t = blockIdx.x * 256 + threadIdx.x;
  if (t >= 4 * E) return;
  int et = t / E, e = t - et * E;
  const int* dp = et == 0 ? d0 : et == 1 ? d1 : et == 2 ? d2 : d3;
  int base = et == 0 ? 0 : et == 1 ? NA : et == 2 ? 2 * NA : 2 * NA + NW;
  atomicAdd(&cnt[base + dp[e]], 1);
}

__global__ __launch_bounds__(256) void scan_block(const int* __restrict__ cnt,
                                                  int* __restrict__ excl,
                                                  int* __restrict__ bsum,
                                                  int n) {
  __shared__ int tmp[256];
  int i = blockIdx.x * 256 + threadIdx.x;
  int v = (i < n) ? cnt[i] : 0;
  tmp[threadIdx.x] = v;
  __syncthreads();
  int acc = v;
  for (int off = 1; off < 256; off <<= 1) {
    int other = (threadIdx.x >= off) ? tmp[threadIdx.x - off] : 0;
    __syncthreads();
    acc += other;
    tmp[threadIdx.x] = acc;
    __syncthreads();
  }
  if (i < n) excl[i] = acc - v;
  if (threadIdx.x == 255) bsum[blockIdx.x] = acc;
}

__global__ __launch_bounds__(256) void scan_bsums(int* __restrict__ bsum,
                                                  int nb) {
  __shared__ int tmp[256];
  __shared__ int carry;
  if (threadIdx.x == 0) carry = 0;
  __syncthreads();
  for (int start = 0; start < nb; start += 256) {
    int i = start + threadIdx.x;
    int v = (i < nb) ? bsum[i] : 0;
    tmp[threadIdx.x] = v;
    __syncthreads();
    int acc = v;
    for (int off = 1; off < 256; off <<= 1) {
      int other = (threadIdx.x >= off) ? tmp[threadIdx.x - off] : 0;
      __syncthreads();
      acc += other;
      tmp[threadIdx.x] = acc;
      __syncthreads();
    }
    int c = carry;
    if (i < nb) bsum[i] = c + acc - v;
    __syncthreads();
    if (threadIdx.x == 255) carry = c + acc;
    __syncthreads();
  }
}

__device__ __forceinline__ void et_of_node(int i, int& et, int& base, int& nd,
                                           int& rpo) {
  if (i < NA) { et = 0; base = 0; nd = NA; rpo = 0; }
  else if (i < 2 * NA) { et = 1; base = NA; nd = NA; rpo = NA + 1; }
  else if (i < 2 * NA + NW) { et = 2; base = 2 * NA; nd = NW; rpo = 2 * (NA + 1); }
  else { et = 3; base = 2 * NA + NW; nd = NO; rpo = 2 * (NA + 1) + NW + 1; }
}

__global__ __launch_bounds__(256) void csr_finalize4(
    int* __restrict__ rpAll, const int* __restrict__ bsum,
    int* __restrict__ cursor) {
  int i = blockIdx.x * 256 + threadIdx.x;
  if (i >= 2 * NA + NW + NO) return;
  int et, base, nd, rpo;
  et_of_node(i, et, base, nd, rpo);
  int local = i - base;
  int v = rpAll[rpo + local] + bsum[et * 512 + (local >> 8)];
  rpAll[rpo + local] = v;
  cursor[base + local] = v;
  if (local == 0) rpAll[rpo + nd] = E;
}

__global__ __launch_bounds__(256) void csr_scatter4(
    const int* __restrict__ d0, const int* __restrict__ d1,
    const int* __restrict__ d2, const int* __restrict__ d3,
    int* __restrict__ cursor, int* __restrict__ ceAll) {
  int t = blockIdx.x * 256 + threadIdx.x;
  if (t >= 4 * E) return;
  int et = t / E, e = t - et * E;
  const int* dp = et == 0 ? d0 : et == 1 ? d1 : et == 2 ? d2 : d3;
  int base = et == 0 ? 0 : et == 1 ? NA : et == 2 ? 2 * NA : 2 * NA + NW;
  int slot = atomicAdd(&cursor[base + dp[e]], 1);
  ceAll[(size_t)et * E + slot] = e;
}

__global__ __launch_bounds__(256) void csr_sort4(const int* __restrict__ rpAll,
                                                 int* __restrict__ ceAll) {
  int i = blockIdx.x * 256 + threadIdx.x;
  if (i >= 2 * NA + NW + NO) return;
  int et, base, nd, rpo;
  et_of_node(i, et, base, nd, rpo);
  int local = i - base;
  int b = rpAll[rpo + local], e = rpAll[rpo + local + 1];
  int* ce = ceAll + (size_t)et * E;
  for (int k = b + 1; k < e; k++) {
    int key = ce[k];
    int j = k - 1;
    while (j >= b && ce[j] > key) { ce[j + 1] = ce[j]; j--; }
    ce[j + 1] = key;
  }
}

// slot-ordered GLOBAL src/dst node ids
__global__ __launch_bounds__(256) void build_sd(
    const int* __restrict__ ce, const int* __restrict__ s0,
    const int* __restrict__ s1, const int* __restrict__ s2,
    const int* __restrict__ s3, const int* __restrict__ d0,
    const int* __restrict__ d1, const int* __restrict__ d2,
    const int* __restrict__ d3, int* __restrict__ srcOf,
    int* __restrict__ dstOf) {
  int t = blockIdx.x * 256 + threadIdx.x;
  if (t >= 4 * E) return;
  int et = t / E;
  int e = ce[t];
  const int* sp = et == 0 ? s0 : et == 1 ? s1 : et == 2 ? s2 : s3;
  const int* dp = et == 0 ? d0 : et == 1 ? d1 : et == 2 ? d2 : d3;
  int sOff = et == 0 ? NA : et == 1 ? NA + NW : 0;
  int dOff = et == 0 ? 0 : et == 1 ? 0 : et == 2 ? NA : NA + NW;
  srcOf[t] = sOff + sp[e];
  dstOf[t] = dOff + dp[e];
}

// ---------------- attention ----------------
__global__ __launch_bounds__(256) void alpha_fused(
    const unsigned short* __restrict__ kqv, const int* __restrict__ srcOf,
    const int* __restrict__ dstOf, const float* __restrict__ Pl,
    float* __restrict__ alphaB) {
  int g = (blockIdx.x * 256 + threadIdx.x) >> 5;
  int lane = threadIdx.x & 31;
  if (g >= 4 * E) return;
  int h = lane >> 3;
  int d4 = (lane & 7) * 4;
  int s_ = srcOf[g], d_ = dstOf[g];
  uint2 av = *(const uint2*)(kqv + (size_t)d_ * LDK + HID + h * 32 + d4);
  uint2 bv = *(const uint2*)(kqv + (size_t)s_ * LDK + h * 32 + d4);
  float pv = bf2f((unsigned short)(av.x & 0xFFFF)) *
                 bf2f((unsigned short)(bv.x & 0xFFFF)) +
             bf2f((unsigned short)(av.x >> 16)) *
                 bf2f((unsigned short)(bv.x >> 16)) +
             bf2f((unsigned short)(av.y & 0xFFFF)) *
                 bf2f((unsigned short)(bv.y & 0xFFFF)) +
             bf2f((unsigned short)(av.y >> 16)) *
                 bf2f((unsigned short)(bv.y >> 16));
  pv += __shfl_xor(pv, 1, 32);
  pv += __shfl_xor(pv, 2, 32);
  pv += __shfl_xor(pv, 4, 32);
  if ((lane & 7) == 0) {
    int et = g / E;
    alphaB[(size_t)g * H + h] = pv * Pl[et * H + h] * SCALE;
  }
}

__global__ __launch_bounds__(256) void softmax_fused(
    const int* __restrict__ rpAll, float* __restrict__ alphaB) {
  int g = (blockIdx.x * 256 + threadIdx.x) >> 5;
  int lane = threadIdx.x & 31;
  if (g >= NTOT * H) return;
  int dl = g >> 2, h = g & 3;
  int b0, e0, b1 = 0, e1 = 0;
  size_t o0;
  const size_t EH = (size_t)E * H;
  if (dl < NA) {
    b0 = rpAll[dl]; e0 = rpAll[dl + 1];
    b1 = rpAll[(NA + 1) + dl]; e1 = rpAll[(NA + 1) + dl + 1];
    o0 = 0;
  } else if (dl < NA + NW) {
    int x = dl - NA;
    b0 = rpAll[2 * (NA + 1) + x]; e0 = rpAll[2 * (NA + 1) + x + 1];
    o0 = 2 * EH;
  } else {
    int x = dl - NA - NW;
    b0 = rpAll[2 * (NA + 1) + (NW + 1) + x];
    e0 = rpAll[2 * (NA + 1) + (NW + 1) + x + 1];
    o0 = 3 * EH;
  }
  float mx = -INFINITY;
  for (int i = b0 + lane; i < e0; i += 32)
    mx = fmaxf(mx, alphaB[o0 + (size_t)i * H + h]);
  for (int i = b1 + lane; i < e1; i += 32)
    mx = fmaxf(mx, alphaB[EH + (size_t)i * H + h]);
  #pragma unroll
  for (int m = 1; m < 32; m <<= 1) mx = fmaxf(mx, __shfl_xor(mx, m, 32));
  float den = 0.f;
  for (int i = b0 + lane; i < e0; i += 32)
    den += expf(alphaB[o0 + (size_t)i * H + h] - mx);
  for (int i = b1 + lane; i < e1; i += 32)
    den += expf(alphaB[EH + (size_t)i * H + h] - mx);
  #pragma unroll
  for (int m = 1; m < 32; m <<= 1) den += __shfl_xor(den, m, 32);
  float inv = 1.f / (den + 1e-16f);
  for (int i = b0 + lane; i < e0; i += 32)
    alphaB[o0 + (size_t)i * H + h] = expf(alphaB[o0 + (size_t)i * H + h] - mx) * inv;
  for (int i = b1 + lane; i < e1; i += 32)
    alphaB[EH + (size_t)i * H + h] = expf(alphaB[EH + (size_t)i * H + h] - mx) * inv;
}

// all-dst aggregation + gelu epilogue (so wo_ln staging is a pure copy)
__global__ __launch_bounds__(256) void agg_fused(
    const unsigned short* __restrict__ kqv, const int* __restrict__ rpAll,
    const int* __restrict__ srcOf, const float* __restrict__ alphaB,
    const float* __restrict__ Ml, unsigned short* __restrict__ out) {
  int g = (blockIdx.x * 256 + threadIdx.x) >> 5;
  int lane = threadIdx.x & 31;
  if (g >= NTOT * H) return;
  int dl = g >> 2, h = g & 3;
  const size_t EH = (size_t)E * H;
  float acc;
  if (dl < NA) {
    acc = 0.f;
    int b = rpAll[dl], e = rpAll[dl + 1];
    for (int i = b; i < e; i++)
      acc += alphaB[(size_t)i * H + h] *
             bf2f(kqv[(size_t)srcOf[i] * LDK + 2 * HID + h * 32 + lane]);
    b = rpAll[(NA + 1) + dl]; e = rpAll[(NA + 1) + dl + 1];
    for (int i = b; i < e; i++)
      acc += alphaB[EH + (size_t)i * H + h] *
             bf2f(kqv[(size_t)srcOf[(size_t)E + i] * LDK + 2 * HID + h * 32 +
                      lane]);
  } else {
    int et, x, rpo;
    if (dl < NA + NW) { et = 2; x = dl - NA; rpo = 2 * (NA + 1); }
    else { et = 3; x = dl - NA - NW; rpo = 2 * (NA + 1) + (NW + 1); }
    int b = rpAll[rpo + x], e = rpAll[rpo + x + 1];
    const float* al = alphaB + (size_t)et * EH;
    const int* so = srcOf + (size_t)et * E;
    float sv = 0.f;
    for (int i = b; i < e; i++)
      sv += al[(size_t)i * H + h] *
            bf2f(kqv[(size_t)so[i] * LDK + 2 * HID + h * 32 + lane]);
    const float* Mm = Ml + ((size_t)et * H + h) * D * D;
    acc = 0.f;
    #pragma unroll 8
    for (int d = 0; d < 32; d++) acc += __shfl(sv, d, 32) * Mm[d * 32 + lane];
  }
  out[(size_t)dl * LDK + HID + h * 32 + lane] = f2bf(gelu_exact(acc));
}

__global__ __launch_bounds__(256) void head_kernel(
    const unsigned short* __restrict__ xs0, const float* __restrict__ w_head,
    const float* __restrict__ b_head, const float* __restrict__ basep,
    float* __restrict__ out, int Nrows) {
  int wid = (blockIdx.x * 256 + threadIdx.x) >> 6;
  int lane = threadIdx.x & 63;
  if (wid >= Nrows) return;
  size_t base = (size_t)wid * HID;
  float d = bf2f(xs0[base + lane]) * w_head[lane] +
            bf2f(xs0[base + 64 + lane]) * w_head[64 + lane];
  #pragma unroll
  for (int m = 1; m < 64; m <<= 1) d += __shfl_xor(d, m, 64);
  if (lane == 0) out[wid] = basep[0] + b_head[0] + d;
}

}  // namespace

extern "C" void kernel_launch(void* const* d_in, const int* in_sizes, int n_in,
                              void* d_out, int out_size, void* d_ws,
                              size_t ws_size, hipStream_t stream) {
  const float* x_a = (const float*)d_in[0];
  const float* x_w = (const float*)d_in[1];
  const float* x_o = (const float*)d_in[2];
  const float* W_in = (const float*)d_in[3];
  const float* b_in = (const float*)d_in[4];
  const float* W_kqv = (const float*)d_in[5];
  const float* b_kqv = (const float*)d_in[6];
  const float* a_rel = (const float*)d_in[7];
  const float* m_rel = (const float*)d_in[8];
  const float* p_rel = (const float*)d_in[9];
  const float* skip_p = (const float*)d_in[10];
  const float* W_o = (const float*)d_in[11];
  const float* b_o = (const float*)d_in[12];
  const float* ln_g = (const float*)d_in[13];
  const float* ln_b = (const float*)d_in[14];
  const float* w_head = (const float*)d_in[15];
  const float* b_head = (const float*)d_in[16];
  const float* basep = (const float*)d_in[17];
  const int* srcs[4] = {(const int*)d_in[18], (const int*)d_in[20],
                        (const int*)d_in[22], (const int*)d_in[24]};
  const int* dsts[4] = {(const int*)d_in[19], (const int*)d_in[21],
                        (const int*)d_in[23], (const int*)d_in[25]};

  // ---- workspace layout (~195 MB) ----
  const size_t SZ_XS = (size_t)NTOT * HID * 2;        // bf16 xs        43.5 MB
  const size_t SZ_KQV = (size_t)NTOT * LDK * 2;       // bf16 kqv      130.6 MB
  const size_t SZ_AL = (size_t)4 * E * H * 4;         // fp32 w          9.6 MB
  const size_t SZ_WINT = (size_t)3 * 128 * 64 * 2;
  const size_t SZ_WK0T = (size_t)2 * 384 * 128 * 2;
  const size_t SZ_WOT = (size_t)6 * 128 * 128 * 2;
  const size_t SZ_WET = (size_t)2 * 384 * 128 * 2;
  const size_t SZ_BE = ((size_t)2 * 384 * 4 + 63) & ~63ull;
  const size_t SZ_SD = (size_t)4 * E * 4;
  const int CNT_TOT = 2 * NA + NW + NO;               // 270000
  const int RP_TOT = 2 * (NA + 1) + (NW + 1) + (NO + 1);
  const size_t SZ_RP = ((size_t)RP_TOT * 4 + 63) & ~63ull;
  const size_t SZ_CE = (size_t)4 * E * 4;
  const size_t SZ_CU = ((size_t)CNT_TOT * 4 + 63) & ~63ull;
  const size_t SZ_BS = 4 * 512 * 4;
  const size_t need = SZ_XS + SZ_KQV + SZ_AL + SZ_WINT + SZ_WK0T + SZ_WOT +
                      SZ_WET + SZ_BE + 2 * SZ_SD + SZ_RP + SZ_CE + 2 * SZ_CU +
                      SZ_BS;
  if (ws_size < need) return;

  char* p = (char*)d_ws;
  unsigned short* xs = (unsigned short*)p;    p += SZ_XS;
  unsigned short* kqvB = (unsigned short*)p;  p += SZ_KQV;
  float* alphaB = (float*)p;                  p += SZ_AL;
  unsigned short* WinT = (unsigned short*)p;  p += SZ_WINT;
  unsigned short* Wk0T = (unsigned short*)p;  p += SZ_WK0T;
  unsigned short* WoT = (unsigned short*)p;   p += SZ_WOT;
  unsigned short* WeT = (unsigned short*)p;   p += SZ_WET;
  float* beB = (float*)p;                     p += SZ_BE;
  int* srcOf = (int*)p;                       p += SZ_SD;
  int* dstOf = (int*)p;                       p += SZ_SD;
  int* rpAll = (int*)p;                       p += SZ_RP;
  int* ceAll = (int*)p;                       p += SZ_CE;
  int* cursor = (int*)p;                      p += SZ_CU;
  int* cnt = (int*)p;                         p += SZ_CU;
  int* bsum = (int*)p;

  const int rpOff[4] = {0, NA + 1, 2 * (NA + 1), 2 * (NA + 1) + NW + 1};
  const int cntBase[4] = {0, NA, 2 * NA, 2 * NA + NW};
  const int ndE[4] = {NA, NA, NW, NO};
  const int e4b = (4 * E + 255) / 256;
  const int nb0 = (NA + 63) / 64, nb01 = nb0 + (NW + 63) / 64;
  const int nbTot = nb01 + (NO + 63) / 64;

  // ---- CSR build (once) ----
  hipMemsetAsync(cnt, 0, (size_t)CNT_TOT * 4, stream);
  csr_hist4<<<e4b, 256, 0, stream>>>(dsts[0], dsts[1], dsts[2], dsts[3], cnt);
  for (int et = 0; et < 4; et++) {
    int nb = (ndE[et] + 255) / 256;
    scan_block<<<nb, 256, 0, stream>>>(cnt + cntBase[et], rpAll + rpOff[et],
                                       bsum + et * 512, ndE[et]);
    scan_bsums<<<1, 256, 0, stream>>>(bsum + et * 512, nb);
  }
  csr_finalize4<<<(CNT_TOT + 255) / 256, 256, 0, stream>>>(rpAll, bsum, cursor);
  csr_scatter4<<<e4b, 256, 0, stream>>>(dsts[0], dsts[1], dsts[2], dsts[3],
                                        cursor, ceAll);
  csr_sort4<<<(CNT_TOT + 255) / 256, 256, 0, stream>>>(rpAll, ceAll);
  build_sd<<<e4b, 256, 0, stream>>>(ceAll, srcs[0], srcs[1], srcs[2], srcs[3],
                                    dsts[0], dsts[1], dsts[2], dsts[3], srcOf,
                                    dstOf);

  // ---- weight prep + input projection ----
  prep_weights<<<(3 * 128 * 64 + 2 * 384 * 128 + 6 * 128 * 128 + 255) / 256,
                 256, 0, stream>>>(W_in, W_kqv, W_o, WinT, Wk0T, WoT);
  in_fused<<<nbTot, 256, 0, stream>>>(x_a, x_w, x_o, WinT, b_in, xs, nb0, nb01);

  const size_t DD = (size_t)H * D * D;
  for (int l = 0; l < 2; l++) {
    const float* Al = a_rel + (size_t)l * 4 * DD;
    const float* Ml = m_rel + (size_t)l * 4 * DD;
    const float* Pl = p_rel + (size_t)l * 4 * H;
    const float* Wl = W_kqv + (size_t)l * 3 * HID * LDK;
    const float* bl = b_kqv + (size_t)l * 3 * LDK;
    fold_weights<<<(2 * 128 * 384 + 2 * 384 + 255) / 256, 256, 0, stream>>>(
        Wl, bl, Al, Ml, WeT, beB);
    kqv_fused<<<dim3(nbTot, 3), 256, 0, stream>>>(
        xs, Wk0T + (size_t)l * 384 * 128, bl, WeT, beB, kqvB, nb0, nb01);
    alpha_fused<<<((size_t)4 * E * 32 + 255) / 256, 256, 0, stream>>>(
        kqvB, srcOf, dstOf, Pl, alphaB);
    softmax_fused<<<((size_t)NTOT * H * 32 + 255) / 256, 256, 0, stream>>>(
        rpAll, alphaB);
    agg_fused<<<((size_t)NTOT * H * 32 + 255) / 256, 256, 0, stream>>>(
        kqvB, rpAll, srcOf, alphaB, Ml, kqvB);
    wo_ln_fused<<<nbTot, 256, 0, stream>>>(
        kqvB, WoT + (size_t)l * 3 * 128 * 128, b_o + (size_t)l * 3 * HID, xs,
        skip_p + l * 3, ln_g + (size_t)l * 3 * HID, ln_b + (size_t)l * 3 * HID,
        nb0, nb01);
  }
  head_kernel<<<(NA + 3) / 4, 256, 0, stream>>>(xs, w_head, b_head, basep,
                                                (float*)d_out, NA);
}

// Round 13
// 908.758 us; speedup vs baseline: 2.4934x; 1.2489x over previous
//
#include <hip/hip_runtime.h>
#include <cstddef>
#include <cmath>

namespace {

constexpr int H = 4, D = 32, HID = 128;
constexpr int NA = 100000, NW = 20000, NO = 50000;
constexpr int NTOT = NA + NW + NO;
constexpr int E = 150000;
constexpr float SCALE = 0.17677669529663687f;  // 1/sqrt(32)
constexpr int LDK = 3 * HID;  // kqv row stride (384)

typedef __attribute__((ext_vector_type(8))) short short8v;
typedef __attribute__((ext_vector_type(4))) float f32x4;

__device__ __forceinline__ float gelu_exact(float x) {
  return 0.5f * x * (1.f + erff(x * 0.7071067811865475f));
}
__device__ __forceinline__ unsigned short f2bf(float f) {  // RNE
  unsigned u = __float_as_uint(f);
  return (unsigned short)((u + 0x7FFF + ((u >> 16) & 1)) >> 16);
}
__device__ __forceinline__ float bf2f(unsigned short s) {
  return __uint_as_float(((unsigned)s) << 16);
}

__device__ __forceinline__ int btype(int bx, int nb0, int nb01) {
  return bx < nb0 ? 0 : (bx < nb01 ? 1 : 2);
}

// ---------------- swizzled BK=64 MFMA GEMM body ----------------
template <int KSTEPS, bool A_FP32>
__device__ __forceinline__ void gemm_body(
    const void* __restrict__ Av, int lda, const unsigned short* __restrict__ BT,
    int ldb, f32x4* acc, int M, int bm) {
  __shared__ unsigned short As[64 * 64];
  __shared__ unsigned short Bs[128 * 64];
  const int tid = threadIdx.x;
  const int wv = tid >> 6, l = tid & 63;
  for (int ks = 0; ks < KSTEPS; ks++) {
    const int kk = ks * 64;
    #pragma unroll
    for (int p = 0; p < 2; p++) {
      int idx = tid + p * 256;
      int r = idx >> 3, c = idx & 7;
      int gr = bm + r;
      unsigned short tmp[8] = {0, 0, 0, 0, 0, 0, 0, 0};
      if (gr < M) {
        if (A_FP32) {
          const float* src = (const float*)Av + (size_t)gr * lda + kk + c * 8;
          float4 f0 = *(const float4*)src;
          float4 f1 = *(const float4*)(src + 4);
          tmp[0] = f2bf(f0.x); tmp[1] = f2bf(f0.y);
          tmp[2] = f2bf(f0.z); tmp[3] = f2bf(f0.w);
          tmp[4] = f2bf(f1.x); tmp[5] = f2bf(f1.y);
          tmp[6] = f2bf(f1.z); tmp[7] = f2bf(f1.w);
        } else {
          *(uint4*)tmp = *(const uint4*)((const unsigned short*)Av +
                                         (size_t)gr * lda + kk + c * 8);
        }
      }
      *(uint4*)&As[r * 64 + ((c ^ (r & 7)) * 8)] = *(const uint4*)tmp;
    }
    #pragma unroll
    for (int p = 0; p < 4; p++) {
      int idx = tid + p * 256;
      int r = idx >> 3, c = idx & 7;
      uint4 v = *(const uint4*)(BT + (size_t)r * ldb + kk + c * 8);
      *(uint4*)&Bs[r * 64 + ((c ^ (r & 7)) * 8)] = v;
    }
    __syncthreads();
    const int arow = wv * 16 + (l & 15);
    #pragma unroll
    for (int ksub = 0; ksub < 2; ksub++) {
      int ch = ksub * 4 + (l >> 4);
      short8v af = *(const short8v*)&As[arow * 64 + ((ch ^ (arow & 7)) * 8)];
      #pragma unroll
      for (int n = 0; n < 8; n++) {
        int brow = n * 16 + (l & 15);
        short8v bf =
            *(const short8v*)&Bs[brow * 64 + ((ch ^ (brow & 7)) * 8)];
        acc[n] =
            __builtin_amdgcn_mfma_f32_16x16x32_bf16(af, bf, acc[n], 0, 0, 0);
      }
    }
    __syncthreads();
  }
}

// ---------------- weight prep: bf16 transposed copies ----------------
__global__ __launch_bounds__(256) void prep_weights(
    const float* __restrict__ W_in, const float* __restrict__ W_kqv,
    const float* __restrict__ W_o, unsigned short* __restrict__ WinT,
    unsigned short* __restrict__ Wk0T, unsigned short* __restrict__ WoT) {
  int idx = blockIdx.x * 256 + threadIdx.x;
  const int N1 = 3 * 128 * 64, N2 = 2 * 384 * 128, N3 = 6 * 128 * 128;
  if (idx < N1) {
    int t = idx / 8192, rem = idx - t * 8192;
    int n = rem >> 6, k = rem & 63;
    WinT[idx] = f2bf(W_in[(size_t)t * 64 * 128 + (size_t)k * 128 + n]);
  } else if (idx < N1 + N2) {
    int r = idx - N1;
    int lyr = r / (384 * 128), rem = r - lyr * (384 * 128);
    int n = rem >> 7, k = rem & 127;
    Wk0T[r] = f2bf(W_kqv[(size_t)lyr * 3 * 128 * 384 + (size_t)k * 384 + n]);
  } else if (idx < N1 + N2 + N3) {
    int r = idx - N1 - N2;
    int lt = r / (128 * 128), rem = r - lt * (128 * 128);
    int n = rem >> 7, k = rem & 127;
    WoT[r] = f2bf(W_o[(size_t)lt * 128 * 128 + (size_t)k * 128 + n]);
  }
}

// ---------------- weight folding (per layer) -> bf16 transposed ----------
__global__ __launch_bounds__(256) void fold_weights(
    const float* __restrict__ Wl, const float* __restrict__ bl,
    const float* __restrict__ Al, const float* __restrict__ Ml,
    unsigned short* __restrict__ WeT, float* __restrict__ be) {
  int idx = blockIdx.x * 256 + threadIdx.x;
  const int NW_ = 2 * 128 * 384;
  if (idx < NW_) {
    int tt = idx / (128 * 384);
    int rem = idx - tt * (128 * 384);
    int r = rem / 384, c = rem - r * 384;
    int slice = c >> 7, h = (c >> 5) & 3, j = c & 31;
    const float* Wsrc = Wl + (size_t)(tt + 1) * 128 * 384 + (size_t)r * 384;
    float acc = 0.f;
    if (slice == 0) {
      const float* A = Al + ((size_t)tt * H + h) * D * D;
      for (int d = 0; d < 32; d++) acc += Wsrc[h * 32 + d] * A[d * 32 + j];
    } else if (slice == 1) {
      const float* A = Al + ((size_t)(2 + tt) * H + h) * D * D;
      for (int e = 0; e < 32; e++)
        acc += Wsrc[128 + h * 32 + e] * A[j * 32 + e];
    } else {
      const float* Mm = Ml + ((size_t)tt * H + h) * D * D;
      for (int d = 0; d < 32; d++)
        acc += Wsrc[256 + h * 32 + d] * Mm[d * 32 + j];
    }
    WeT[(size_t)tt * 384 * 128 + (size_t)c * 128 + r] = f2bf(acc);
  } else if (idx < NW_ + 2 * 384) {
    int rem = idx - NW_;
    int tt = rem / 384, c = rem - tt * 384;
    int slice = c >> 7, h = (c >> 5) & 3, j = c & 31;
    const float* bsrc = bl + (size_t)(tt + 1) * 384;
    float acc = 0.f;
    if (slice == 0) {
      const float* A = Al + ((size_t)tt * H + h) * D * D;
      for (int d = 0; d < 32; d++) acc += bsrc[h * 32 + d] * A[d * 32 + j];
    } else if (slice == 1) {
      const float* A = Al + ((size_t)(2 + tt) * H + h) * D * D;
      for (int e = 0; e < 32; e++)
        acc += bsrc[128 + h * 32 + e] * A[j * 32 + e];
    } else {
      const float* Mm = Ml + ((size_t)tt * H + h) * D * D;
      for (int d = 0; d < 32; d++)
        acc += bsrc[256 + h * 32 + d] * Mm[d * 32 + j];
    }
    be[rem] = acc;
  }
}

// input proj: xs = relu(x @ W_in[t] + b_in[t])
__global__ __launch_bounds__(256) void in_fused(
    const float* __restrict__ xa, const float* __restrict__ xw,
    const float* __restrict__ xo, const unsigned short* __restrict__ WinT,
    const float* __restrict__ b_in, unsigned short* __restrict__ xs, int nb0,
    int nb01) {
  int t = btype(blockIdx.x, nb0, nb01);
  int base = t == 0 ? 0 : (t == 1 ? nb0 : nb01);
  int M = t == 0 ? NA : (t == 1 ? NW : NO);
  int off = t == 0 ? 0 : (t == 1 ? NA : NA + NW);
  const float* A = t == 0 ? xa : (t == 1 ? xw : xo);
  const int bm = (blockIdx.x - base) * 64;
  f32x4 acc[8] = {};
  gemm_body<1, true>(A, 64, WinT + (size_t)t * 128 * 64, 64, acc, M, bm);
  const int l = threadIdx.x & 63, wv = threadIdx.x >> 6;
  const float* bias = b_in + t * HID;
  unsigned short* C = xs + (size_t)off * HID;
  #pragma unroll
  for (int n = 0; n < 8; n++) {
    int col = n * 16 + (l & 15);
    float bb = bias[col];
    #pragma unroll
    for (int j = 0; j < 4; j++) {
      int row = bm + wv * 16 + (l >> 4) * 4 + j;
      if (row < M) C[(size_t)row * HID + col] = f2bf(fmaxf(acc[n][j] + bb, 0.f));
    }
  }
}

// kqv proj: t=0 raw Wk0T; t=1,2 folded WeT. 64x128 tile, y = col-tile (3).
__global__ __launch_bounds__(256) void kqv_fused(
    const unsigned short* __restrict__ xs, const unsigned short* __restrict__ Wk0Tl,
    const float* __restrict__ b0, const unsigned short* __restrict__ WeT,
    const float* __restrict__ be, unsigned short* __restrict__ kqvB, int nb0,
    int nb01) {
  int t = btype(blockIdx.x, nb0, nb01);
  int base = t == 0 ? 0 : (t == 1 ? nb0 : nb01);
  int M = t == 0 ? NA : (t == 1 ? NW : NO);
  int off = t == 0 ? 0 : (t == 1 ? NA : NA + NW);
  const unsigned short* BT =
      (t == 0 ? Wk0Tl : WeT + (size_t)(t - 1) * 384 * 128);
  const float* bias = t == 0 ? b0 : be + (size_t)(t - 1) * 384;
  const int bm = (blockIdx.x - base) * 64;
  const int bn = blockIdx.y * 128;
  f32x4 acc[8] = {};
  gemm_body<2, false>(xs + (size_t)off * HID, HID, BT + (size_t)bn * 128, 128,
                      acc, M, bm);
  const int l = threadIdx.x & 63, wv = threadIdx.x >> 6;
  unsigned short* C = kqvB + (size_t)off * LDK;
  #pragma unroll
  for (int n = 0; n < 8; n++) {
    int col = bn + n * 16 + (l & 15);
    float bb = bias[col];
    #pragma unroll
    for (int j = 0; j < 4; j++) {
      int row = bm + wv * 16 + (l >> 4) * 4 + j;
      if (row < M) C[(size_t)row * LDK + col] = f2bf(acc[n][j] + bb);
    }
  }
}

// fused: xs = relu(LN( g*(agg_gelu @ W_o + b_o) + (1-g)*xs ))
__global__ __launch_bounds__(256) void wo_ln_fused(
    const unsigned short* __restrict__ kqvB, const unsigned short* __restrict__ WoTl,
    const float* __restrict__ bl, unsigned short* __restrict__ xs,
    const float* __restrict__ skipl, const float* __restrict__ gll,
    const float* __restrict__ bll, int nb0, int nb01) {
  int t = btype(blockIdx.x, nb0, nb01);
  int base = t == 0 ? 0 : (t == 1 ? nb0 : nb01);
  int M = t == 0 ? NA : (t == 1 ? NW : NO);
  int off = t == 0 ? 0 : (t == 1 ? NA : NA + NW);
  const int bm = (blockIdx.x - base) * 64;
  f32x4 acc[8] = {};
  gemm_body<2, false>(kqvB + (size_t)off * LDK + HID, LDK,
                      WoTl + (size_t)t * 128 * 128, 128, acc, M, bm);
  const int l = threadIdx.x & 63, wv = threadIdx.x >> 6;
  const float* bias = bl + t * HID;
  const float* gln = gll + t * HID;
  const float* bln = bll + t * HID;
  unsigned short* xsT = xs + (size_t)off * HID;
  const float g = 1.f / (1.f + expf(-skipl[t]));
  float bb[8], gl8[8], bl8[8];
  #pragma unroll
  for (int n = 0; n < 8; n++) {
    int col = n * 16 + (l & 15);
    bb[n] = bias[col];
    gl8[n] = gln[col];
    bl8[n] = bln[col];
  }
  #pragma unroll
  for (int j = 0; j < 4; j++) {
    int row = bm + wv * 16 + (l >> 4) * 4 + j;
    bool ok = row < M;
    float vv[8], sum = 0.f, sq = 0.f;
    #pragma unroll
    for (int n = 0; n < 8; n++) {
      int col = n * 16 + (l & 15);
      float xo = ok ? bf2f(xsT[(size_t)row * HID + col]) : 0.f;
      float val = g * (acc[n][j] + bb[n]) + (1.f - g) * xo;
      vv[n] = val;
      sum += val;
      sq += val * val;
    }
    #pragma unroll
    for (int m = 1; m < 16; m <<= 1) {
      sum += __shfl_xor(sum, m, 64);
      sq += __shfl_xor(sq, m, 64);
    }
    float mu = sum * (1.f / 128.f);
    float var = sq * (1.f / 128.f) - mu * mu;
    float r = rsqrtf(var + 1e-5f);
    if (ok) {
      #pragma unroll
      for (int n = 0; n < 8; n++) {
        float y = fmaxf((vv[n] - mu) * r * gl8[n] + bl8[n], 0.f);
        xsT[(size_t)row * HID + n * 16 + (l & 15)] = f2bf(y);
      }
    }
  }
}

// ---------------- CSR build (deterministic, 4 ets fused) ----------------
__global__ __launch_bounds__(256) void csr_hist4(
    const int* __restrict__ d0, const int* __restrict__ d1,
    const int* __restrict__ d2, const int* __restrict__ d3,
    int* __restrict__ cnt) {
  int t = blockIdx.x * 256 + threadIdx.x;
  if (t >= 4 * E) return;
  int et = t / E, e = t - et * E;
  const int* dp = et == 0 ? d0 : et == 1 ? d1 : et == 2 ? d2 : d3;
  int base = et == 0 ? 0 : et == 1 ? NA : et == 2 ? 2 * NA : 2 * NA + NW;
  atomicAdd(&cnt[base + dp[e]], 1);
}

__global__ __launch_bounds__(256) void scan_block(const int* __restrict__ cnt,
                                                  int* __restrict__ excl,
                                                  int* __restrict__ bsum,
                                                  int n) {
  __shared__ int tmp[256];
  int i = blockIdx.x * 256 + threadIdx.x;
  int v = (i < n) ? cnt[i] : 0;
  tmp[threadIdx.x] = v;
  __syncthreads();
  int acc = v;
  for (int off = 1; off < 256; off <<= 1) {
    int other = (threadIdx.x >= off) ? tmp[threadIdx.x - off] : 0;
    __syncthreads();
    acc += other;
    tmp[threadIdx.x] = acc;
    __syncthreads();
  }
  if (i < n) excl[i] = acc - v;
  if (threadIdx.x == 255) bsum[blockIdx.x] = acc;
}

__global__ __launch_bounds__(256) void scan_bsums(int* __restrict__ bsum,
                                                  int nb) {
  __shared__ int tmp[256];
  __shared__ int carry;
  if (threadIdx.x == 0) carry = 0;
  __syncthreads();
  for (int start = 0; start < nb; start += 256) {
    int i = start + threadIdx.x;
    int v = (i < nb) ? bsum[i] : 0;
    tmp[threadIdx.x] = v;
    __syncthreads();
    int acc = v;
    for (int off = 1; off < 256; off <<= 1) {
      int other = (threadIdx.x >= off) ? tmp[threadIdx.x - off] : 0;
      __syncthreads();
      acc += other;
      tmp[threadIdx.x] = acc;
      __syncthreads();
    }
    int c = carry;
    if (i < nb) bsum[i] = c + acc - v;
    __syncthreads();
    if (threadIdx.x == 255) carry = c + acc;
    __syncthreads();
  }
}

__device__ __forceinline__ void et_of_node(int i, int& et, int& base, int& nd,
                                           int& rpo) {
  if (i < NA) { et = 0; base = 0; nd = NA; rpo = 0; }
  else if (i < 2 * NA) { et = 1; base = NA; nd = NA; rpo = NA + 1; }
  else if (i < 2 * NA + NW) { et = 2; base = 2 * NA; nd = NW; rpo = 2 * (NA + 1); }
  else { et = 3; base = 2 * NA + NW; nd = NO; rpo = 2 * (NA + 1) + NW + 1; }
}

__global__ __launch_bounds__(256) void csr_finalize4(
    int* __restrict__ rpAll, const int* __restrict__ bsum,
    int* __restrict__ cursor) {
  int i = blockIdx.x * 256 + threadIdx.x;
  if (i >= 2 * NA + NW + NO) return;
  int et, base, nd, rpo;
  et_of_node(i, et, base, nd, rpo);
  int local = i - base;
  int v = rpAll[rpo + local] + bsum[et * 512 + (local >> 8)];
  rpAll[rpo + local] = v;
  cursor[base + local] = v;
  if (local == 0) rpAll[rpo + nd] = E;
}

__global__ __launch_bounds__(256) void csr_scatter4(
    const int* __restrict__ d0, const int* __restrict__ d1,
    const int* __restrict__ d2, const int* __restrict__ d3,
    int* __restrict__ cursor, int* __restrict__ ceAll) {
  int t = blockIdx.x * 256 + threadIdx.x;
  if (t >= 4 * E) return;
  int et = t / E, e = t - et * E;
  const int* dp = et == 0 ? d0 : et == 1 ? d1 : et == 2 ? d2 : d3;
  int base = et == 0 ? 0 : et == 1 ? NA : et == 2 ? 2 * NA : 2 * NA + NW;
  int slot = atomicAdd(&cursor[base + dp[e]], 1);
  ceAll[(size_t)et * E + slot] = e;
}

__global__ __launch_bounds__(256) void csr_sort4(const int* __restrict__ rpAll,
                                                 int* __restrict__ ceAll) {
  int i = blockIdx.x * 256 + threadIdx.x;
  if (i >= 2 * NA + NW + NO) return;
  int et, base, nd, rpo;
  et_of_node(i, et, base, nd, rpo);
  int local = i - base;
  int b = rpAll[rpo + local], e = rpAll[rpo + local + 1];
  int* ce = ceAll + (size_t)et * E;
  for (int k = b + 1; k < e; k++) {
    int key = ce[k];
    int j = k - 1;
    while (j >= b && ce[j] > key) { ce[j + 1] = ce[j]; j--; }
    ce[j + 1] = key;
  }
}

// slot-ordered GLOBAL src/dst node ids
__global__ __launch_bounds__(256) void build_sd(
    const int* __restrict__ ce, const int* __restrict__ s0,
    const int* __restrict__ s1, const int* __restrict__ s2,
    const int* __restrict__ s3, const int* __restrict__ d0,
    const int* __restrict__ d1, const int* __restrict__ d2,
    const int* __restrict__ d3, int* __restrict__ srcOf,
    int* __restrict__ dstOf) {
  int t = blockIdx.x * 256 + threadIdx.x;
  if (t >= 4 * E) return;
  int et = t / E;
  int e = ce[t];
  const int* sp = et == 0 ? s0 : et == 1 ? s1 : et == 2 ? s2 : s3;
  const int* dp = et == 0 ? d0 : et == 1 ? d1 : et == 2 ? d2 : d3;
  int sOff = et == 0 ? NA : et == 1 ? NA + NW : 0;
  int dOff = et == 0 ? 0 : et == 1 ? 0 : et == 2 ? NA : NA + NW;
  srcOf[t] = sOff + sp[e];
  dstOf[t] = dOff + dp[e];
}

// ---------------- attention ----------------
__global__ __launch_bounds__(256) void alpha_fused(
    const unsigned short* __restrict__ kqv, const int* __restrict__ srcOf,
    const int* __restrict__ dstOf, const float* __restrict__ Pl,
    float* __restrict__ alphaB) {
  int g = (blockIdx.x * 256 + threadIdx.x) >> 5;
  int lane = threadIdx.x & 31;
  if (g >= 4 * E) return;
  int h = lane >> 3;
  int d4 = (lane & 7) * 4;
  int s_ = srcOf[g], d_ = dstOf[g];
  uint2 av = *(const uint2*)(kqv + (size_t)d_ * LDK + HID + h * 32 + d4);
  uint2 bv = *(const uint2*)(kqv + (size_t)s_ * LDK + h * 32 + d4);
  float pv = bf2f((unsigned short)(av.x & 0xFFFF)) *
                 bf2f((unsigned short)(bv.x & 0xFFFF)) +
             bf2f((unsigned short)(av.x >> 16)) *
                 bf2f((unsigned short)(bv.x >> 16)) +
             bf2f((unsigned short)(av.y & 0xFFFF)) *
                 bf2f((unsigned short)(bv.y & 0xFFFF)) +
             bf2f((unsigned short)(av.y >> 16)) *
                 bf2f((unsigned short)(bv.y >> 16));
  pv += __shfl_xor(pv, 1, 32);
  pv += __shfl_xor(pv, 2, 32);
  pv += __shfl_xor(pv, 4, 32);
  if ((lane & 7) == 0) {
    int et = g / E;
    alphaB[(size_t)g * H + h] = pv * Pl[et * H + h] * SCALE;
  }
}

// one 64-lane wave per dst node: in-wave softmax (per head quarter) +
// single-request 256B v gathers + (W/O) per-dst M transform + gelu.
__global__ __launch_bounds__(256) void agg_all(
    const unsigned short* __restrict__ kqv, const int* __restrict__ rpAll,
    const int* __restrict__ srcOf, const float* __restrict__ alphaB,
    const float* __restrict__ Ml, unsigned short* __restrict__ out) {
  int dl = (blockIdx.x * 256 + threadIdx.x) >> 6;
  int lane = threadIdx.x & 63;
  if (dl >= NTOT) return;
  int q = lane >> 4, p = lane & 15;  // head quarter, pos within quarter
  const size_t EH = (size_t)E * H;
  int b0, e0, b1 = 0, e1 = 0, et23 = -1;
  const float* al0;
  const int* so0;
  const float* al1 = alphaB;
  const int* so1 = srcOf;
  if (dl < NA) {
    b0 = rpAll[dl]; e0 = rpAll[dl + 1];
    b1 = rpAll[(NA + 1) + dl]; e1 = rpAll[(NA + 1) + dl + 1];
    al0 = alphaB; so0 = srcOf;
    al1 = alphaB + EH; so1 = srcOf + E;
  } else if (dl < NA + NW) {
    int x = dl - NA;
    b0 = rpAll[2 * (NA + 1) + x]; e0 = rpAll[2 * (NA + 1) + x + 1];
    al0 = alphaB + 2 * EH; so0 = srcOf + 2 * (size_t)E;
    et23 = 2;
  } else {
    int x = dl - NA - NW;
    b0 = rpAll[2 * (NA + 1) + (NW + 1) + x];
    e0 = rpAll[2 * (NA + 1) + (NW + 1) + x + 1];
    al0 = alphaB + 3 * EH; so0 = srcOf + 3 * (size_t)E;
    et23 = 3;
  }
  // phase 1: per-quarter max (coalesced alpha reads across the wave)
  float mx = -INFINITY;
  for (int i = b0 + p; i < e0; i += 16) mx = fmaxf(mx, al0[(size_t)i * 4 + q]);
  for (int i = b1 + p; i < e1; i += 16) mx = fmaxf(mx, al1[(size_t)i * 4 + q]);
  #pragma unroll
  for (int m = 1; m < 16; m <<= 1) mx = fmaxf(mx, __shfl_xor(mx, m, 16));
  // phase 2: per-quarter den
  float den = 0.f;
  for (int i = b0 + p; i < e0; i += 16)
    den += expf(al0[(size_t)i * 4 + q] - mx);
  for (int i = b1 + p; i < e1; i += 16)
    den += expf(al1[(size_t)i * 4 + q] - mx);
  #pragma unroll
  for (int m = 1; m < 16; m <<= 1) den += __shfl_xor(den, m, 16);
  float inv = 1.f / (den + 1e-16f);
  // phase 3: gather (one 256B request per edge), weight on the fly
  float ax = 0.f, ay = 0.f;
  const int npass = (dl < NA) ? 2 : 1;
  for (int pass = 0; pass < npass; pass++) {
    int b = pass ? b1 : b0, e = pass ? e1 : e0;
    const float* al = pass ? al1 : al0;
    const int* so = pass ? so1 : so0;
    for (int i = b; i < e; i++) {
      float w = expf(al[(size_t)i * 4 + q] - mx) * inv;
      int row = so[i];
      unsigned vv =
          *(const unsigned*)(kqv + (size_t)row * LDK + 2 * HID + lane * 2);
      ax += w * bf2f((unsigned short)(vv & 0xFFFF));
      ay += w * bf2f((unsigned short)(vv >> 16));
    }
  }
  // W/O dst: M transform (dims d=2j,2j+1 live in lanes of this quarter)
  if (et23 >= 0) {
    const float* Mm = Ml + ((size_t)et23 * H + q) * D * D;
    int base = lane & 48;
    float o0 = 0.f, o1 = 0.f;
    #pragma unroll
    for (int j = 0; j < 16; j++) {
      float s0 = __shfl(ax, base + j, 64);
      float s1 = __shfl(ay, base + j, 64);
      float2 m0 = *(const float2*)&Mm[(2 * j) * 32 + 2 * p];
      float2 m1 = *(const float2*)&Mm[(2 * j + 1) * 32 + 2 * p];
      o0 += s0 * m0.x + s1 * m1.x;
      o1 += s0 * m0.y + s1 * m1.y;
    }
    ax = o0; ay = o1;
  }
  unsigned ov = (unsigned)f2bf(gelu_exact(ax)) |
                ((unsigned)f2bf(gelu_exact(ay)) << 16);
  *(unsigned*)(out + (size_t)dl * LDK + HID + lane * 2) = ov;
}

__global__ __launch_bounds__(256) void head_kernel(
    const unsigned short* __restrict__ xs0, const float* __restrict__ w_head,
    const float* __restrict__ b_head, const float* __restrict__ basep,
    float* __restrict__ out, int Nrows) {
  int wid = (blockIdx.x * 256 + threadIdx.x) >> 6;
  int lane = threadIdx.x & 63;
  if (wid >= Nrows) return;
  size_t base = (size_t)wid * HID;
  float d = bf2f(xs0[base + lane]) * w_head[lane] +
            bf2f(xs0[base + 64 + lane]) * w_head[64 + lane];
  #pragma unroll
  for (int m = 1; m < 64; m <<= 1) d += __shfl_xor(d, m, 64);
  if (lane == 0) out[wid] = basep[0] + b_head[0] + d;
}

}  // namespace

extern "C" void kernel_launch(void* const* d_in, const int* in_sizes, int n_in,
                              void* d_out, int out_size, void* d_ws,
                              size_t ws_size, hipStream_t stream) {
  const float* x_a = (const float*)d_in[0];
  const float* x_w = (const float*)d_in[1];
  const float* x_o = (const float*)d_in[2];
  const float* W_in = (const float*)d_in[3];
  const float* b_in = (const float*)d_in[4];
  const float* W_kqv = (const float*)d_in[5];
  const float* b_kqv = (const float*)d_in[6];
  const float* a_rel = (const float*)d_in[7];
  const float* m_rel = (const float*)d_in[8];
  const float* p_rel = (const float*)d_in[9];
  const float* skip_p = (const float*)d_in[10];
  const float* W_o = (const float*)d_in[11];
  const float* b_o = (const float*)d_in[12];
  const float* ln_g = (const float*)d_in[13];
  const float* ln_b = (const float*)d_in[14];
  const float* w_head = (const float*)d_in[15];
  const float* b_head = (const float*)d_in[16];
  const float* basep = (const float*)d_in[17];
  const int* srcs[4] = {(const int*)d_in[18], (const int*)d_in[20],
                        (const int*)d_in[22], (const int*)d_in[24]};
  const int* dsts[4] = {(const int*)d_in[19], (const int*)d_in[21],
                        (const int*)d_in[23], (const int*)d_in[25]};

  // ---- workspace layout (~195 MB) ----
  const size_t SZ_XS = (size_t)NTOT * HID * 2;
  const size_t SZ_KQV = (size_t)NTOT * LDK * 2;
  const size_t SZ_AL = (size_t)4 * E * H * 4;
  const size_t SZ_WINT = (size_t)3 * 128 * 64 * 2;
  const size_t SZ_WK0T = (size_t)2 * 384 * 128 * 2;
  const size_t SZ_WOT = (size_t)6 * 128 * 128 * 2;
  const size_t SZ_WET = (size_t)2 * 384 * 128 * 2;
  const size_t SZ_BE = ((size_t)2 * 384 * 4 + 63) & ~63ull;
  const size_t SZ_SD = (size_t)4 * E * 4;
  const int CNT_TOT = 2 * NA + NW + NO;
  const int RP_TOT = 2 * (NA + 1) + (NW + 1) + (NO + 1);
  const size_t SZ_RP = ((size_t)RP_TOT * 4 + 63) & ~63ull;
  const size_t SZ_CE = (size_t)4 * E * 4;
  const size_t SZ_CU = ((size_t)CNT_TOT * 4 + 63) & ~63ull;
  const size_t SZ_BS = 4 * 512 * 4;
  const size_t need = SZ_XS + SZ_KQV + SZ_AL + SZ_WINT + SZ_WK0T + SZ_WOT +
                      SZ_WET + SZ_BE + 2 * SZ_SD + SZ_RP + SZ_CE + 2 * SZ_CU +
                      SZ_BS;
  if (ws_size < need) return;

  char* p = (char*)d_ws;
  unsigned short* xs = (unsigned short*)p;    p += SZ_XS;
  unsigned short* kqvB = (unsigned short*)p;  p += SZ_KQV;
  float* alphaB = (float*)p;                  p += SZ_AL;
  unsigned short* WinT = (unsigned short*)p;  p += SZ_WINT;
  unsigned short* Wk0T = (unsigned short*)p;  p += SZ_WK0T;
  unsigned short* WoT = (unsigned short*)p;   p += SZ_WOT;
  unsigned short* WeT = (unsigned short*)p;   p += SZ_WET;
  float* beB = (float*)p;                     p += SZ_BE;
  int* srcOf = (int*)p;                       p += SZ_SD;
  int* dstOf = (int*)p;                       p += SZ_SD;
  int* rpAll = (int*)p;                       p += SZ_RP;
  int* ceAll = (int*)p;                       p += SZ_CE;
  int* cursor = (int*)p;                      p += SZ_CU;
  int* cnt = (int*)p;                         p += SZ_CU;
  int* bsum = (int*)p;

  const int rpOff[4] = {0, NA + 1, 2 * (NA + 1), 2 * (NA + 1) + NW + 1};
  const int cntBase[4] = {0, NA, 2 * NA, 2 * NA + NW};
  const int ndE[4] = {NA, NA, NW, NO};
  const int e4b = (4 * E + 255) / 256;
  const int nb0 = (NA + 63) / 64, nb01 = nb0 + (NW + 63) / 64;
  const int nbTot = nb01 + (NO + 63) / 64;

  // ---- CSR build (once) ----
  hipMemsetAsync(cnt, 0, (size_t)CNT_TOT * 4, stream);
  csr_hist4<<<e4b, 256, 0, stream>>>(dsts[0], dsts[1], dsts[2], dsts[3], cnt);
  for (int et = 0; et < 4; et++) {
    int nb = (ndE[et] + 255) / 256;
    scan_block<<<nb, 256, 0, stream>>>(cnt + cntBase[et], rpAll + rpOff[et],
                                       bsum + et * 512, ndE[et]);
    scan_bsums<<<1, 256, 0, stream>>>(bsum + et * 512, nb);
  }
  csr_finalize4<<<(CNT_TOT + 255) / 256, 256, 0, stream>>>(rpAll, bsum, cursor);
  csr_scatter4<<<e4b, 256, 0, stream>>>(dsts[0], dsts[1], dsts[2], dsts[3],
                                        cursor, ceAll);
  csr_sort4<<<(CNT_TOT + 255) / 256, 256, 0, stream>>>(rpAll, ceAll);
  build_sd<<<e4b, 256, 0, stream>>>(ceAll, srcs[0], srcs[1], srcs[2], srcs[3],
                                    dsts[0], dsts[1], dsts[2], dsts[3], srcOf,
                                    dstOf);

  // ---- weight prep + input projection ----
  prep_weights<<<(3 * 128 * 64 + 2 * 384 * 128 + 6 * 128 * 128 + 255) / 256,
                 256, 0, stream>>>(W_in, W_kqv, W_o, WinT, Wk0T, WoT);
  in_fused<<<nbTot, 256, 0, stream>>>(x_a, x_w, x_o, WinT, b_in, xs, nb0, nb01);

  const size_t DD = (size_t)H * D * D;
  for (int l = 0; l < 2; l++) {
    const float* Al = a_rel + (size_t)l * 4 * DD;
    const float* Ml = m_rel + (size_t)l * 4 * DD;
    const float* Pl = p_rel + (size_t)l * 4 * H;
    const float* Wl = W_kqv + (size_t)l * 3 * HID * LDK;
    const float* bl = b_kqv + (size_t)l * 3 * LDK;
    fold_weights<<<(2 * 128 * 384 + 2 * 384 + 255) / 256, 256, 0, stream>>>(
        Wl, bl, Al, Ml, WeT, beB);
    kqv_fused<<<dim3(nbTot, 3), 256, 0, stream>>>(
        xs, Wk0T + (size_t)l * 384 * 128, bl, WeT, beB, kqvB, nb0, nb01);
    alpha_fused<<<((size_t)4 * E * 32 + 255) / 256, 256, 0, stream>>>(
        kqvB, srcOf, dstOf, Pl, alphaB);
    agg_all<<<((size_t)NTOT * 64 + 255) / 256, 256, 0, stream>>>(
        kqvB, rpAll, srcOf, alphaB, Ml, kqvB);
    wo_ln_fused<<<nbTot, 256, 0, stream>>>(
        kqvB, WoT + (size_t)l * 3 * 128 * 128, b_o + (size_t)l * 3 * HID, xs,
        skip_p + l * 3, ln_g + (size_t)l * 3 * HID, ln_b + (size_t)l * 3 * HID,
        nb0, nb01);
  }
  head_kernel<<<(NA + 3) / 4, 256, 0, stream>>>(xs, w_head, b_head, basep,
                                                (float*)d_out, NA);
}

// Round 14
// 903.551 us; speedup vs baseline: 2.5078x; 1.0058x over previous
//
#include <hip/hip_runtime.h>
#include <cstddef>
#include <cmath>

namespace {

constexpr int H = 4, D = 32, HID = 128;
constexpr int NA = 100000, NW = 20000, NO = 50000;
constexpr int NTOT = NA + NW + NO;
constexpr int E = 150000;
constexpr float SCALE = 0.17677669529663687f;  // 1/sqrt(32)
constexpr int LDK = 3 * HID;  // kqv row stride (384)
constexpr int MAXDEG = 64;    // LDS alpha scratch per dst (overflow -> recompute)

typedef __attribute__((ext_vector_type(8))) short short8v;
typedef __attribute__((ext_vector_type(4))) float f32x4;

__device__ __forceinline__ float gelu_exact(float x) {
  return 0.5f * x * (1.f + erff(x * 0.7071067811865475f));
}
__device__ __forceinline__ unsigned short f2bf(float f) {  // RNE
  unsigned u = __float_as_uint(f);
  return (unsigned short)((u + 0x7FFF + ((u >> 16) & 1)) >> 16);
}
__device__ __forceinline__ float bf2f(unsigned short s) {
  return __uint_as_float(((unsigned)s) << 16);
}

__device__ __forceinline__ int btype(int bx, int nb0, int nb01) {
  return bx < nb0 ? 0 : (bx < nb01 ? 1 : 2);
}

// ---------------- swizzled BK=64 MFMA GEMM body ----------------
template <int KSTEPS, bool A_FP32>
__device__ __forceinline__ void gemm_body(
    const void* __restrict__ Av, int lda, const unsigned short* __restrict__ BT,
    int ldb, f32x4* acc, int M, int bm) {
  __shared__ unsigned short As[64 * 64];
  __shared__ unsigned short Bs[128 * 64];
  const int tid = threadIdx.x;
  const int wv = tid >> 6, l = tid & 63;
  for (int ks = 0; ks < KSTEPS; ks++) {
    const int kk = ks * 64;
    #pragma unroll
    for (int p = 0; p < 2; p++) {
      int idx = tid + p * 256;
      int r = idx >> 3, c = idx & 7;
      int gr = bm + r;
      unsigned short tmp[8] = {0, 0, 0, 0, 0, 0, 0, 0};
      if (gr < M) {
        if (A_FP32) {
          const float* src = (const float*)Av + (size_t)gr * lda + kk + c * 8;
          float4 f0 = *(const float4*)src;
          float4 f1 = *(const float4*)(src + 4);
          tmp[0] = f2bf(f0.x); tmp[1] = f2bf(f0.y);
          tmp[2] = f2bf(f0.z); tmp[3] = f2bf(f0.w);
          tmp[4] = f2bf(f1.x); tmp[5] = f2bf(f1.y);
          tmp[6] = f2bf(f1.z); tmp[7] = f2bf(f1.w);
        } else {
          *(uint4*)tmp = *(const uint4*)((const unsigned short*)Av +
                                         (size_t)gr * lda + kk + c * 8);
        }
      }
      *(uint4*)&As[r * 64 + ((c ^ (r & 7)) * 8)] = *(const uint4*)tmp;
    }
    #pragma unroll
    for (int p = 0; p < 4; p++) {
      int idx = tid + p * 256;
      int r = idx >> 3, c = idx & 7;
      uint4 v = *(const uint4*)(BT + (size_t)r * ldb + kk + c * 8);
      *(uint4*)&Bs[r * 64 + ((c ^ (r & 7)) * 8)] = v;
    }
    __syncthreads();
    const int arow = wv * 16 + (l & 15);
    #pragma unroll
    for (int ksub = 0; ksub < 2; ksub++) {
      int ch = ksub * 4 + (l >> 4);
      short8v af = *(const short8v*)&As[arow * 64 + ((ch ^ (arow & 7)) * 8)];
      #pragma unroll
      for (int n = 0; n < 8; n++) {
        int brow = n * 16 + (l & 15);
        short8v bf =
            *(const short8v*)&Bs[brow * 64 + ((ch ^ (brow & 7)) * 8)];
        acc[n] =
            __builtin_amdgcn_mfma_f32_16x16x32_bf16(af, bf, acc[n], 0, 0, 0);
      }
    }
    __syncthreads();
  }
}

// ---------------- weight prep: bf16 transposed copies ----------------
__global__ __launch_bounds__(256) void prep_weights(
    const float* __restrict__ W_in, const float* __restrict__ W_kqv,
    const float* __restrict__ W_o, unsigned short* __restrict__ WinT,
    unsigned short* __restrict__ Wk0T, unsigned short* __restrict__ WoT) {
  int idx = blockIdx.x * 256 + threadIdx.x;
  const int N1 = 3 * 128 * 64, N2 = 2 * 384 * 128, N3 = 6 * 128 * 128;
  if (idx < N1) {
    int t = idx / 8192, rem = idx - t * 8192;
    int n = rem >> 6, k = rem & 63;
    WinT[idx] = f2bf(W_in[(size_t)t * 64 * 128 + (size_t)k * 128 + n]);
  } else if (idx < N1 + N2) {
    int r = idx - N1;
    int lyr = r / (384 * 128), rem = r - lyr * (384 * 128);
    int n = rem >> 7, k = rem & 127;
    Wk0T[r] = f2bf(W_kqv[(size_t)lyr * 3 * 128 * 384 + (size_t)k * 384 + n]);
  } else if (idx < N1 + N2 + N3) {
    int r = idx - N1 - N2;
    int lt = r / (128 * 128), rem = r - lt * (128 * 128);
    int n = rem >> 7, k = rem & 127;
    WoT[r] = f2bf(W_o[(size_t)lt * 128 * 128 + (size_t)k * 128 + n]);
  }
}

// ---------------- weight folding (per layer) -> bf16 transposed ----------
__global__ __launch_bounds__(256) void fold_weights(
    const float* __restrict__ Wl, const float* __restrict__ bl,
    const float* __restrict__ Al, const float* __restrict__ Ml,
    unsigned short* __restrict__ WeT, float* __restrict__ be) {
  int idx = blockIdx.x * 256 + threadIdx.x;
  const int NW_ = 2 * 128 * 384;
  if (idx < NW_) {
    int tt = idx / (128 * 384);
    int rem = idx - tt * (128 * 384);
    int r = rem / 384, c = rem - r * 384;
    int slice = c >> 7, h = (c >> 5) & 3, j = c & 31;
    const float* Wsrc = Wl + (size_t)(tt + 1) * 128 * 384 + (size_t)r * 384;
    float acc = 0.f;
    if (slice == 0) {
      const float* A = Al + ((size_t)tt * H + h) * D * D;
      for (int d = 0; d < 32; d++) acc += Wsrc[h * 32 + d] * A[d * 32 + j];
    } else if (slice == 1) {
      const float* A = Al + ((size_t)(2 + tt) * H + h) * D * D;
      for (int e = 0; e < 32; e++)
        acc += Wsrc[128 + h * 32 + e] * A[j * 32 + e];
    } else {
      const float* Mm = Ml + ((size_t)tt * H + h) * D * D;
      for (int d = 0; d < 32; d++)
        acc += Wsrc[256 + h * 32 + d] * Mm[d * 32 + j];
    }
    WeT[(size_t)tt * 384 * 128 + (size_t)c * 128 + r] = f2bf(acc);
  } else if (idx < NW_ + 2 * 384) {
    int rem = idx - NW_;
    int tt = rem / 384, c = rem - tt * 384;
    int slice = c >> 7, h = (c >> 5) & 3, j = c & 31;
    const float* bsrc = bl + (size_t)(tt + 1) * 384;
    float acc = 0.f;
    if (slice == 0) {
      const float* A = Al + ((size_t)tt * H + h) * D * D;
      for (int d = 0; d < 32; d++) acc += bsrc[h * 32 + d] * A[d * 32 + j];
    } else if (slice == 1) {
      const float* A = Al + ((size_t)(2 + tt) * H + h) * D * D;
      for (int e = 0; e < 32; e++)
        acc += bsrc[128 + h * 32 + e] * A[j * 32 + e];
    } else {
      const float* Mm = Ml + ((size_t)tt * H + h) * D * D;
      for (int d = 0; d < 32; d++)
        acc += bsrc[256 + h * 32 + d] * Mm[d * 32 + j];
    }
    be[rem] = acc;
  }
}

// input proj: xs = relu(x @ W_in[t] + b_in[t])
__global__ __launch_bounds__(256) void in_fused(
    const float* __restrict__ xa, const float* __restrict__ xw,
    const float* __restrict__ xo, const unsigned short* __restrict__ WinT,
    const float* __restrict__ b_in, unsigned short* __restrict__ xs, int nb0,
    int nb01) {
  int t = btype(blockIdx.x, nb0, nb01);
  int base = t == 0 ? 0 : (t == 1 ? nb0 : nb01);
  int M = t == 0 ? NA : (t == 1 ? NW : NO);
  int off = t == 0 ? 0 : (t == 1 ? NA : NA + NW);
  const float* A = t == 0 ? xa : (t == 1 ? xw : xo);
  const int bm = (blockIdx.x - base) * 64;
  f32x4 acc[8] = {};
  gemm_body<1, true>(A, 64, WinT + (size_t)t * 128 * 64, 64, acc, M, bm);
  const int l = threadIdx.x & 63, wv = threadIdx.x >> 6;
  const float* bias = b_in + t * HID;
  unsigned short* C = xs + (size_t)off * HID;
  #pragma unroll
  for (int n = 0; n < 8; n++) {
    int col = n * 16 + (l & 15);
    float bb = bias[col];
    #pragma unroll
    for (int j = 0; j < 4; j++) {
      int row = bm + wv * 16 + (l >> 4) * 4 + j;
      if (row < M) C[(size_t)row * HID + col] = f2bf(fmaxf(acc[n][j] + bb, 0.f));
    }
  }
}

// kqv proj: t=0 raw Wk0T; t=1,2 folded WeT. 64x128 tile, y = col-tile (3).
__global__ __launch_bounds__(256) void kqv_fused(
    const unsigned short* __restrict__ xs, const unsigned short* __restrict__ Wk0Tl,
    const float* __restrict__ b0, const unsigned short* __restrict__ WeT,
    const float* __restrict__ be, unsigned short* __restrict__ kqvB, int nb0,
    int nb01) {
  int t = btype(blockIdx.x, nb0, nb01);
  int base = t == 0 ? 0 : (t == 1 ? nb0 : nb01);
  int M = t == 0 ? NA : (t == 1 ? NW : NO);
  int off = t == 0 ? 0 : (t == 1 ? NA : NA + NW);
  const unsigned short* BT =
      (t == 0 ? Wk0Tl : WeT + (size_t)(t - 1) * 384 * 128);
  const float* bias = t == 0 ? b0 : be + (size_t)(t - 1) * 384;
  const int bm = (blockIdx.x - base) * 64;
  const int bn = blockIdx.y * 128;
  f32x4 acc[8] = {};
  gemm_body<2, false>(xs + (size_t)off * HID, HID, BT + (size_t)bn * 128, 128,
                      acc, M, bm);
  const int l = threadIdx.x & 63, wv = threadIdx.x >> 6;
  unsigned short* C = kqvB + (size_t)off * LDK;
  #pragma unroll
  for (int n = 0; n < 8; n++) {
    int col = bn + n * 16 + (l & 15);
    float bb = bias[col];
    #pragma unroll
    for (int j = 0; j < 4; j++) {
      int row = bm + wv * 16 + (l >> 4) * 4 + j;
      if (row < M) C[(size_t)row * LDK + col] = f2bf(acc[n][j] + bb);
    }
  }
}

// fused: xs = relu(LN( g*(agg_gelu @ W_o + b_o) + (1-g)*xs ))
__global__ __launch_bounds__(256) void wo_ln_fused(
    const unsigned short* __restrict__ kqvB, const unsigned short* __restrict__ WoTl,
    const float* __restrict__ bl, unsigned short* __restrict__ xs,
    const float* __restrict__ skipl, const float* __restrict__ gll,
    const float* __restrict__ bll, int nb0, int nb01) {
  int t = btype(blockIdx.x, nb0, nb01);
  int base = t == 0 ? 0 : (t == 1 ? nb0 : nb01);
  int M = t == 0 ? NA : (t == 1 ? NW : NO);
  int off = t == 0 ? 0 : (t == 1 ? NA : NA + NW);
  const int bm = (blockIdx.x - base) * 64;
  f32x4 acc[8] = {};
  gemm_body<2, false>(kqvB + (size_t)off * LDK + HID, LDK,
                      WoTl + (size_t)t * 128 * 128, 128, acc, M, bm);
  const int l = threadIdx.x & 63, wv = threadIdx.x >> 6;
  const float* bias = bl + t * HID;
  const float* gln = gll + t * HID;
  const float* bln = bll + t * HID;
  unsigned short* xsT = xs + (size_t)off * HID;
  const float g = 1.f / (1.f + expf(-skipl[t]));
  float bb[8], gl8[8], bl8[8];
  #pragma unroll
  for (int n = 0; n < 8; n++) {
    int col = n * 16 + (l & 15);
    bb[n] = bias[col];
    gl8[n] = gln[col];
    bl8[n] = bln[col];
  }
  #pragma unroll
  for (int j = 0; j < 4; j++) {
    int row = bm + wv * 16 + (l >> 4) * 4 + j;
    bool ok = row < M;
    float vv[8], sum = 0.f, sq = 0.f;
    #pragma unroll
    for (int n = 0; n < 8; n++) {
      int col = n * 16 + (l & 15);
      float xo = ok ? bf2f(xsT[(size_t)row * HID + col]) : 0.f;
      float val = g * (acc[n][j] + bb[n]) + (1.f - g) * xo;
      vv[n] = val;
      sum += val;
      sq += val * val;
    }
    #pragma unroll
    for (int m = 1; m < 16; m <<= 1) {
      sum += __shfl_xor(sum, m, 64);
      sq += __shfl_xor(sq, m, 64);
    }
    float mu = sum * (1.f / 128.f);
    float var = sq * (1.f / 128.f) - mu * mu;
    float r = rsqrtf(var + 1e-5f);
    if (ok) {
      #pragma unroll
      for (int n = 0; n < 8; n++) {
        float y = fmaxf((vv[n] - mu) * r * gl8[n] + bl8[n], 0.f);
        xsT[(size_t)row * HID + n * 16 + (l & 15)] = f2bf(y);
      }
    }
  }
}

// ---------------- CSR build (deterministic, 4 ets fused) ----------------
__global__ __launch_bounds__(256) void csr_hist4(
    const int* __restrict__ d0, const int* __restrict__ d1,
    const int* __restrict__ d2, const int* __restrict__ d3,
    int* __restrict__ cnt) {
  int t = blockIdx.x * 256 + threadIdx.x;
  if (t >= 4 * E) return;
  int et = t / E, e = t - et * E;
  const int* dp = et == 0 ? d0 : et == 1 ? d1 : et == 2 ? d2 : d3;
  int base = et == 0 ? 0 : et == 1 ? NA : et == 2 ? 2 * NA : 2 * NA + NW;
  atomicAdd(&cnt[base + dp[e]], 1);
}

__global__ __launch_bounds__(256) void scan_block(const int* __restrict__ cnt,
                                                  int* __restrict__ excl,
                                                  int* __restrict__ bsum,
                                                  int n) {
  __shared__ int tmp[256];
  int i = blockIdx.x * 256 + threadIdx.x;
  int v = (i < n) ? cnt[i] : 0;
  tmp[threadIdx.x] = v;
  __syncthreads();
  int acc = v;
  for (int off = 1; off < 256; off <<= 1) {
    int other = (threadIdx.x >= off) ? tmp[threadIdx.x - off] : 0;
    __syncthreads();
    acc += other;
    tmp[threadIdx.x] = acc;
    __syncthreads();
  }
  if (i < n) excl[i] = acc - v;
  if (threadIdx.x == 255) bsum[blockIdx.x] = acc;
}

__global__ __launch_bounds__(256) void scan_bsums(int* __restrict__ bsum,
                                                  int nb) {
  __shared__ int tmp[256];
  __shared__ int carry;
  if (threadIdx.x == 0) carry = 0;
  __syncthreads();
  for (int start = 0; start < nb; start += 256) {
    int i = start + threadIdx.x;
    int v = (i < nb) ? bsum[i] : 0;
    tmp[threadIdx.x] = v;
    __syncthreads();
    int acc = v;
    for (int off = 1; off < 256; off <<= 1) {
      int other = (threadIdx.x >= off) ? tmp[threadIdx.x - off] : 0;
      __syncthreads();
      acc += other;
      tmp[threadIdx.x] = acc;
      __syncthreads();
    }
    int c = carry;
    if (i < nb) bsum[i] = c + acc - v;
    __syncthreads();
    if (threadIdx.x == 255) carry = c + acc;
    __syncthreads();
  }
}

__device__ __forceinline__ void et_of_node(int i, int& et, int& base, int& nd,
                                           int& rpo) {
  if (i < NA) { et = 0; base = 0; nd = NA; rpo = 0; }
  else if (i < 2 * NA) { et = 1; base = NA; nd = NA; rpo = NA + 1; }
  else if (i < 2 * NA + NW) { et = 2; base = 2 * NA; nd = NW; rpo = 2 * (NA + 1); }
  else { et = 3; base = 2 * NA + NW; nd = NO; rpo = 2 * (NA + 1) + NW + 1; }
}

__global__ __launch_bounds__(256) void csr_finalize4(
    int* __restrict__ rpAll, const int* __restrict__ bsum,
    int* __restrict__ cursor) {
  int i = blockIdx.x * 256 + threadIdx.x;
  if (i >= 2 * NA + NW + NO) return;
  int et, base, nd, rpo;
  et_of_node(i, et, base, nd, rpo);
  int local = i - base;
  int v = rpAll[rpo + local] + bsum[et * 512 + (local >> 8)];
  rpAll[rpo + local] = v;
  cursor[base + local] = v;
  if (local == 0) rpAll[rpo + nd] = E;
}

__global__ __launch_bounds__(256) void csr_scatter4(
    const int* __restrict__ d0, const int* __restrict__ d1,
    const int* __restrict__ d2, const int* __restrict__ d3,
    int* __restrict__ cursor, int* __restrict__ ceAll) {
  int t = blockIdx.x * 256 + threadIdx.x;
  if (t >= 4 * E) return;
  int et = t / E, e = t - et * E;
  const int* dp = et == 0 ? d0 : et == 1 ? d1 : et == 2 ? d2 : d3;
  int base = et == 0 ? 0 : et == 1 ? NA : et == 2 ? 2 * NA : 2 * NA + NW;
  int slot = atomicAdd(&cursor[base + dp[e]], 1);
  ceAll[(size_t)et * E + slot] = e;
}

__global__ __launch_bounds__(256) void csr_sort4(const int* __restrict__ rpAll,
                                                 int* __restrict__ ceAll) {
  int i = blockIdx.x * 256 + threadIdx.x;
  if (i >= 2 * NA + NW + NO) return;
  int et, base, nd, rpo;
  et_of_node(i, et, base, nd, rpo);
  int local = i - base;
  int b = rpAll[rpo + local], e = rpAll[rpo + local + 1];
  int* ce = ceAll + (size_t)et * E;
  for (int k = b + 1; k < e; k++) {
    int key = ce[k];
    int j = k - 1;
    while (j >= b && ce[j] > key) { ce[j + 1] = ce[j]; j--; }
    ce[j + 1] = key;
  }
}

// slot-ordered GLOBAL src node ids
__global__ __launch_bounds__(256) void build_sd(
    const int* __restrict__ ce, const int* __restrict__ s0,
    const int* __restrict__ s1, const int* __restrict__ s2,
    const int* __restrict__ s3, int* __restrict__ srcOf) {
  int t = blockIdx.x * 256 + threadIdx.x;
  if (t >= 4 * E) return;
  int et = t / E;
  int e = ce[t];
  const int* sp = et == 0 ? s0 : et == 1 ? s1 : et == 2 ? s2 : s3;
  int sOff = et == 0 ? NA : et == 1 ? NA + NW : 0;
  srcOf[t] = sOff + sp[e];
}

// ---------------- fused attention: one 64-lane wave per dst ----------------
// lane = dim-pair (dims 2*lane, 2*lane+1); quarter q = lane>>4 = head.
// 3-phase (max / den / weighted-gather) with per-wave LDS alpha scratch.
__global__ __launch_bounds__(256) void attn_fused(
    const unsigned short* __restrict__ kqv, const int* __restrict__ rpAll,
    const int* __restrict__ srcOf, const float* __restrict__ Pl,
    const float* __restrict__ Ml, unsigned short* __restrict__ out) {
  __shared__ float alds[4][MAXDEG * 4];
  int dl = (blockIdx.x * 256 + threadIdx.x) >> 6;
  int lane = threadIdx.x & 63;
  int wv = threadIdx.x >> 6;
  if (dl >= NTOT) return;
  int q = lane >> 4, p = lane & 15;
  int b0, e0, b1 = 0, e1 = 0, et23 = -1;
  const int* so0;
  const int* so1 = srcOf;
  float ps0, ps1 = 0.f;
  if (dl < NA) {
    b0 = rpAll[dl]; e0 = rpAll[dl + 1];
    b1 = rpAll[(NA + 1) + dl]; e1 = rpAll[(NA + 1) + dl + 1];
    so0 = srcOf; so1 = srcOf + E;
    ps0 = Pl[q] * SCALE; ps1 = Pl[H + q] * SCALE;
  } else if (dl < NA + NW) {
    int x = dl - NA;
    b0 = rpAll[2 * (NA + 1) + x]; e0 = rpAll[2 * (NA + 1) + x + 1];
    so0 = srcOf + 2 * (size_t)E;
    ps0 = Pl[2 * H + q] * SCALE;
    et23 = 2;
  } else {
    int x = dl - NA - NW;
    b0 = rpAll[2 * (NA + 1) + (NW + 1) + x];
    e0 = rpAll[2 * (NA + 1) + (NW + 1) + x + 1];
    so0 = srcOf + 3 * (size_t)E;
    ps0 = Pl[3 * H + q] * SCALE;
    et23 = 3;
  }
  const int n0 = e0 - b0;
  const int n01 = n0 + (e1 - b1);
  // q-row (one coalesced 256B load, stays in regs)
  unsigned qv = *(const unsigned*)(kqv + (size_t)dl * LDK + HID + lane * 2);
  float qx = bf2f((unsigned short)(qv & 0xFFFF));
  float qy = bf2f((unsigned short)(qv >> 16));
  // alpha(t): gather k-row, per-quarter dot (uniform across quarter lanes)
  auto alpha_of = [&](int t) -> float {
    int slot = t < n0 ? b0 + t : b1 + (t - n0);
    const int* so = t < n0 ? so0 : so1;
    float ps = t < n0 ? ps0 : ps1;
    int src = so[slot];
    unsigned kv = *(const unsigned*)(kqv + (size_t)src * LDK + lane * 2);
    float s = qx * bf2f((unsigned short)(kv & 0xFFFF)) +
              qy * bf2f((unsigned short)(kv >> 16));
    s += __shfl_xor(s, 1, 64);
    s += __shfl_xor(s, 2, 64);
    s += __shfl_xor(s, 4, 64);
    s += __shfl_xor(s, 8, 64);
    return s * ps;
  };
  // phase A: compute alphas -> LDS, track per-quarter max (uniform)
  float mx = -INFINITY;
  const int nl = n01 < MAXDEG ? n01 : MAXDEG;
  for (int t = 0; t < n01; t++) {
    float a = alpha_of(t);
    if (t < MAXDEG && p == 0) alds[wv][t * 4 + q] = a;
    mx = fmaxf(mx, a);
  }
  // phase B: den
  float den = 0.f;
  for (int t = p; t < nl; t += 16) den += expf(alds[wv][t * 4 + q] - mx);
  den += __shfl_xor(den, 1, 64);
  den += __shfl_xor(den, 2, 64);
  den += __shfl_xor(den, 4, 64);
  den += __shfl_xor(den, 8, 64);
  for (int t = MAXDEG; t < n01; t++) den += expf(alpha_of(t) - mx);
  float inv = 1.f / (den + 1e-16f);
  // phase C: weighted v gather; w computed 16-wide, broadcast by shfl
  float ax = 0.f, ay = 0.f;
  for (int c = 0; c < nl; c += 16) {
    int tp = c + p;
    float wp = (tp < nl) ? expf(alds[wv][tp * 4 + q] - mx) * inv : 0.f;
    int jend = nl - c < 16 ? nl - c : 16;
    for (int j = 0; j < jend; j++) {
      float w = __shfl(wp, (lane & 48) + j, 64);
      int t = c + j;
      int slot = t < n0 ? b0 + t : b1 + (t - n0);
      const int* so = t < n0 ? so0 : so1;
      int src = so[slot];
      unsigned vv =
          *(const unsigned*)(kqv + (size_t)src * LDK + 2 * HID + lane * 2);
      ax += w * bf2f((unsigned short)(vv & 0xFFFF));
      ay += w * bf2f((unsigned short)(vv >> 16));
    }
  }
  for (int t = MAXDEG; t < n01; t++) {  // overflow (deg > MAXDEG): recompute
    float w = expf(alpha_of(t) - mx) * inv;
    int slot = t < n0 ? b0 + t : b1 + (t - n0);
    const int* so = t < n0 ? so0 : so1;
    int src = so[slot];
    unsigned vv =
        *(const unsigned*)(kqv + (size_t)src * LDK + 2 * HID + lane * 2);
    ax += w * bf2f((unsigned short)(vv & 0xFFFF));
    ay += w * bf2f((unsigned short)(vv >> 16));
  }
  // W/O dst: M transform (raw-v aggregated; apply per-dst once)
  if (et23 >= 0) {
    const float* Mm = Ml + ((size_t)et23 * H + q) * D * D;
    int base = lane & 48;
    float o0 = 0.f, o1 = 0.f;
    #pragma unroll
    for (int j = 0; j < 16; j++) {
      float s0 = __shfl(ax, base + j, 64);
      float s1 = __shfl(ay, base + j, 64);
      float2 m0 = *(const float2*)&Mm[(2 * j) * 32 + 2 * p];
      float2 m1 = *(const float2*)&Mm[(2 * j + 1) * 32 + 2 * p];
      o0 += s0 * m0.x + s1 * m1.x;
      o1 += s0 * m0.y + s1 * m1.y;
    }
    ax = o0; ay = o1;
  }
  unsigned ov = (unsigned)f2bf(gelu_exact(ax)) |
                ((unsigned)f2bf(gelu_exact(ay)) << 16);
  *(unsigned*)(out + (size_t)dl * LDK + HID + lane * 2) = ov;
}

__global__ __launch_bounds__(256) void head_kernel(
    const unsigned short* __restrict__ xs0, const float* __restrict__ w_head,
    const float* __restrict__ b_head, const float* __restrict__ basep,
    float* __restrict__ out, int Nrows) {
  int wid = (blockIdx.x * 256 + threadIdx.x) >> 6;
  int lane = threadIdx.x & 63;
  if (wid >= Nrows) return;
  size_t base = (size_t)wid * HID;
  float d = bf2f(xs0[base + lane]) * w_head[lane] +
            bf2f(xs0[base + 64 + lane]) * w_head[64 + lane];
  #pragma unroll
  for (int m = 1; m < 64; m <<= 1) d += __shfl_xor(d, m, 64);
  if (lane == 0) out[wid] = basep[0] + b_head[0] + d;
}

}  // namespace

extern "C" void kernel_launch(void* const* d_in, const int* in_sizes, int n_in,
                              void* d_out, int out_size, void* d_ws,
                              size_t ws_size, hipStream_t stream) {
  const float* x_a = (const float*)d_in[0];
  const float* x_w = (const float*)d_in[1];
  const float* x_o = (const float*)d_in[2];
  const float* W_in = (const float*)d_in[3];
  const float* b_in = (const float*)d_in[4];
  const float* W_kqv = (const float*)d_in[5];
  const float* b_kqv = (const float*)d_in[6];
  const float* a_rel = (const float*)d_in[7];
  const float* m_rel = (const float*)d_in[8];
  const float* p_rel = (const float*)d_in[9];
  const float* skip_p = (const float*)d_in[10];
  const float* W_o = (const float*)d_in[11];
  const float* b_o = (const float*)d_in[12];
  const float* ln_g = (const float*)d_in[13];
  const float* ln_b = (const float*)d_in[14];
  const float* w_head = (const float*)d_in[15];
  const float* b_head = (const float*)d_in[16];
  const float* basep = (const float*)d_in[17];
  const int* srcs[4] = {(const int*)d_in[18], (const int*)d_in[20],
                        (const int*)d_in[22], (const int*)d_in[24]};
  const int* dsts[4] = {(const int*)d_in[19], (const int*)d_in[21],
                        (const int*)d_in[23], (const int*)d_in[25]};

  // ---- workspace layout (~183 MB) ----
  const size_t SZ_XS = (size_t)NTOT * HID * 2;
  const size_t SZ_KQV = (size_t)NTOT * LDK * 2;
  const size_t SZ_WINT = (size_t)3 * 128 * 64 * 2;
  const size_t SZ_WK0T = (size_t)2 * 384 * 128 * 2;
  const size_t SZ_WOT = (size_t)6 * 128 * 128 * 2;
  const size_t SZ_WET = (size_t)2 * 384 * 128 * 2;
  const size_t SZ_BE = ((size_t)2 * 384 * 4 + 63) & ~63ull;
  const size_t SZ_SD = (size_t)4 * E * 4;
  const int CNT_TOT = 2 * NA + NW + NO;
  const int RP_TOT = 2 * (NA + 1) + (NW + 1) + (NO + 1);
  const size_t SZ_RP = ((size_t)RP_TOT * 4 + 63) & ~63ull;
  const size_t SZ_CE = (size_t)4 * E * 4;
  const size_t SZ_CU = ((size_t)CNT_TOT * 4 + 63) & ~63ull;
  const size_t SZ_BS = 4 * 512 * 4;
  const size_t need = SZ_XS + SZ_KQV + SZ_WINT + SZ_WK0T + SZ_WOT + SZ_WET +
                      SZ_BE + SZ_SD + SZ_RP + SZ_CE + 2 * SZ_CU + SZ_BS;
  if (ws_size < need) return;

  char* p = (char*)d_ws;
  unsigned short* xs = (unsigned short*)p;    p += SZ_XS;
  unsigned short* kqvB = (unsigned short*)p;  p += SZ_KQV;
  unsigned short* WinT = (unsigned short*)p;  p += SZ_WINT;
  unsigned short* Wk0T = (unsigned short*)p;  p += SZ_WK0T;
  unsigned short* WoT = (unsigned short*)p;   p += SZ_WOT;
  unsigned short* WeT = (unsigned short*)p;   p += SZ_WET;
  float* beB = (float*)p;                     p += SZ_BE;
  int* srcOf = (int*)p;                       p += SZ_SD;
  int* rpAll = (int*)p;                       p += SZ_RP;
  int* ceAll = (int*)p;                       p += SZ_CE;
  int* cursor = (int*)p;                      p += SZ_CU;
  int* cnt = (int*)p;                         p += SZ_CU;
  int* bsum = (int*)p;

  const int rpOff[4] = {0, NA + 1, 2 * (NA + 1), 2 * (NA + 1) + NW + 1};
  const int cntBase[4] = {0, NA, 2 * NA, 2 * NA + NW};
  const int ndE[4] = {NA, NA, NW, NO};
  const int e4b = (4 * E + 255) / 256;
  const int nb0 = (NA + 63) / 64, nb01 = nb0 + (NW + 63) / 64;
  const int nbTot = nb01 + (NO + 63) / 64;

  // ---- CSR build (once) ----
  hipMemsetAsync(cnt, 0, (size_t)CNT_TOT * 4, stream);
  csr_hist4<<<e4b, 256, 0, stream>>>(dsts[0], dsts[1], dsts[2], dsts[3], cnt);
  for (int et = 0; et < 4; et++) {
    int nb = (ndE[et] + 255) / 256;
    scan_block<<<nb, 256, 0, stream>>>(cnt + cntBase[et], rpAll + rpOff[et],
                                       bsum + et * 512, ndE[et]);
    scan_bsums<<<1, 256, 0, stream>>>(bsum + et * 512, nb);
  }
  csr_finalize4<<<(CNT_TOT + 255) / 256, 256, 0, stream>>>(rpAll, bsum, cursor);
  csr_scatter4<<<e4b, 256, 0, stream>>>(dsts[0], dsts[1], dsts[2], dsts[3],
                                        cursor, ceAll);
  csr_sort4<<<(CNT_TOT + 255) / 256, 256, 0, stream>>>(rpAll, ceAll);
  build_sd<<<e4b, 256, 0, stream>>>(ceAll, srcs[0], srcs[1], srcs[2], srcs[3],
                                    srcOf);

  // ---- weight prep + input projection ----
  prep_weights<<<(3 * 128 * 64 + 2 * 384 * 128 + 6 * 128 * 128 + 255) / 256,
                 256, 0, stream>>>(W_in, W_kqv, W_o, WinT, Wk0T, WoT);
  in_fused<<<nbTot, 256, 0, stream>>>(x_a, x_w, x_o, WinT, b_in, xs, nb0, nb01);

  const size_t DD = (size_t)H * D * D;
  for (int l = 0; l < 2; l++) {
    const float* Al = a_rel + (size_t)l * 4 * DD;
    const float* Ml = m_rel + (size_t)l * 4 * DD;
    const float* Pl = p_rel + (size_t)l * 4 * H;
    const float* Wl = W_kqv + (size_t)l * 3 * HID * LDK;
    const float* bl = b_kqv + (size_t)l * 3 * LDK;
    fold_weights<<<(2 * 128 * 384 + 2 * 384 + 255) / 256, 256, 0, stream>>>(
        Wl, bl, Al, Ml, WeT, beB);
    kqv_fused<<<dim3(nbTot, 3), 256, 0, stream>>>(
        xs, Wk0T + (size_t)l * 384 * 128, bl, WeT, beB, kqvB, nb0, nb01);
    attn_fused<<<(NTOT + 3) / 4, 256, 0, stream>>>(kqvB, rpAll, srcOf, Pl, Ml,
                                                   kqvB);
    wo_ln_fused<<<nbTot, 256, 0, stream>>>(
        kqvB, WoT + (size_t)l * 3 * 128 * 128, b_o + (size_t)l * 3 * HID, xs,
        skip_p + l * 3, ln_g + (size_t)l * 3 * HID, ln_b + (size_t)l * 3 * HID,
        nb0, nb01);
  }
  head_kernel<<<(NA + 3) / 4, 256, 0, stream>>>(xs, w_head, b_head, basep,
                                                (float*)d_out, NA);
}

// Round 15
// 791.594 us; speedup vs baseline: 2.8625x; 1.1414x over previous
//
#include <hip/hip_runtime.h>
#include <cstddef>
#include <cmath>

namespace {

constexpr int H = 4, D = 32, HID = 128;
constexpr int NA = 100000, NW = 20000, NO = 50000;
constexpr int NTOT = NA + NW + NO;
constexpr int E = 150000;
constexpr float SCALE = 0.17677669529663687f;  // 1/sqrt(32)
constexpr int LDK = 3 * HID;  // kqv row stride (384)

typedef __attribute__((ext_vector_type(8))) short short8v;
typedef __attribute__((ext_vector_type(4))) float f32x4;

__device__ __forceinline__ float gelu_exact(float x) {
  return 0.5f * x * (1.f + erff(x * 0.7071067811865475f));
}
__device__ __forceinline__ unsigned short f2bf(float f) {  // RNE
  unsigned u = __float_as_uint(f);
  return (unsigned short)((u + 0x7FFF + ((u >> 16) & 1)) >> 16);
}
__device__ __forceinline__ float bf2f(unsigned short s) {
  return __uint_as_float(((unsigned)s) << 16);
}

__device__ __forceinline__ int btype(int bx, int nb0, int nb01) {
  return bx < nb0 ? 0 : (bx < nb01 ? 1 : 2);
}

// ---------------- swizzled BK=64 MFMA GEMM body ----------------
template <int KSTEPS, bool A_FP32>
__device__ __forceinline__ void gemm_body(
    const void* __restrict__ Av, int lda, const unsigned short* __restrict__ BT,
    int ldb, f32x4* acc, int M, int bm) {
  __shared__ unsigned short As[64 * 64];
  __shared__ unsigned short Bs[128 * 64];
  const int tid = threadIdx.x;
  const int wv = tid >> 6, l = tid & 63;
  for (int ks = 0; ks < KSTEPS; ks++) {
    const int kk = ks * 64;
    #pragma unroll
    for (int p = 0; p < 2; p++) {
      int idx = tid + p * 256;
      int r = idx >> 3, c = idx & 7;
      int gr = bm + r;
      unsigned short tmp[8] = {0, 0, 0, 0, 0, 0, 0, 0};
      if (gr < M) {
        if (A_FP32) {
          const float* src = (const float*)Av + (size_t)gr * lda + kk + c * 8;
          float4 f0 = *(const float4*)src;
          float4 f1 = *(const float4*)(src + 4);
          tmp[0] = f2bf(f0.x); tmp[1] = f2bf(f0.y);
          tmp[2] = f2bf(f0.z); tmp[3] = f2bf(f0.w);
          tmp[4] = f2bf(f1.x); tmp[5] = f2bf(f1.y);
          tmp[6] = f2bf(f1.z); tmp[7] = f2bf(f1.w);
        } else {
          *(uint4*)tmp = *(const uint4*)((const unsigned short*)Av +
                                         (size_t)gr * lda + kk + c * 8);
        }
      }
      *(uint4*)&As[r * 64 + ((c ^ (r & 7)) * 8)] = *(const uint4*)tmp;
    }
    #pragma unroll
    for (int p = 0; p < 4; p++) {
      int idx = tid + p * 256;
      int r = idx >> 3, c = idx & 7;
      uint4 v = *(const uint4*)(BT + (size_t)r * ldb + kk + c * 8);
      *(uint4*)&Bs[r * 64 + ((c ^ (r & 7)) * 8)] = v;
    }
    __syncthreads();
    const int arow = wv * 16 + (l & 15);
    #pragma unroll
    for (int ksub = 0; ksub < 2; ksub++) {
      int ch = ksub * 4 + (l >> 4);
      short8v af = *(const short8v*)&As[arow * 64 + ((ch ^ (arow & 7)) * 8)];
      #pragma unroll
      for (int n = 0; n < 8; n++) {
        int brow = n * 16 + (l & 15);
        short8v bf =
            *(const short8v*)&Bs[brow * 64 + ((ch ^ (brow & 7)) * 8)];
        acc[n] =
            __builtin_amdgcn_mfma_f32_16x16x32_bf16(af, bf, acc[n], 0, 0, 0);
      }
    }
    __syncthreads();
  }
}

// ---------------- weight prep: bf16 transposed copies ----------------
__global__ __launch_bounds__(256) void prep_weights(
    const float* __restrict__ W_in, const float* __restrict__ W_kqv,
    const float* __restrict__ W_o, unsigned short* __restrict__ WinT,
    unsigned short* __restrict__ Wk0T, unsigned short* __restrict__ WoT) {
  int idx = blockIdx.x * 256 + threadIdx.x;
  const int N1 = 3 * 128 * 64, N2 = 2 * 384 * 128, N3 = 6 * 128 * 128;
  if (idx < N1) {
    int t = idx / 8192, rem = idx - t * 8192;
    int n = rem >> 6, k = rem & 63;
    WinT[idx] = f2bf(W_in[(size_t)t * 64 * 128 + (size_t)k * 128 + n]);
  } else if (idx < N1 + N2) {
    int r = idx - N1;
    int lyr = r / (384 * 128), rem = r - lyr * (384 * 128);
    int n = rem >> 7, k = rem & 127;
    Wk0T[r] = f2bf(W_kqv[(size_t)lyr * 3 * 128 * 384 + (size_t)k * 384 + n]);
  } else if (idx < N1 + N2 + N3) {
    int r = idx - N1 - N2;
    int lt = r / (128 * 128), rem = r - lt * (128 * 128);
    int n = rem >> 7, k = rem & 127;
    WoT[r] = f2bf(W_o[(size_t)lt * 128 * 128 + (size_t)k * 128 + n]);
  }
}

// ---------------- weight folding (per layer) -> bf16 transposed ----------
__global__ __launch_bounds__(256) void fold_weights(
    const float* __restrict__ Wl, const float* __restrict__ bl,
    const float* __restrict__ Al, const float* __restrict__ Ml,
    unsigned short* __restrict__ WeT, float* __restrict__ be) {
  int idx = blockIdx.x * 256 + threadIdx.x;
  const int NW_ = 2 * 128 * 384;
  if (idx < NW_) {
    int tt = idx / (128 * 384);
    int rem = idx - tt * (128 * 384);
    int r = rem / 384, c = rem - r * 384;
    int slice = c >> 7, h = (c >> 5) & 3, j = c & 31;
    const float* Wsrc = Wl + (size_t)(tt + 1) * 128 * 384 + (size_t)r * 384;
    float acc = 0.f;
    if (slice == 0) {
      const float* A = Al + ((size_t)tt * H + h) * D * D;
      for (int d = 0; d < 32; d++) acc += Wsrc[h * 32 + d] * A[d * 32 + j];
    } else if (slice == 1) {
      const float* A = Al + ((size_t)(2 + tt) * H + h) * D * D;
      for (int e = 0; e < 32; e++)
        acc += Wsrc[128 + h * 32 + e] * A[j * 32 + e];
    } else {
      const float* Mm = Ml + ((size_t)tt * H + h) * D * D;
      for (int d = 0; d < 32; d++)
        acc += Wsrc[256 + h * 32 + d] * Mm[d * 32 + j];
    }
    WeT[(size_t)tt * 384 * 128 + (size_t)c * 128 + r] = f2bf(acc);
  } else if (idx < NW_ + 2 * 384) {
    int rem = idx - NW_;
    int tt = rem / 384, c = rem - tt * 384;
    int slice = c >> 7, h = (c >> 5) & 3, j = c & 31;
    const float* bsrc = bl + (size_t)(tt + 1) * 384;
    float acc = 0.f;
    if (slice == 0) {
      const float* A = Al + ((size_t)tt * H + h) * D * D;
      for (int d = 0; d < 32; d++) acc += bsrc[h * 32 + d] * A[d * 32 + j];
    } else if (slice == 1) {
      const float* A = Al + ((size_t)(2 + tt) * H + h) * D * D;
      for (int e = 0; e < 32; e++)
        acc += bsrc[128 + h * 32 + e] * A[j * 32 + e];
    } else {
      const float* Mm = Ml + ((size_t)tt * H + h) * D * D;
      for (int d = 0; d < 32; d++)
        acc += bsrc[256 + h * 32 + d] * Mm[d * 32 + j];
    }
    be[rem] = acc;
  }
}

// input proj: xs = relu(x @ W_in[t] + b_in[t])
__global__ __launch_bounds__(256) void in_fused(
    const float* __restrict__ xa, const float* __restrict__ xw,
    const float* __restrict__ xo, const unsigned short* __restrict__ WinT,
    const float* __restrict__ b_in, unsigned short* __restrict__ xs, int nb0,
    int nb01) {
  int t = btype(blockIdx.x, nb0, nb01);
  int base = t == 0 ? 0 : (t == 1 ? nb0 : nb01);
  int M = t == 0 ? NA : (t == 1 ? NW : NO);
  int off = t == 0 ? 0 : (t == 1 ? NA : NA + NW);
  const float* A = t == 0 ? xa : (t == 1 ? xw : xo);
  const int bm = (blockIdx.x - base) * 64;
  f32x4 acc[8] = {};
  gemm_body<1, true>(A, 64, WinT + (size_t)t * 128 * 64, 64, acc, M, bm);
  const int l = threadIdx.x & 63, wv = threadIdx.x >> 6;
  const float* bias = b_in + t * HID;
  unsigned short* C = xs + (size_t)off * HID;
  #pragma unroll
  for (int n = 0; n < 8; n++) {
    int col = n * 16 + (l & 15);
    float bb = bias[col];
    #pragma unroll
    for (int j = 0; j < 4; j++) {
      int row = bm + wv * 16 + (l >> 4) * 4 + j;
      if (row < M) C[(size_t)row * HID + col] = f2bf(fmaxf(acc[n][j] + bb, 0.f));
    }
  }
}

// kqv proj: t=0 raw Wk0T; t=1,2 folded WeT. 64x128 tile, y = col-tile (3).
__global__ __launch_bounds__(256) void kqv_fused(
    const unsigned short* __restrict__ xs, const unsigned short* __restrict__ Wk0Tl,
    const float* __restrict__ b0, const unsigned short* __restrict__ WeT,
    const float* __restrict__ be, unsigned short* __restrict__ kqvB, int nb0,
    int nb01) {
  int t = btype(blockIdx.x, nb0, nb01);
  int base = t == 0 ? 0 : (t == 1 ? nb0 : nb01);
  int M = t == 0 ? NA : (t == 1 ? NW : NO);
  int off = t == 0 ? 0 : (t == 1 ? NA : NA + NW);
  const unsigned short* BT =
      (t == 0 ? Wk0Tl : WeT + (size_t)(t - 1) * 384 * 128);
  const float* bias = t == 0 ? b0 : be + (size_t)(t - 1) * 384;
  const int bm = (blockIdx.x - base) * 64;
  const int bn = blockIdx.y * 128;
  f32x4 acc[8] = {};
  gemm_body<2, false>(xs + (size_t)off * HID, HID, BT + (size_t)bn * 128, 128,
                      acc, M, bm);
  const int l = threadIdx.x & 63, wv = threadIdx.x >> 6;
  unsigned short* C = kqvB + (size_t)off * LDK;
  #pragma unroll
  for (int n = 0; n < 8; n++) {
    int col = bn + n * 16 + (l & 15);
    float bb = bias[col];
    #pragma unroll
    for (int j = 0; j < 4; j++) {
      int row = bm + wv * 16 + (l >> 4) * 4 + j;
      if (row < M) C[(size_t)row * LDK + col] = f2bf(acc[n][j] + bb);
    }
  }
}

// fused: xs = relu(LN( g*(agg_gelu @ W_o + b_o) + (1-g)*xs ))
__global__ __launch_bounds__(256) void wo_ln_fused(
    const unsigned short* __restrict__ kqvB, const unsigned short* __restrict__ WoTl,
    const float* __restrict__ bl, unsigned short* __restrict__ xs,
    const float* __restrict__ skipl, const float* __restrict__ gll,
    const float* __restrict__ bll, int nb0, int nb01) {
  int t = btype(blockIdx.x, nb0, nb01);
  int base = t == 0 ? 0 : (t == 1 ? nb0 : nb01);
  int M = t == 0 ? NA : (t == 1 ? NW : NO);
  int off = t == 0 ? 0 : (t == 1 ? NA : NA + NW);
  const int bm = (blockIdx.x - base) * 64;
  f32x4 acc[8] = {};
  gemm_body<2, false>(kqvB + (size_t)off * LDK + HID, LDK,
                      WoTl + (size_t)t * 128 * 128, 128, acc, M, bm);
  const int l = threadIdx.x & 63, wv = threadIdx.x >> 6;
  const float* bias = bl + t * HID;
  const float* gln = gll + t * HID;
  const float* bln = bll + t * HID;
  unsigned short* xsT = xs + (size_t)off * HID;
  const float g = 1.f / (1.f + expf(-skipl[t]));
  float bb[8], gl8[8], bl8[8];
  #pragma unroll
  for (int n = 0; n < 8; n++) {
    int col = n * 16 + (l & 15);
    bb[n] = bias[col];
    gl8[n] = gln[col];
    bl8[n] = bln[col];
  }
  #pragma unroll
  for (int j = 0; j < 4; j++) {
    int row = bm + wv * 16 + (l >> 4) * 4 + j;
    bool ok = row < M;
    float vv[8], sum = 0.f, sq = 0.f;
    #pragma unroll
    for (int n = 0; n < 8; n++) {
      int col = n * 16 + (l & 15);
      float xo = ok ? bf2f(xsT[(size_t)row * HID + col]) : 0.f;
      float val = g * (acc[n][j] + bb[n]) + (1.f - g) * xo;
      vv[n] = val;
      sum += val;
      sq += val * val;
    }
    #pragma unroll
    for (int m = 1; m < 16; m <<= 1) {
      sum += __shfl_xor(sum, m, 64);
      sq += __shfl_xor(sq, m, 64);
    }
    float mu = sum * (1.f / 128.f);
    float var = sq * (1.f / 128.f) - mu * mu;
    float r = rsqrtf(var + 1e-5f);
    if (ok) {
      #pragma unroll
      for (int n = 0; n < 8; n++) {
        float y = fmaxf((vv[n] - mu) * r * gl8[n] + bl8[n], 0.f);
        xsT[(size_t)row * HID + n * 16 + (l & 15)] = f2bf(y);
      }
    }
  }
}

// ---------------- CSR build (deterministic, 4 ets fused) ----------------
__global__ __launch_bounds__(256) void csr_hist4(
    const int* __restrict__ d0, const int* __restrict__ d1,
    const int* __restrict__ d2, const int* __restrict__ d3,
    int* __restrict__ cnt) {
  int t = blockIdx.x * 256 + threadIdx.x;
  if (t >= 4 * E) return;
  int et = t / E, e = t - et * E;
  const int* dp = et == 0 ? d0 : et == 1 ? d1 : et == 2 ? d2 : d3;
  int base = et == 0 ? 0 : et == 1 ? NA : et == 2 ? 2 * NA : 2 * NA + NW;
  atomicAdd(&cnt[base + dp[e]], 1);
}

__global__ __launch_bounds__(256) void scan_block(const int* __restrict__ cnt,
                                                  int* __restrict__ excl,
                                                  int* __restrict__ bsum,
                                                  int n) {
  __shared__ int tmp[256];
  int i = blockIdx.x * 256 + threadIdx.x;
  int v = (i < n) ? cnt[i] : 0;
  tmp[threadIdx.x] = v;
  __syncthreads();
  int acc = v;
  for (int off = 1; off < 256; off <<= 1) {
    int other = (threadIdx.x >= off) ? tmp[threadIdx.x - off] : 0;
    __syncthreads();
    acc += other;
    tmp[threadIdx.x] = acc;
    __syncthreads();
  }
  if (i < n) excl[i] = acc - v;
  if (threadIdx.x == 255) bsum[blockIdx.x] = acc;
}

__global__ __launch_bounds__(256) void scan_bsums(int* __restrict__ bsum,
                                                  int nb) {
  __shared__ int tmp[256];
  __shared__ int carry;
  if (threadIdx.x == 0) carry = 0;
  __syncthreads();
  for (int start = 0; start < nb; start += 256) {
    int i = start + threadIdx.x;
    int v = (i < nb) ? bsum[i] : 0;
    tmp[threadIdx.x] = v;
    __syncthreads();
    int acc = v;
    for (int off = 1; off < 256; off <<= 1) {
      int other = (threadIdx.x >= off) ? tmp[threadIdx.x - off] : 0;
      __syncthreads();
      acc += other;
      tmp[threadIdx.x] = acc;
      __syncthreads();
    }
    int c = carry;
    if (i < nb) bsum[i] = c + acc - v;
    __syncthreads();
    if (threadIdx.x == 255) carry = c + acc;
    __syncthreads();
  }
}

__device__ __forceinline__ void et_of_node(int i, int& et, int& base, int& nd,
                                           int& rpo) {
  if (i < NA) { et = 0; base = 0; nd = NA; rpo = 0; }
  else if (i < 2 * NA) { et = 1; base = NA; nd = NA; rpo = NA + 1; }
  else if (i < 2 * NA + NW) { et = 2; base = 2 * NA; nd = NW; rpo = 2 * (NA + 1); }
  else { et = 3; base = 2 * NA + NW; nd = NO; rpo = 2 * (NA + 1) + NW + 1; }
}

__global__ __launch_bounds__(256) void csr_finalize4(
    int* __restrict__ rpAll, const int* __restrict__ bsum,
    int* __restrict__ cursor) {
  int i = blockIdx.x * 256 + threadIdx.x;
  if (i >= 2 * NA + NW + NO) return;
  int et, base, nd, rpo;
  et_of_node(i, et, base, nd, rpo);
  int local = i - base;
  int v = rpAll[rpo + local] + bsum[et * 512 + (local >> 8)];
  rpAll[rpo + local] = v;
  cursor[base + local] = v;
  if (local == 0) rpAll[rpo + nd] = E;
}

__global__ __launch_bounds__(256) void csr_scatter4(
    const int* __restrict__ d0, const int* __restrict__ d1,
    const int* __restrict__ d2, const int* __restrict__ d3,
    int* __restrict__ cursor, int* __restrict__ ceAll) {
  int t = blockIdx.x * 256 + threadIdx.x;
  if (t >= 4 * E) return;
  int et = t / E, e = t - et * E;
  const int* dp = et == 0 ? d0 : et == 1 ? d1 : et == 2 ? d2 : d3;
  int base = et == 0 ? 0 : et == 1 ? NA : et == 2 ? 2 * NA : 2 * NA + NW;
  int slot = atomicAdd(&cursor[base + dp[e]], 1);
  ceAll[(size_t)et * E + slot] = e;
}

__global__ __launch_bounds__(256) void csr_sort4(const int* __restrict__ rpAll,
                                                 int* __restrict__ ceAll) {
  int i = blockIdx.x * 256 + threadIdx.x;
  if (i >= 2 * NA + NW + NO) return;
  int et, base, nd, rpo;
  et_of_node(i, et, base, nd, rpo);
  int local = i - base;
  int b = rpAll[rpo + local], e = rpAll[rpo + local + 1];
  int* ce = ceAll + (size_t)et * E;
  for (int k = b + 1; k < e; k++) {
    int key = ce[k];
    int j = k - 1;
    while (j >= b && ce[j] > key) { ce[j + 1] = ce[j]; j--; }
    ce[j + 1] = key;
  }
}

// slot-ordered GLOBAL src node ids
__global__ __launch_bounds__(256) void build_sd(
    const int* __restrict__ ce, const int* __restrict__ s0,
    const int* __restrict__ s1, const int* __restrict__ s2,
    const int* __restrict__ s3, int* __restrict__ srcOf) {
  int t = blockIdx.x * 256 + threadIdx.x;
  if (t >= 4 * E) return;
  int et = t / E;
  int e = ce[t];
  const int* sp = et == 0 ? s0 : et == 1 ? s1 : et == 2 ? s2 : s3;
  int sOff = et == 0 ? NA : et == 1 ? NA + NW : 0;
  srcOf[t] = sOff + sp[e];
}

// ---------------- fused attention (online softmax, single edge pass) ------
// one 64-lane wave per dst; lane = dim-pair; quarter q = lane>>4 = head.
__global__ __launch_bounds__(256) void attn_fused(
    const unsigned short* __restrict__ kqv, const int* __restrict__ rpAll,
    const int* __restrict__ srcOf, const float* __restrict__ Pl,
    const float* __restrict__ Ml, unsigned short* __restrict__ out) {
  int dl = (blockIdx.x * 256 + threadIdx.x) >> 6;
  int lane = threadIdx.x & 63;
  if (dl >= NTOT) return;
  int q = lane >> 4, p = lane & 15;
  int b0, e0, b1 = 0, e1 = 0, et23 = -1;
  const int* so0;
  const int* so1 = srcOf;
  float ps0, ps1 = 0.f;
  if (dl < NA) {
    b0 = rpAll[dl]; e0 = rpAll[dl + 1];
    b1 = rpAll[(NA + 1) + dl]; e1 = rpAll[(NA + 1) + dl + 1];
    so0 = srcOf; so1 = srcOf + E;
    ps0 = Pl[q] * SCALE; ps1 = Pl[H + q] * SCALE;
  } else if (dl < NA + NW) {
    int x = dl - NA;
    b0 = rpAll[2 * (NA + 1) + x]; e0 = rpAll[2 * (NA + 1) + x + 1];
    so0 = srcOf + 2 * (size_t)E;
    ps0 = Pl[2 * H + q] * SCALE;
    et23 = 2;
  } else {
    int x = dl - NA - NW;
    b0 = rpAll[2 * (NA + 1) + (NW + 1) + x];
    e0 = rpAll[2 * (NA + 1) + (NW + 1) + x + 1];
    so0 = srcOf + 3 * (size_t)E;
    ps0 = Pl[3 * H + q] * SCALE;
    et23 = 3;
  }
  const int n0 = e0 - b0;
  const int n01 = n0 + (e1 - b1);
  // q-row (one coalesced 256B load, stays in regs)
  unsigned qv = *(const unsigned*)(kqv + (size_t)dl * LDK + HID + lane * 2);
  float qx = bf2f((unsigned short)(qv & 0xFFFF));
  float qy = bf2f((unsigned short)(qv >> 16));
  // online softmax accumulation, single pass over edges
  float m = -INFINITY, den = 0.f, ax = 0.f, ay = 0.f;
  for (int t = 0; t < n01; t++) {
    int slot = t < n0 ? b0 + t : b1 + (t - n0);
    const int* so = t < n0 ? so0 : so1;
    float ps = t < n0 ? ps0 : ps1;
    int src = so[slot];
    const unsigned short* row = kqv + (size_t)src * LDK;
    unsigned kv2 = *(const unsigned*)(row + lane * 2);            // k
    unsigned vv = *(const unsigned*)(row + 2 * HID + lane * 2);   // v
    float s = qx * bf2f((unsigned short)(kv2 & 0xFFFF)) +
              qy * bf2f((unsigned short)(kv2 >> 16));
    s += __shfl_xor(s, 1, 64);
    s += __shfl_xor(s, 2, 64);
    s += __shfl_xor(s, 4, 64);
    s += __shfl_xor(s, 8, 64);
    s *= ps;  // uniform across the 16 lanes of this quarter
    float nm = fmaxf(m, s);
    float c = expf(m - nm);   // 1 if no new max; 0 on first iter (m=-inf)
    float w = expf(s - nm);
    den = den * c + w;
    ax = ax * c + w * bf2f((unsigned short)(vv & 0xFFFF));
    ay = ay * c + w * bf2f((unsigned short)(vv >> 16));
    m = nm;
  }
  float inv = 1.f / (den + 1e-16f);
  ax *= inv;
  ay *= inv;
  // W/O dst: M transform (raw-v aggregated; apply per-dst once)
  if (et23 >= 0) {
    const float* Mm = Ml + ((size_t)et23 * H + q) * D * D;
    int base = lane & 48;
    float o0 = 0.f, o1 = 0.f;
    #pragma unroll
    for (int j = 0; j < 16; j++) {
      float s0 = __shfl(ax, base + j, 64);
      float s1 = __shfl(ay, base + j, 64);
      float2 m0 = *(const float2*)&Mm[(2 * j) * 32 + 2 * p];
      float2 m1 = *(const float2*)&Mm[(2 * j + 1) * 32 + 2 * p];
      o0 += s0 * m0.x + s1 * m1.x;
      o1 += s0 * m0.y + s1 * m1.y;
    }
    ax = o0; ay = o1;
  }
  unsigned ov = (unsigned)f2bf(gelu_exact(ax)) |
                ((unsigned)f2bf(gelu_exact(ay)) << 16);
  *(unsigned*)(out + (size_t)dl * LDK + HID + lane * 2) = ov;
}

__global__ __launch_bounds__(256) void head_kernel(
    const unsigned short* __restrict__ xs0, const float* __restrict__ w_head,
    const float* __restrict__ b_head, const float* __restrict__ basep,
    float* __restrict__ out, int Nrows) {
  int wid = (blockIdx.x * 256 + threadIdx.x) >> 6;
  int lane = threadIdx.x & 63;
  if (wid >= Nrows) return;
  size_t base = (size_t)wid * HID;
  float d = bf2f(xs0[base + lane]) * w_head[lane] +
            bf2f(xs0[base + 64 + lane]) * w_head[64 + lane];
  #pragma unroll
  for (int m = 1; m < 64; m <<= 1) d += __shfl_xor(d, m, 64);
  if (lane == 0) out[wid] = basep[0] + b_head[0] + d;
}

}  // namespace

extern "C" void kernel_launch(void* const* d_in, const int* in_sizes, int n_in,
                              void* d_out, int out_size, void* d_ws,
                              size_t ws_size, hipStream_t stream) {
  const float* x_a = (const float*)d_in[0];
  const float* x_w = (const float*)d_in[1];
  const float* x_o = (const float*)d_in[2];
  const float* W_in = (const float*)d_in[3];
  const float* b_in = (const float*)d_in[4];
  const float* W_kqv = (const float*)d_in[5];
  const float* b_kqv = (const float*)d_in[6];
  const float* a_rel = (const float*)d_in[7];
  const float* m_rel = (const float*)d_in[8];
  const float* p_rel = (const float*)d_in[9];
  const float* skip_p = (const float*)d_in[10];
  const float* W_o = (const float*)d_in[11];
  const float* b_o = (const float*)d_in[12];
  const float* ln_g = (const float*)d_in[13];
  const float* ln_b = (const float*)d_in[14];
  const float* w_head = (const float*)d_in[15];
  const float* b_head = (const float*)d_in[16];
  const float* basep = (const float*)d_in[17];
  const int* srcs[4] = {(const int*)d_in[18], (const int*)d_in[20],
                        (const int*)d_in[22], (const int*)d_in[24]};
  const int* dsts[4] = {(const int*)d_in[19], (const int*)d_in[21],
                        (const int*)d_in[23], (const int*)d_in[25]};

  // ---- workspace layout (~183 MB) ----
  const size_t SZ_XS = (size_t)NTOT * HID * 2;
  const size_t SZ_KQV = (size_t)NTOT * LDK * 2;
  const size_t SZ_WINT = (size_t)3 * 128 * 64 * 2;
  const size_t SZ_WK0T = (size_t)2 * 384 * 128 * 2;
  const size_t SZ_WOT = (size_t)6 * 128 * 128 * 2;
  const size_t SZ_WET = (size_t)2 * 384 * 128 * 2;
  const size_t SZ_BE = ((size_t)2 * 384 * 4 + 63) & ~63ull;
  const size_t SZ_SD = (size_t)4 * E * 4;
  const int CNT_TOT = 2 * NA + NW + NO;
  const int RP_TOT = 2 * (NA + 1) + (NW + 1) + (NO + 1);
  const size_t SZ_RP = ((size_t)RP_TOT * 4 + 63) & ~63ull;
  const size_t SZ_CE = (size_t)4 * E * 4;
  const size_t SZ_CU = ((size_t)CNT_TOT * 4 + 63) & ~63ull;
  const size_t SZ_BS = 4 * 512 * 4;
  const size_t need = SZ_XS + SZ_KQV + SZ_WINT + SZ_WK0T + SZ_WOT + SZ_WET +
                      SZ_BE + SZ_SD + SZ_RP + SZ_CE + 2 * SZ_CU + SZ_BS;
  if (ws_size < need) return;

  char* p = (char*)d_ws;
  unsigned short* xs = (unsigned short*)p;    p += SZ_XS;
  unsigned short* kqvB = (unsigned short*)p;  p += SZ_KQV;
  unsigned short* WinT = (unsigned short*)p;  p += SZ_WINT;
  unsigned short* Wk0T = (unsigned short*)p;  p += SZ_WK0T;
  unsigned short* WoT = (unsigned short*)p;   p += SZ_WOT;
  unsigned short* WeT = (unsigned short*)p;   p += SZ_WET;
  float* beB = (float*)p;                     p += SZ_BE;
  int* srcOf = (int*)p;                       p += SZ_SD;
  int* rpAll = (int*)p;                       p += SZ_RP;
  int* ceAll = (int*)p;                       p += SZ_CE;
  int* cursor = (int*)p;                      p += SZ_CU;
  int* cnt = (int*)p;                         p += SZ_CU;
  int* bsum = (int*)p;

  const int rpOff[4] = {0, NA + 1, 2 * (NA + 1), 2 * (NA + 1) + NW + 1};
  const int cntBase[4] = {0, NA, 2 * NA, 2 * NA + NW};
  const int ndE[4] = {NA, NA, NW, NO};
  const int e4b = (4 * E + 255) / 256;
  const int nb0 = (NA + 63) / 64, nb01 = nb0 + (NW + 63) / 64;
  const int nbTot = nb01 + (NO + 63) / 64;

  // ---- CSR build (once) ----
  hipMemsetAsync(cnt, 0, (size_t)CNT_TOT * 4, stream);
  csr_hist4<<<e4b, 256, 0, stream>>>(dsts[0], dsts[1], dsts[2], dsts[3], cnt);
  for (int et = 0; et < 4; et++) {
    int nb = (ndE[et] + 255) / 256;
    scan_block<<<nb, 256, 0, stream>>>(cnt + cntBase[et], rpAll + rpOff[et],
                                       bsum + et * 512, ndE[et]);
    scan_bsums<<<1, 256, 0, stream>>>(bsum + et * 512, nb);
  }
  csr_finalize4<<<(CNT_TOT + 255) / 256, 256, 0, stream>>>(rpAll, bsum, cursor);
  csr_scatter4<<<e4b, 256, 0, stream>>>(dsts[0], dsts[1], dsts[2], dsts[3],
                                        cursor, ceAll);
  csr_sort4<<<(CNT_TOT + 255) / 256, 256, 0, stream>>>(rpAll, ceAll);
  build_sd<<<e4b, 256, 0, stream>>>(ceAll, srcs[0], srcs[1], srcs[2], srcs[3],
                                    srcOf);

  // ---- weight prep + input projection ----
  prep_weights<<<(3 * 128 * 64 + 2 * 384 * 128 + 6 * 128 * 128 + 255) / 256,
                 256, 0, stream>>>(W_in, W_kqv, W_o, WinT, Wk0T, WoT);
  in_fused<<<nbTot, 256, 0, stream>>>(x_a, x_w, x_o, WinT, b_in, xs, nb0, nb01);

  const size_t DD = (size_t)H * D * D;
  for (int l = 0; l < 2; l++) {
    const float* Al = a_rel + (size_t)l * 4 * DD;
    const float* Ml = m_rel + (size_t)l * 4 * DD;
    const float* Pl = p_rel + (size_t)l * 4 * H;
    const float* Wl = W_kqv + (size_t)l * 3 * HID * LDK;
    const float* bl = b_kqv + (size_t)l * 3 * LDK;
    fold_weights<<<(2 * 128 * 384 + 2 * 384 + 255) / 256, 256, 0, stream>>>(
        Wl, bl, Al, Ml, WeT, beB);
    kqv_fused<<<dim3(nbTot, 3), 256, 0, stream>>>(
        xs, Wk0T + (size_t)l * 384 * 128, bl, WeT, beB, kqvB, nb0, nb01);
    attn_fused<<<(NTOT + 3) / 4, 256, 0, stream>>>(kqvB, rpAll, srcOf, Pl, Ml,
                                                   kqvB);
    wo_ln_fused<<<nbTot, 256, 0, stream>>>(
        kqvB, WoT + (size_t)l * 3 * 128 * 128, b_o + (size_t)l * 3 * HID, xs,
        skip_p + l * 3, ln_g + (size_t)l * 3 * HID, ln_b + (size_t)l * 3 * HID,
        nb0, nb01);
  }
  head_kernel<<<(NA + 3) / 4, 256, 0, stream>>>(xs, w_head, b_head, basep,
                                                (float*)d_out, NA);
}

// Round 16
// 722.815 us; speedup vs baseline: 3.1349x; 1.0952x over previous
//
#include <hip/hip_runtime.h>
#include <cstddef>
#include <cmath>

namespace {

constexpr int H = 4, D = 32, HID = 128;
constexpr int NA = 100000, NW = 20000, NO = 50000;
constexpr int NTOT = NA + NW + NO;
constexpr int E = 150000;
constexpr float SCALE = 0.17677669529663687f;  // 1/sqrt(32)
constexpr int LDK = 3 * HID;  // kqv row stride (384)

typedef __attribute__((ext_vector_type(8))) short short8v;
typedef __attribute__((ext_vector_type(4))) float f32x4;

__device__ __forceinline__ float gelu_exact(float x) {
  return 0.5f * x * (1.f + erff(x * 0.7071067811865475f));
}
__device__ __forceinline__ unsigned short f2bf(float f) {  // RNE
  unsigned u = __float_as_uint(f);
  return (unsigned short)((u + 0x7FFF + ((u >> 16) & 1)) >> 16);
}
__device__ __forceinline__ float bf2f(unsigned short s) {
  return __uint_as_float(((unsigned)s) << 16);
}
__device__ __forceinline__ float blo(unsigned w) {
  return __uint_as_float(w << 16);
}
__device__ __forceinline__ float bhi(unsigned w) {
  return __uint_as_float(w & 0xFFFF0000u);
}

__device__ __forceinline__ int btype(int bx, int nb0, int nb01) {
  return bx < nb0 ? 0 : (bx < nb01 ? 1 : 2);
}

// ---------------- swizzled BK=64 MFMA GEMM body ----------------
template <int KSTEPS, bool A_FP32>
__device__ __forceinline__ void gemm_body(
    const void* __restrict__ Av, int lda, const unsigned short* __restrict__ BT,
    int ldb, f32x4* acc, int M, int bm) {
  __shared__ unsigned short As[64 * 64];
  __shared__ unsigned short Bs[128 * 64];
  const int tid = threadIdx.x;
  const int wv = tid >> 6, l = tid & 63;
  for (int ks = 0; ks < KSTEPS; ks++) {
    const int kk = ks * 64;
    #pragma unroll
    for (int p = 0; p < 2; p++) {
      int idx = tid + p * 256;
      int r = idx >> 3, c = idx & 7;
      int gr = bm + r;
      unsigned short tmp[8] = {0, 0, 0, 0, 0, 0, 0, 0};
      if (gr < M) {
        if (A_FP32) {
          const float* src = (const float*)Av + (size_t)gr * lda + kk + c * 8;
          float4 f0 = *(const float4*)src;
          float4 f1 = *(const float4*)(src + 4);
          tmp[0] = f2bf(f0.x); tmp[1] = f2bf(f0.y);
          tmp[2] = f2bf(f0.z); tmp[3] = f2bf(f0.w);
          tmp[4] = f2bf(f1.x); tmp[5] = f2bf(f1.y);
          tmp[6] = f2bf(f1.z); tmp[7] = f2bf(f1.w);
        } else {
          *(uint4*)tmp = *(const uint4*)((const unsigned short*)Av +
                                         (size_t)gr * lda + kk + c * 8);
        }
      }
      *(uint4*)&As[r * 64 + ((c ^ (r & 7)) * 8)] = *(const uint4*)tmp;
    }
    #pragma unroll
    for (int p = 0; p < 4; p++) {
      int idx = tid + p * 256;
      int r = idx >> 3, c = idx & 7;
      uint4 v = *(const uint4*)(BT + (size_t)r * ldb + kk + c * 8);
      *(uint4*)&Bs[r * 64 + ((c ^ (r & 7)) * 8)] = v;
    }
    __syncthreads();
    const int arow = wv * 16 + (l & 15);
    #pragma unroll
    for (int ksub = 0; ksub < 2; ksub++) {
      int ch = ksub * 4 + (l >> 4);
      short8v af = *(const short8v*)&As[arow * 64 + ((ch ^ (arow & 7)) * 8)];
      #pragma unroll
      for (int n = 0; n < 8; n++) {
        int brow = n * 16 + (l & 15);
        short8v bf =
            *(const short8v*)&Bs[brow * 64 + ((ch ^ (brow & 7)) * 8)];
        acc[n] =
            __builtin_amdgcn_mfma_f32_16x16x32_bf16(af, bf, acc[n], 0, 0, 0);
      }
    }
    __syncthreads();
  }
}

// ---------------- weight prep: bf16 transposed copies ----------------
__global__ __launch_bounds__(256) void prep_weights(
    const float* __restrict__ W_in, const float* __restrict__ W_kqv,
    const float* __restrict__ W_o, unsigned short* __restrict__ WinT,
    unsigned short* __restrict__ Wk0T, unsigned short* __restrict__ WoT) {
  int idx = blockIdx.x * 256 + threadIdx.x;
  const int N1 = 3 * 128 * 64, N2 = 2 * 384 * 128, N3 = 6 * 128 * 128;
  if (idx < N1) {
    int t = idx / 8192, rem = idx - t * 8192;
    int n = rem >> 6, k = rem & 63;
    WinT[idx] = f2bf(W_in[(size_t)t * 64 * 128 + (size_t)k * 128 + n]);
  } else if (idx < N1 + N2) {
    int r = idx - N1;
    int lyr = r / (384 * 128), rem = r - lyr * (384 * 128);
    int n = rem >> 7, k = rem & 127;
    Wk0T[r] = f2bf(W_kqv[(size_t)lyr * 3 * 128 * 384 + (size_t)k * 384 + n]);
  } else if (idx < N1 + N2 + N3) {
    int r = idx - N1 - N2;
    int lt = r / (128 * 128), rem = r - lt * (128 * 128);
    int n = rem >> 7, k = rem & 127;
    WoT[r] = f2bf(W_o[(size_t)lt * 128 * 128 + (size_t)k * 128 + n]);
  }
}

// ---------------- weight folding (per layer) -> bf16 transposed ----------
__global__ __launch_bounds__(256) void fold_weights(
    const float* __restrict__ Wl, const float* __restrict__ bl,
    const float* __restrict__ Al, const float* __restrict__ Ml,
    unsigned short* __restrict__ WeT, float* __restrict__ be) {
  int idx = blockIdx.x * 256 + threadIdx.x;
  const int NW_ = 2 * 128 * 384;
  if (idx < NW_) {
    int tt = idx / (128 * 384);
    int rem = idx - tt * (128 * 384);
    int r = rem / 384, c = rem - r * 384;
    int slice = c >> 7, h = (c >> 5) & 3, j = c & 31;
    const float* Wsrc = Wl + (size_t)(tt + 1) * 128 * 384 + (size_t)r * 384;
    float acc = 0.f;
    if (slice == 0) {
      const float* A = Al + ((size_t)tt * H + h) * D * D;
      for (int d = 0; d < 32; d++) acc += Wsrc[h * 32 + d] * A[d * 32 + j];
    } else if (slice == 1) {
      const float* A = Al + ((size_t)(2 + tt) * H + h) * D * D;
      for (int e = 0; e < 32; e++)
        acc += Wsrc[128 + h * 32 + e] * A[j * 32 + e];
    } else {
      const float* Mm = Ml + ((size_t)tt * H + h) * D * D;
      for (int d = 0; d < 32; d++)
        acc += Wsrc[256 + h * 32 + d] * Mm[d * 32 + j];
    }
    WeT[(size_t)tt * 384 * 128 + (size_t)c * 128 + r] = f2bf(acc);
  } else if (idx < NW_ + 2 * 384) {
    int rem = idx - NW_;
    int tt = rem / 384, c = rem - tt * 384;
    int slice = c >> 7, h = (c >> 5) & 3, j = c & 31;
    const float* bsrc = bl + (size_t)(tt + 1) * 384;
    float acc = 0.f;
    if (slice == 0) {
      const float* A = Al + ((size_t)tt * H + h) * D * D;
      for (int d = 0; d < 32; d++) acc += bsrc[h * 32 + d] * A[d * 32 + j];
    } else if (slice == 1) {
      const float* A = Al + ((size_t)(2 + tt) * H + h) * D * D;
      for (int e = 0; e < 32; e++)
        acc += bsrc[128 + h * 32 + e] * A[j * 32 + e];
    } else {
      const float* Mm = Ml + ((size_t)tt * H + h) * D * D;
      for (int d = 0; d < 32; d++)
        acc += bsrc[256 + h * 32 + d] * Mm[d * 32 + j];
    }
    be[rem] = acc;
  }
}

// input proj: xs = relu(x @ W_in[t] + b_in[t])
__global__ __launch_bounds__(256) void in_fused(
    const float* __restrict__ xa, const float* __restrict__ xw,
    const float* __restrict__ xo, const unsigned short* __restrict__ WinT,
    const float* __restrict__ b_in, unsigned short* __restrict__ xs, int nb0,
    int nb01) {
  int t = btype(blockIdx.x, nb0, nb01);
  int base = t == 0 ? 0 : (t == 1 ? nb0 : nb01);
  int M = t == 0 ? NA : (t == 1 ? NW : NO);
  int off = t == 0 ? 0 : (t == 1 ? NA : NA + NW);
  const float* A = t == 0 ? xa : (t == 1 ? xw : xo);
  const int bm = (blockIdx.x - base) * 64;
  f32x4 acc[8] = {};
  gemm_body<1, true>(A, 64, WinT + (size_t)t * 128 * 64, 64, acc, M, bm);
  const int l = threadIdx.x & 63, wv = threadIdx.x >> 6;
  const float* bias = b_in + t * HID;
  unsigned short* C = xs + (size_t)off * HID;
  #pragma unroll
  for (int n = 0; n < 8; n++) {
    int col = n * 16 + (l & 15);
    float bb = bias[col];
    #pragma unroll
    for (int j = 0; j < 4; j++) {
      int row = bm + wv * 16 + (l >> 4) * 4 + j;
      if (row < M) C[(size_t)row * HID + col] = f2bf(fmaxf(acc[n][j] + bb, 0.f));
    }
  }
}

// kqv proj: t=0 raw Wk0T; t=1,2 folded WeT. 64x128 tile, y = col-tile (3).
__global__ __launch_bounds__(256) void kqv_fused(
    const unsigned short* __restrict__ xs, const unsigned short* __restrict__ Wk0Tl,
    const float* __restrict__ b0, const unsigned short* __restrict__ WeT,
    const float* __restrict__ be, unsigned short* __restrict__ kqvB, int nb0,
    int nb01) {
  int t = btype(blockIdx.x, nb0, nb01);
  int base = t == 0 ? 0 : (t == 1 ? nb0 : nb01);
  int M = t == 0 ? NA : (t == 1 ? NW : NO);
  int off = t == 0 ? 0 : (t == 1 ? NA : NA + NW);
  const unsigned short* BT =
      (t == 0 ? Wk0Tl : WeT + (size_t)(t - 1) * 384 * 128);
  const float* bias = t == 0 ? b0 : be + (size_t)(t - 1) * 384;
  const int bm = (blockIdx.x - base) * 64;
  const int bn = blockIdx.y * 128;
  f32x4 acc[8] = {};
  gemm_body<2, false>(xs + (size_t)off * HID, HID, BT + (size_t)bn * 128, 128,
                      acc, M, bm);
  const int l = threadIdx.x & 63, wv = threadIdx.x >> 6;
  unsigned short* C = kqvB + (size_t)off * LDK;
  #pragma unroll
  for (int n = 0; n < 8; n++) {
    int col = bn + n * 16 + (l & 15);
    float bb = bias[col];
    #pragma unroll
    for (int j = 0; j < 4; j++) {
      int row = bm + wv * 16 + (l >> 4) * 4 + j;
      if (row < M) C[(size_t)row * LDK + col] = f2bf(acc[n][j] + bb);
    }
  }
}

// fused: xs = relu(LN( g*(agg_gelu @ W_o + b_o) + (1-g)*xs ))
__global__ __launch_bounds__(256) void wo_ln_fused(
    const unsigned short* __restrict__ kqvB, const unsigned short* __restrict__ WoTl,
    const float* __restrict__ bl, unsigned short* __restrict__ xs,
    const float* __restrict__ skipl, const float* __restrict__ gll,
    const float* __restrict__ bll, int nb0, int nb01) {
  int t = btype(blockIdx.x, nb0, nb01);
  int base = t == 0 ? 0 : (t == 1 ? nb0 : nb01);
  int M = t == 0 ? NA : (t == 1 ? NW : NO);
  int off = t == 0 ? 0 : (t == 1 ? NA : NA + NW);
  const int bm = (blockIdx.x - base) * 64;
  f32x4 acc[8] = {};
  gemm_body<2, false>(kqvB + (size_t)off * LDK + HID, LDK,
                      WoTl + (size_t)t * 128 * 128, 128, acc, M, bm);
  const int l = threadIdx.x & 63, wv = threadIdx.x >> 6;
  const float* bias = bl + t * HID;
  const float* gln = gll + t * HID;
  const float* bln = bll + t * HID;
  unsigned short* xsT = xs + (size_t)off * HID;
  const float g = 1.f / (1.f + expf(-skipl[t]));
  float bb[8], gl8[8], bl8[8];
  #pragma unroll
  for (int n = 0; n < 8; n++) {
    int col = n * 16 + (l & 15);
    bb[n] = bias[col];
    gl8[n] = gln[col];
    bl8[n] = bln[col];
  }
  #pragma unroll
  for (int j = 0; j < 4; j++) {
    int row = bm + wv * 16 + (l >> 4) * 4 + j;
    bool ok = row < M;
    float vv[8], sum = 0.f, sq = 0.f;
    #pragma unroll
    for (int n = 0; n < 8; n++) {
      int col = n * 16 + (l & 15);
      float xo = ok ? bf2f(xsT[(size_t)row * HID + col]) : 0.f;
      float val = g * (acc[n][j] + bb[n]) + (1.f - g) * xo;
      vv[n] = val;
      sum += val;
      sq += val * val;
    }
    #pragma unroll
    for (int m = 1; m < 16; m <<= 1) {
      sum += __shfl_xor(sum, m, 64);
      sq += __shfl_xor(sq, m, 64);
    }
    float mu = sum * (1.f / 128.f);
    float var = sq * (1.f / 128.f) - mu * mu;
    float r = rsqrtf(var + 1e-5f);
    if (ok) {
      #pragma unroll
      for (int n = 0; n < 8; n++) {
        float y = fmaxf((vv[n] - mu) * r * gl8[n] + bl8[n], 0.f);
        xsT[(size_t)row * HID + n * 16 + (l & 15)] = f2bf(y);
      }
    }
  }
}

// ---------------- CSR build (deterministic, 4 ets fused) ----------------
__global__ __launch_bounds__(256) void csr_hist4(
    const int* __restrict__ d0, const int* __restrict__ d1,
    const int* __restrict__ d2, const int* __restrict__ d3,
    int* __restrict__ cnt) {
  int t = blockIdx.x * 256 + threadIdx.x;
  if (t >= 4 * E) return;
  int et = t / E, e = t - et * E;
  const int* dp = et == 0 ? d0 : et == 1 ? d1 : et == 2 ? d2 : d3;
  int base = et == 0 ? 0 : et == 1 ? NA : et == 2 ? 2 * NA : 2 * NA + NW;
  atomicAdd(&cnt[base + dp[e]], 1);
}

__global__ __launch_bounds__(256) void scan_block(const int* __restrict__ cnt,
                                                  int* __restrict__ excl,
                                                  int* __restrict__ bsum,
                                                  int n) {
  __shared__ int tmp[256];
  int i = blockIdx.x * 256 + threadIdx.x;
  int v = (i < n) ? cnt[i] : 0;
  tmp[threadIdx.x] = v;
  __syncthreads();
  int acc = v;
  for (int off = 1; off < 256; off <<= 1) {
    int other = (threadIdx.x >= off) ? tmp[threadIdx.x - off] : 0;
    __syncthreads();
    acc += other;
    tmp[threadIdx.x] = acc;
    __syncthreads();
  }
  if (i < n) excl[i] = acc - v;
  if (threadIdx.x == 255) bsum[blockIdx.x] = acc;
}

__global__ __launch_bounds__(256) void scan_bsums(int* __restrict__ bsum,
                                                  int nb) {
  __shared__ int tmp[256];
  __shared__ int carry;
  if (threadIdx.x == 0) carry = 0;
  __syncthreads();
  for (int start = 0; start < nb; start += 256) {
    int i = start + threadIdx.x;
    int v = (i < nb) ? bsum[i] : 0;
    tmp[threadIdx.x] = v;
    __syncthreads();
    int acc = v;
    for (int off = 1; off < 256; off <<= 1) {
      int other = (threadIdx.x >= off) ? tmp[threadIdx.x - off] : 0;
      __syncthreads();
      acc += other;
      tmp[threadIdx.x] = acc;
      __syncthreads();
    }
    int c = carry;
    if (i < nb) bsum[i] = c + acc - v;
    __syncthreads();
    if (threadIdx.x == 255) carry = c + acc;
    __syncthreads();
  }
}

__device__ __forceinline__ void et_of_node(int i, int& et, int& base, int& nd,
                                           int& rpo) {
  if (i < NA) { et = 0; base = 0; nd = NA; rpo = 0; }
  else if (i < 2 * NA) { et = 1; base = NA; nd = NA; rpo = NA + 1; }
  else if (i < 2 * NA + NW) { et = 2; base = 2 * NA; nd = NW; rpo = 2 * (NA + 1); }
  else { et = 3; base = 2 * NA + NW; nd = NO; rpo = 2 * (NA + 1) + NW + 1; }
}

__global__ __launch_bounds__(256) void csr_finalize4(
    int* __restrict__ rpAll, const int* __restrict__ bsum,
    int* __restrict__ cursor) {
  int i = blockIdx.x * 256 + threadIdx.x;
  if (i >= 2 * NA + NW + NO) return;
  int et, base, nd, rpo;
  et_of_node(i, et, base, nd, rpo);
  int local = i - base;
  int v = rpAll[rpo + local] + bsum[et * 512 + (local >> 8)];
  rpAll[rpo + local] = v;
  cursor[base + local] = v;
  if (local == 0) rpAll[rpo + nd] = E;
}

__global__ __launch_bounds__(256) void csr_scatter4(
    const int* __restrict__ d0, const int* __restrict__ d1,
    const int* __restrict__ d2, const int* __restrict__ d3,
    int* __restrict__ cursor, int* __restrict__ ceAll) {
  int t = blockIdx.x * 256 + threadIdx.x;
  if (t >= 4 * E) return;
  int et = t / E, e = t - et * E;
  const int* dp = et == 0 ? d0 : et == 1 ? d1 : et == 2 ? d2 : d3;
  int base = et == 0 ? 0 : et == 1 ? NA : et == 2 ? 2 * NA : 2 * NA + NW;
  int slot = atomicAdd(&cursor[base + dp[e]], 1);
  ceAll[(size_t)et * E + slot] = e;
}

__global__ __launch_bounds__(256) void csr_sort4(const int* __restrict__ rpAll,
                                                 int* __restrict__ ceAll) {
  int i = blockIdx.x * 256 + threadIdx.x;
  if (i >= 2 * NA + NW + NO) return;
  int et, base, nd, rpo;
  et_of_node(i, et, base, nd, rpo);
  int local = i - base;
  int b = rpAll[rpo + local], e = rpAll[rpo + local + 1];
  int* ce = ceAll + (size_t)et * E;
  for (int k = b + 1; k < e; k++) {
    int key = ce[k];
    int j = k - 1;
    while (j >= b && ce[j] > key) { ce[j + 1] = ce[j]; j--; }
    ce[j + 1] = key;
  }
}

// slot-ordered GLOBAL src node ids
__global__ __launch_bounds__(256) void build_sd(
    const int* __restrict__ ce, const int* __restrict__ s0,
    const int* __restrict__ s1, const int* __restrict__ s2,
    const int* __restrict__ s3, int* __restrict__ srcOf) {
  int t = blockIdx.x * 256 + threadIdx.x;
  if (t >= 4 * E) return;
  int et = t / E;
  int e = ce[t];
  const int* sp = et == 0 ? s0 : et == 1 ? s1 : et == 2 ? s2 : s3;
  int sOff = et == 0 ? NA : et == 1 ? NA + NW : 0;
  srcOf[t] = sOff + sp[e];
}

// ---------------- fused attention (online softmax, pipelined) -------------
// one 64-lane wave per dst; lane = dim-pair; quarter q = lane>>4 = head.
// 2-wide unrolled edge loop with 2-stage prefetch (rows t+2/t+3, idx t+4/t+5).
__global__ __launch_bounds__(256) void attn_fused(
    const unsigned short* __restrict__ kqv, const int* __restrict__ rpAll,
    const int* __restrict__ srcOf, const float* __restrict__ Pl,
    const float* __restrict__ Ml, unsigned short* __restrict__ out) {
  int dl = (blockIdx.x * 256 + threadIdx.x) >> 6;
  int lane = threadIdx.x & 63;
  if (dl >= NTOT) return;
  int q = lane >> 4, p = lane & 15;
  int b0, e0, b1 = 0, e1 = 0, et23 = -1;
  const int* so0;
  const int* so1 = srcOf;
  float ps0, ps1 = 0.f;
  if (dl < NA) {
    b0 = rpAll[dl]; e0 = rpAll[dl + 1];
    b1 = rpAll[(NA + 1) + dl]; e1 = rpAll[(NA + 1) + dl + 1];
    so0 = srcOf; so1 = srcOf + E;
    ps0 = Pl[q] * SCALE; ps1 = Pl[H + q] * SCALE;
  } else if (dl < NA + NW) {
    int x = dl - NA;
    b0 = rpAll[2 * (NA + 1) + x]; e0 = rpAll[2 * (NA + 1) + x + 1];
    so0 = srcOf + 2 * (size_t)E;
    ps0 = Pl[2 * H + q] * SCALE;
    et23 = 2;
  } else {
    int x = dl - NA - NW;
    b0 = rpAll[2 * (NA + 1) + (NW + 1) + x];
    e0 = rpAll[2 * (NA + 1) + (NW + 1) + x + 1];
    so0 = srcOf + 3 * (size_t)E;
    ps0 = Pl[3 * H + q] * SCALE;
    et23 = 3;
  }
  const int n0 = e0 - b0;
  const int n01 = n0 + (e1 - b1);
  auto srcAt = [&](int t) -> int {
    return (t < n0) ? so0[b0 + t] : so1[b1 + (t - n0)];
  };
  // q-row (one coalesced 256B load, stays in regs)
  unsigned qv = *(const unsigned*)(kqv + (size_t)dl * LDK + HID + lane * 2);
  float qx = blo(qv), qy = bhi(qv);
  const int lo2 = lane * 2;

  float m = -INFINITY, den = 0.f, ax = 0.f, ay = 0.f;
  // pipeline prologue: rows for edges 0,1; indices for 2,3
  unsigned ka = 0, va = 0, kb = 0, vb = 0;
  int i2 = 0, i3 = 0;
  if (n01 > 0) {
    const unsigned short* r = kqv + (size_t)srcAt(0) * LDK;
    ka = *(const unsigned*)(r + lo2);
    va = *(const unsigned*)(r + 2 * HID + lo2);
  }
  if (n01 > 1) {
    const unsigned short* r = kqv + (size_t)srcAt(1) * LDK;
    kb = *(const unsigned*)(r + lo2);
    vb = *(const unsigned*)(r + 2 * HID + lo2);
  }
  if (n01 > 2) i2 = srcAt(2);
  if (n01 > 3) i3 = srcAt(3);
  int t = 0;
  for (; t + 1 < n01; t += 2) {
    unsigned pka = ka, pva = va, pkb = kb, pvb = vb;
    float psa = (t < n0) ? ps0 : ps1;
    float psb = (t + 1 < n0) ? ps0 : ps1;
    // prefetch rows for t+2, t+3
    if (t + 2 < n01) {
      const unsigned short* r = kqv + (size_t)i2 * LDK;
      ka = *(const unsigned*)(r + lo2);
      va = *(const unsigned*)(r + 2 * HID + lo2);
    }
    if (t + 3 < n01) {
      const unsigned short* r = kqv + (size_t)i3 * LDK;
      kb = *(const unsigned*)(r + lo2);
      vb = *(const unsigned*)(r + 2 * HID + lo2);
    }
    // prefetch indices for t+4, t+5
    if (t + 4 < n01) i2 = srcAt(t + 4);
    if (t + 5 < n01) i3 = srcAt(t + 5);
    // compute pair (independent shfl chains -> ILP)
    float sa = qx * blo(pka) + qy * bhi(pka);
    float sb = qx * blo(pkb) + qy * bhi(pkb);
    sa += __shfl_xor(sa, 1, 64);
    sb += __shfl_xor(sb, 1, 64);
    sa += __shfl_xor(sa, 2, 64);
    sb += __shfl_xor(sb, 2, 64);
    sa += __shfl_xor(sa, 4, 64);
    sb += __shfl_xor(sb, 4, 64);
    sa += __shfl_xor(sa, 8, 64);
    sb += __shfl_xor(sb, 8, 64);
    sa *= psa;
    sb *= psb;
    float nm = fmaxf(m, fmaxf(sa, sb));
    float c = __expf(m - nm);
    float wa = __expf(sa - nm), wb = __expf(sb - nm);
    den = den * c + wa + wb;
    ax = ax * c + wa * blo(pva) + wb * blo(pvb);
    ay = ay * c + wa * bhi(pva) + wb * bhi(pvb);
    m = nm;
  }
  if (t < n01) {  // odd tail (rows already in ka/va)
    float ps = (t < n0) ? ps0 : ps1;
    float s = qx * blo(ka) + qy * bhi(ka);
    s += __shfl_xor(s, 1, 64);
    s += __shfl_xor(s, 2, 64);
    s += __shfl_xor(s, 4, 64);
    s += __shfl_xor(s, 8, 64);
    s *= ps;
    float nm = fmaxf(m, s);
    float c = __expf(m - nm);
    float w = __expf(s - nm);
    den = den * c + w;
    ax = ax * c + w * blo(va);
    ay = ay * c + w * bhi(va);
  }
  float inv = 1.f / (den + 1e-16f);
  ax *= inv;
  ay *= inv;
  // W/O dst: M transform (raw-v aggregated; apply per-dst once)
  if (et23 >= 0) {
    const float* Mm = Ml + ((size_t)et23 * H + q) * D * D;
    int base = lane & 48;
    float o0 = 0.f, o1 = 0.f;
    #pragma unroll
    for (int j = 0; j < 16; j++) {
      float s0 = __shfl(ax, base + j, 64);
      float s1 = __shfl(ay, base + j, 64);
      float2 m0 = *(const float2*)&Mm[(2 * j) * 32 + 2 * p];
      float2 m1 = *(const float2*)&Mm[(2 * j + 1) * 32 + 2 * p];
      o0 += s0 * m0.x + s1 * m1.x;
      o1 += s0 * m0.y + s1 * m1.y;
    }
    ax = o0; ay = o1;
  }
  unsigned ov = (unsigned)f2bf(gelu_exact(ax)) |
                ((unsigned)f2bf(gelu_exact(ay)) << 16);
  *(unsigned*)(out + (size_t)dl * LDK + HID + lane * 2) = ov;
}

__global__ __launch_bounds__(256) void head_kernel(
    const unsigned short* __restrict__ xs0, const float* __restrict__ w_head,
    const float* __restrict__ b_head, const float* __restrict__ basep,
    float* __restrict__ out, int Nrows) {
  int wid = (blockIdx.x * 256 + threadIdx.x) >> 6;
  int lane = threadIdx.x & 63;
  if (wid >= Nrows) return;
  size_t base = (size_t)wid * HID;
  float d = bf2f(xs0[base + lane]) * w_head[lane] +
            bf2f(xs0[base + 64 + lane]) * w_head[64 + lane];
  #pragma unroll
  for (int m = 1; m < 64; m <<= 1) d += __shfl_xor(d, m, 64);
  if (lane == 0) out[wid] = basep[0] + b_head[0] + d;
}

}  // namespace

extern "C" void kernel_launch(void* const* d_in, const int* in_sizes, int n_in,
                              void* d_out, int out_size, void* d_ws,
                              size_t ws_size, hipStream_t stream) {
  const float* x_a = (const float*)d_in[0];
  const float* x_w = (const float*)d_in[1];
  const float* x_o = (const float*)d_in[2];
  const float* W_in = (const float*)d_in[3];
  const float* b_in = (const float*)d_in[4];
  const float* W_kqv = (const float*)d_in[5];
  const float* b_kqv = (const float*)d_in[6];
  const float* a_rel = (const float*)d_in[7];
  const float* m_rel = (const float*)d_in[8];
  const float* p_rel = (const float*)d_in[9];
  const float* skip_p = (const float*)d_in[10];
  const float* W_o = (const float*)d_in[11];
  const float* b_o = (const float*)d_in[12];
  const float* ln_g = (const float*)d_in[13];
  const float* ln_b = (const float*)d_in[14];
  const float* w_head = (const float*)d_in[15];
  const float* b_head = (const float*)d_in[16];
  const float* basep = (const float*)d_in[17];
  const int* srcs[4] = {(const int*)d_in[18], (const int*)d_in[20],
                        (const int*)d_in[22], (const int*)d_in[24]};
  const int* dsts[4] = {(const int*)d_in[19], (const int*)d_in[21],
                        (const int*)d_in[23], (const int*)d_in[25]};

  // ---- workspace layout (~183 MB) ----
  const size_t SZ_XS = (size_t)NTOT * HID * 2;
  const size_t SZ_KQV = (size_t)NTOT * LDK * 2;
  const size_t SZ_WINT = (size_t)3 * 128 * 64 * 2;
  const size_t SZ_WK0T = (size_t)2 * 384 * 128 * 2;
  const size_t SZ_WOT = (size_t)6 * 128 * 128 * 2;
  const size_t SZ_WET = (size_t)2 * 384 * 128 * 2;
  const size_t SZ_BE = ((size_t)2 * 384 * 4 + 63) & ~63ull;
  const size_t SZ_SD = (size_t)4 * E * 4;
  const int CNT_TOT = 2 * NA + NW + NO;
  const int RP_TOT = 2 * (NA + 1) + (NW + 1) + (NO + 1);
  const size_t SZ_RP = ((size_t)RP_TOT * 4 + 63) & ~63ull;
  const size_t SZ_CE = (size_t)4 * E * 4;
  const size_t SZ_CU = ((size_t)CNT_TOT * 4 + 63) & ~63ull;
  const size_t SZ_BS = 4 * 512 * 4;
  const size_t need = SZ_XS + SZ_KQV + SZ_WINT + SZ_WK0T + SZ_WOT + SZ_WET +
                      SZ_BE + SZ_SD + SZ_RP + SZ_CE + 2 * SZ_CU + SZ_BS;
  if (ws_size < need) return;

  char* p = (char*)d_ws;
  unsigned short* xs = (unsigned short*)p;    p += SZ_XS;
  unsigned short* kqvB = (unsigned short*)p;  p += SZ_KQV;
  unsigned short* WinT = (unsigned short*)p;  p += SZ_WINT;
  unsigned short* Wk0T = (unsigned short*)p;  p += SZ_WK0T;
  unsigned short* WoT = (unsigned short*)p;   p += SZ_WOT;
  unsigned short* WeT = (unsigned short*)p;   p += SZ_WET;
  float* beB = (float*)p;                     p += SZ_BE;
  int* srcOf = (int*)p;                       p += SZ_SD;
  int* rpAll = (int*)p;                       p += SZ_RP;
  int* ceAll = (int*)p;                       p += SZ_CE;
  int* cursor = (int*)p;                      p += SZ_CU;
  int* cnt = (int*)p;                         p += SZ_CU;
  int* bsum = (int*)p;

  const int rpOff[4] = {0, NA + 1, 2 * (NA + 1), 2 * (NA + 1) + NW + 1};
  const int cntBase[4] = {0, NA, 2 * NA, 2 * NA + NW};
  const int ndE[4] = {NA, NA, NW, NO};
  const int e4b = (4 * E + 255) / 256;
  const int nb0 = (NA + 63) / 64, nb01 = nb0 + (NW + 63) / 64;
  const int nbTot = nb01 + (NO + 63) / 64;

  // ---- CSR build (once) ----
  hipMemsetAsync(cnt, 0, (size_t)CNT_TOT * 4, stream);
  csr_hist4<<<e4b, 256, 0, stream>>>(dsts[0], dsts[1], dsts[2], dsts[3], cnt);
  for (int et = 0; et < 4; et++) {
    int nb = (ndE[et] + 255) / 256;
    scan_block<<<nb, 256, 0, stream>>>(cnt + cntBase[et], rpAll + rpOff[et],
                                       bsum + et * 512, ndE[et]);
    scan_bsums<<<1, 256, 0, stream>>>(bsum + et * 512, nb);
  }
  csr_finalize4<<<(CNT_TOT + 255) / 256, 256, 0, stream>>>(rpAll, bsum, cursor);
  csr_scatter4<<<e4b, 256, 0, stream>>>(dsts[0], dsts[1], dsts[2], dsts[3],
                                        cursor, ceAll);
  csr_sort4<<<(CNT_TOT + 255) / 256, 256, 0, stream>>>(rpAll, ceAll);
  build_sd<<<e4b, 256, 0, stream>>>(ceAll, srcs[0], srcs[1], srcs[2], srcs[3],
                                    srcOf);

  // ---- weight prep + input projection ----
  prep_weights<<<(3 * 128 * 64 + 2 * 384 * 128 + 6 * 128 * 128 + 255) / 256,
                 256, 0, stream>>>(W_in, W_kqv, W_o, WinT, Wk0T, WoT);
  in_fused<<<nbTot, 256, 0, stream>>>(x_a, x_w, x_o, WinT, b_in, xs, nb0, nb01);

  const size_t DD = (size_t)H * D * D;
  for (int l = 0; l < 2; l++) {
    const float* Al = a_rel + (size_t)l * 4 * DD;
    const float* Ml = m_rel + (size_t)l * 4 * DD;
    const float* Pl = p_rel + (size_t)l * 4 * H;
    const float* Wl = W_kqv + (size_t)l * 3 * HID * LDK;
    const float* bl = b_kqv + (size_t)l * 3 * LDK;
    fold_weights<<<(2 * 128 * 384 + 2 * 384 + 255) / 256, 256, 0, stream>>>(
        Wl, bl, Al, Ml, WeT, beB);
    kqv_fused<<<dim3(nbTot, 3), 256, 0, stream>>>(
        xs, Wk0T + (size_t)l * 384 * 128, bl, WeT, beB, kqvB, nb0, nb01);
    attn_fused<<<(NTOT + 3) / 4, 256, 0, stream>>>(kqvB, rpAll, srcOf, Pl, Ml,
                                                   kqvB);
    wo_ln_fused<<<nbTot, 256, 0, stream>>>(
        kqvB, WoT + (size_t)l * 3 * 128 * 128, b_o + (size_t)l * 3 * HID, xs,
        skip_p + l * 3, ln_g + (size_t)l * 3 * HID, ln_b + (size_t)l * 3 * HID,
        nb0, nb01);
  }
  head_kernel<<<(NA + 3) / 4, 256, 0, stream>>>(xs, w_head, b_head, basep,
                                                (float*)d_out, NA);
}